// Round 7
// baseline (537.075 us; speedup 1.0000x reference)
//
#include <hip/hip_runtime.h>
#include <math.h>

#define NN 4096
#define TT 32
#define FF 7
#define HH 64
#define NHEAD 8
#define DOUT 8

__device__ __forceinline__ float sigm(float x){
  x = fminf(fmaxf(x, -30.f), 30.f);
  return 1.f / (1.f + __expf(-x));
}
__device__ __forceinline__ float tanh_fast(float x){
  x = fminf(fmaxf(x, -15.f), 15.f);
  float e = __expf(2.f*x);
  return (e - 1.f) / (e + 1.f);
}
__device__ __forceinline__ float bcast(float v, int k){
  return __uint_as_float(__builtin_amdgcn_readlane(__float_as_uint(v), k));
}

// ---------------- K0: transpose small 64x64 weights to k-major ----------------
__global__ void k0_prep(const float* __restrict__ pw, const float* __restrict__ msw,
                        const float* __restrict__ mpw, const float* __restrict__ sw1,
                        float* __restrict__ wtproj, float* __restrict__ wtself,
                        float* __restrict__ wtpos, float* __restrict__ wtsem)
{
  int tid = threadIdx.x + blockIdx.x*blockDim.x;
  if (tid < 4096){
    int d = tid >> 6, k = tid & 63;
    wtproj[k*64+d] = pw[tid];
    wtself[k*64+d] = msw[tid];
    wtpos[k*64+d]  = mpw[tid];
    wtsem[k*64+d]  = sw1[tid];
  }
}

// ---------------- K1: GRU encoder (readlane h-broadcast, no per-t LDS chain) ----------------
// 256 blocks x 256 threads; wave owns 4 nodes; lane l owns gate rows {l,l+64,l+128}.
// W_hh in LDS (XOR-swizzled b128 reads); h stays in registers across t and is
// broadcast via v_readlane (SGPR operand into v_fma) -- zero LDS in the t-chain.
__global__ __launch_bounds__(256, 2) void k1_gru(
    const float* __restrict__ x,      // [N][T][F]
    const float* __restrict__ Wih,    // [192][7]
    const float* __restrict__ Whh,    // [192][64]
    const float* __restrict__ bih, const float* __restrict__ bhh,
    float* __restrict__ hout)         // [N][64]
{
  __shared__ float s_whh[192*64];     // swizzled, 48KB
  __shared__ float s_x[4][448];       // per-wave x staging (4 nodes x 16 t x 7 f), 7KB

  int tid = threadIdx.x;
  int lane = tid & 63, wave = tid >> 6;

  for (int i = tid; i < 192*64; i += 256){
    int g = i >> 6, k = i & 63;
    s_whh[g*64 + (k ^ ((g & 7) << 2))] = Whh[i];
  }

  float wr_[7], wz_[7], wn_[7];
  #pragma unroll
  for (int f = 0; f < 7; ++f){
    wr_[f] = Wih[lane*7 + f];
    wz_[f] = Wih[(lane+64)*7 + f];
    wn_[f] = Wih[(lane+128)*7 + f];
  }
  float bir = bih[lane], biz = bih[lane+64], bin_ = bih[lane+128];
  float bhr = bhh[lane], bhz = bhh[lane+64], bhn = bhh[lane+128];

  int nb = blockIdx.x*16 + wave*4;    // first node of this wave
  float hreg[4] = {0.f, 0.f, 0.f, 0.f};
  __syncthreads();                    // only barrier: s_whh staging

  int sw = (lane & 7) << 2;           // word swizzle for this lane's rows
  const float* rowr = s_whh + lane*64;
  const float* rowz = s_whh + (lane+64)*64;
  const float* rown = s_whh + (lane+128)*64;

  for (int half = 0; half < 2; ++half){
    // stage x for this wave's 4 nodes, 16 timesteps (wave-private: no barrier)
    for (int i = lane; i < 448; i += 64){
      int n = i / 112, rem = i - n*112;
      s_x[wave][i] = x[(size_t)(nb + n)*224 + half*112 + rem];
    }
    for (int tt = 0; tt < 16; ++tt){
      float accr[4] = {0.f,0.f,0.f,0.f};
      float accz[4] = {0.f,0.f,0.f,0.f};
      float accn[4] = {0.f,0.f,0.f,0.f};
      #pragma unroll
      for (int k4 = 0; k4 < 16; ++k4){
        int off = (k4*4) ^ sw;
        float4 w4r = *(const float4*)(rowr + off);
        float4 w4z = *(const float4*)(rowz + off);
        float4 w4n = *(const float4*)(rown + off);
        #pragma unroll
        for (int n = 0; n < 4; ++n){
          float h0 = bcast(hreg[n], k4*4+0);
          float h1 = bcast(hreg[n], k4*4+1);
          float h2 = bcast(hreg[n], k4*4+2);
          float h3 = bcast(hreg[n], k4*4+3);
          accr[n] += w4r.x*h0 + w4r.y*h1 + w4r.z*h2 + w4r.w*h3;
          accz[n] += w4z.x*h0 + w4z.y*h1 + w4z.z*h2 + w4z.w*h3;
          accn[n] += w4n.x*h0 + w4n.y*h1 + w4n.z*h2 + w4n.w*h3;
        }
      }
      #pragma unroll
      for (int n = 0; n < 4; ++n){
        const float* xp = &s_x[wave][n*112 + tt*7];
        float gr = bir, gz = biz, gn = bin_;
        #pragma unroll
        for (int f = 0; f < 7; ++f){
          float xv = xp[f];
          gr += wr_[f]*xv; gz += wz_[f]*xv; gn += wn_[f]*xv;
        }
        float rr = sigm(gr + bhr + accr[n]);
        float zz = sigm(gz + bhz + accz[n]);
        float nn = tanh_fast(gn + rr*(bhn + accn[n]));
        hreg[n] = (1.f - zz)*nn + zz*hreg[n];
      }
    }
  }
  #pragma unroll
  for (int n = 0; n < 4; ++n)
    hout[(size_t)(nb+n)*64 + lane] = hreg[n];
}

// ---------------- K2: sup (transposed) = h@gat_w, f1t/f2 head scalars, block f1 max ----------------
__global__ __launch_bounds__(256) void k2_sup(
    const float* __restrict__ h, const float* __restrict__ gat_w,
    const float* __restrict__ wu, const float* __restrict__ wv,
    float* __restrict__ supt,    // [64][N]  row = hh*8+o
    float* __restrict__ f1t,     // [8][N]
    float* __restrict__ f2,      // [N][8]
    float* __restrict__ bmax)
{
  int tid = threadIdx.x;
  int wave = tid >> 6, lane = tid & 63;
  int n = blockIdx.x*4 + wave;
  float hreg = h[n*64 + lane];
  float acc = 0.f;
  #pragma unroll
  for (int k = 0; k < 64; ++k){
    float hk = __shfl(hreg, k, 64);
    acc += hk * gat_w[k*64 + lane];
  }
  supt[(size_t)lane*NN + n] = acc;     // transposed write (j-major per head-out row)
  float p1 = acc * wu[lane];
  float p2 = acc * wv[lane];
  #pragma unroll
  for (int s = 1; s < 8; s <<= 1){
    p1 += __shfl_xor(p1, s, 64);
    p2 += __shfl_xor(p2, s, 64);
  }
  int hh = lane >> 3;
  __shared__ float s_m[4][8];
  if ((lane & 7) == 0){
    f1t[(size_t)hh*NN + n] = p1;
    f2[n*8 + hh] = p2;
    s_m[wave][hh] = p1;
  }
  __syncthreads();
  if (tid < 8){
    float mm = fmaxf(fmaxf(s_m[0][tid], s_m[1][tid]), fmaxf(s_m[2][tid], s_m[3][tid]));
    bmax[blockIdx.x*8 + tid] = mm;
  }
}

__global__ __launch_bounds__(256) void k2b_max(const float* __restrict__ bmax, float* __restrict__ maxf1)
{
  int tid = threadIdx.x;
  int hh = tid & 7, chunk = tid >> 3;   // 32 chunks of 32 blocks
  float m = -1e30f;
  for (int b = chunk*32; b < chunk*32+32; ++b) m = fmaxf(m, bmax[b*8 + hh]);
  __shared__ float sm[256];
  sm[tid] = m;
  __syncthreads();
  if (tid < 8){
    float mm = -1e30f;
    for (int c = 0; c < 32; ++c) mm = fmaxf(mm, sm[c*8 + tid]);
    maxf1[tid] = mm;
  }
}

// ---------------- K2c: pack adjacency rows into 64-bit masks ----------------
__global__ __launch_bounds__(256) void k2c_pack(const int* __restrict__ adj,
                                               unsigned long long* __restrict__ adjm)
{
  int lane = threadIdx.x & 63, wave = threadIdx.x >> 6;
  int row = blockIdx.x*4 + wave;
  const int* ap = adj + (size_t)row*NN;
  #pragma unroll 8
  for (int s = 0; s < 64; ++s){
    unsigned long long m = __ballot(ap[s*64 + lane] != 0);
    if (lane == 0) adjm[(size_t)row*64 + s] = m;
  }
}

// ---------------- K3: masked-softmax GAT, one wave per (8 rows, 1 head) ----------------
__global__ __launch_bounds__(256) void k3_gat(
    const unsigned long long* __restrict__ adjm,   // [N][64]
    const float* __restrict__ supt,                // [64][N]
    const float* __restrict__ f1t,                 // [8][N]
    const float* __restrict__ f2,                  // [N][8]
    const float* __restrict__ maxf1, float* __restrict__ posg)
{
  int tid = threadIdx.x;
  int lane = tid & 63, wave = tid >> 6;
  int gid = blockIdx.x*4 + wave;        // 0..4095
  int ib = gid >> 3, h = gid & 7;
  int i0 = ib*8;

  float mf = maxf1[h];
  float f2v[8], M[8];
  #pragma unroll
  for (int r = 0; r < 8; ++r){
    f2v[r] = f2[(size_t)(i0+r)*8 + h];
    float lg = mf + f2v[r];
    lg = fmaxf(lg, 0.2f*lg);
    M[r] = fmaxf(lg, 0.f);              // upper bound on reference rowmax
  }

  const float2* f1p = (const float2*)(f1t + (size_t)h*NN);
  const float2* sp0 = (const float2*)(supt + (size_t)(h*8+0)*NN);
  const float2* sp1 = (const float2*)(supt + (size_t)(h*8+1)*NN);
  const float2* sp2 = (const float2*)(supt + (size_t)(h*8+2)*NN);
  const float2* sp3 = (const float2*)(supt + (size_t)(h*8+3)*NN);
  const float2* sp4 = (const float2*)(supt + (size_t)(h*8+4)*NN);
  const float2* sp5 = (const float2*)(supt + (size_t)(h*8+5)*NN);
  const float2* sp6 = (const float2*)(supt + (size_t)(h*8+6)*NN);
  const float2* sp7 = (const float2*)(supt + (size_t)(h*8+7)*NN);
  const unsigned long long* mbase = adjm + (size_t)i0*64;

  int sh0 = (lane*2) & 63;              // bit position of this lane's first j
  int woff = (lane >> 5);               // which of the 2 words this iter

  float sum[8] = {0.f,0.f,0.f,0.f,0.f,0.f,0.f,0.f};
  float pos[8][8];
  #pragma unroll
  for (int r = 0; r < 8; ++r)
    #pragma unroll
    for (int o = 0; o < 8; ++o) pos[r][o] = 0.f;

  for (int b = 0; b < 32; ++b){         // 128 j per iter (2 j per lane)
    int idx = b*64 + lane;
    float2 f1v = f1p[idx];
    float2 s0 = sp0[idx], s1 = sp1[idx], s2 = sp2[idx], s3 = sp3[idx];
    float2 s4 = sp4[idx], s5 = sp5[idx], s6 = sp6[idx], s7 = sp7[idx];
    int w = b*2 + woff;
    unsigned long long mw[8];
    #pragma unroll
    for (int r = 0; r < 8; ++r) mw[r] = mbase[r*64 + w];

    #pragma unroll
    for (int r = 0; r < 8; ++r){
      float l0 = f1v.x + f2v[r];
      float l1 = f1v.y + f2v[r];
      l0 = fmaxf(l0, 0.2f*l0);
      l1 = fmaxf(l1, 0.2f*l1);
      float p0 = __expf(l0 - M[r]);
      float p1 = __expf(l1 - M[r]);
      p0 = ((mw[r] >> sh0) & 1ull) ? p0 : 0.f;
      p1 = ((mw[r] >> (sh0+1)) & 1ull) ? p1 : 0.f;
      sum[r] += p0 + p1;
      pos[r][0] += p0*s0.x + p1*s0.y;
      pos[r][1] += p0*s1.x + p1*s1.y;
      pos[r][2] += p0*s2.x + p1*s2.y;
      pos[r][3] += p0*s3.x + p1*s3.y;
      pos[r][4] += p0*s4.x + p1*s4.y;
      pos[r][5] += p0*s5.x + p1*s5.y;
      pos[r][6] += p0*s6.x + p1*s6.y;
      pos[r][7] += p0*s7.x + p1*s7.y;
    }
  }

  // butterfly reduce all 72 accumulators across the wave
  #pragma unroll
  for (int s = 1; s < 64; s <<= 1){
    #pragma unroll
    for (int r = 0; r < 8; ++r){
      sum[r] += __shfl_xor(sum[r], s, 64);
      #pragma unroll
      for (int o = 0; o < 8; ++o) pos[r][o] += __shfl_xor(pos[r][o], s, 64);
    }
  }

  // lane (r*8+o) stores pos[r][o]/sum[r]  (static-index selection, rule #20)
  int lr = lane >> 3, lo = lane & 7;
  float sv = sum[0];
  #pragma unroll
  for (int r = 1; r < 8; ++r) sv = (lr == r) ? sum[r] : sv;
  float val = pos[0][0];
  #pragma unroll
  for (int r = 0; r < 8; ++r)
    #pragma unroll
    for (int o = 0; o < 8; ++o)
      if (r + o) val = (lane == r*8+o) ? pos[r][o] : val;
  float inv = 1.f / fmaxf(sv, 1e-10f);
  posg[(size_t)(i0 + lr)*64 + h*8 + lo] = val * inv;
}

// ---------------- K4: residual proj + the two MLP channels + PairNorm partials ----------------
__global__ __launch_bounds__(256) void k4_mix(
    const float* __restrict__ h, const float* __restrict__ posg,
    const float* __restrict__ gat_bias, const float* __restrict__ proj_b,
    const float* __restrict__ wtproj, const float* __restrict__ wtself,
    const float* __restrict__ wtpos,
    const float* __restrict__ mlp_self_b, const float* __restrict__ mlp_pos_b,
    float* __restrict__ s0, float* __restrict__ s1, float* __restrict__ part)
{
  int tid = threadIdx.x;
  int wave = tid >> 6, lane = tid & 63;
  int n = blockIdx.x*4 + wave;
  float hreg = h[n*64 + lane];
  float pr = proj_b[lane];
  float se = mlp_self_b[lane];
  #pragma unroll
  for (int k = 0; k < 64; ++k){
    float hk = __shfl(hreg, k, 64);
    pr += hk * wtproj[k*64 + lane];
    se += hk * wtself[k*64 + lane];
  }
  float posf = posg[n*64 + lane] + gat_bias[lane] + pr;
  float s1v = mlp_pos_b[lane];
  #pragma unroll
  for (int k = 0; k < 64; ++k){
    float pk = __shfl(posf, k, 64);
    s1v += pk * wtpos[k*64 + lane];
  }
  s0[n*64+lane] = se;
  s1[n*64+lane] = s1v;

  __shared__ float sb0[4][64];
  __shared__ float sb1[4][64];
  __shared__ float sq[4];
  sb0[wave][lane] = se;
  sb1[wave][lane] = s1v;
  float q = se*se + s1v*s1v;
  #pragma unroll
  for (int s = 1; s < 64; s <<= 1) q += __shfl_xor(q, s, 64);
  if (lane == 0) sq[wave] = q;
  __syncthreads();
  if (tid < 64){
    part[blockIdx.x*130 + tid] = sb0[0][tid]+sb0[1][tid]+sb0[2][tid]+sb0[3][tid];
  } else if (tid < 128){
    int d = tid - 64;
    part[blockIdx.x*130 + 64 + d] = sb1[0][d]+sb1[1][d]+sb1[2][d]+sb1[3][d];
  } else if (tid == 128){
    part[blockIdx.x*130 + 128] = sq[0]+sq[1]+sq[2]+sq[3];
  }
}

// ---------------- K5: PairNorm stats (1024-thread two-stage reduce) ----------------
__global__ __launch_bounds__(1024) void k5_stats(const float* __restrict__ part, float* __restrict__ stats)
{
  int tid = threadIdx.x;
  __shared__ float s_mu[8][128];
  __shared__ float s_sq[8];
  int c = tid & 127, ch = tid >> 7;
  float a = 0.f;
  for (int b = ch*128; b < ch*128+128; ++b) a += part[b*130 + c];
  s_mu[ch][c] = a;
  if (tid < 8){
    float q = 0.f;
    for (int b = tid*128; b < tid*128+128; ++b) q += part[b*130 + 128];
    s_sq[tid] = q;
  }
  __syncthreads();
  if (tid < 128){
    float m = 0.f;
    #pragma unroll
    for (int j = 0; j < 8; ++j) m += s_mu[j][tid];
    s_mu[0][tid] = m;
    stats[tid] = m / 4096.f;
  }
  __syncthreads();
  if (tid == 0){
    float sq = 0.f;
    #pragma unroll
    for (int j = 0; j < 8; ++j) sq += s_sq[j];
    float mu2 = 0.f;
    for (int i = 0; i < 128; ++i){ float m = s_mu[0][i] / 4096.f; mu2 += m*m; }
    float msq = sq/(4096.f*64.f) - mu2/64.f;
    stats[128] = 1.f / sqrtf(1e-6f + msq);
  }
}

// ---------------- K6: semantic attention + predictor ----------------
__global__ __launch_bounds__(256) void k6_sem(
    const float* __restrict__ s0, const float* __restrict__ s1,
    const float* __restrict__ stats, const float* __restrict__ wtsem,
    const float* __restrict__ sem_b1, const float* __restrict__ sem_w2,
    const float* __restrict__ pred_w, const float* __restrict__ pred_b,
    float* __restrict__ out)
{
  int tid = threadIdx.x;
  int wave = tid >> 6, lane = tid & 63;
  int n = blockIdx.x*4 + wave;
  float rinv = stats[128];
  float a0 = (s0[n*64+lane] - stats[lane]) * rinv;
  float a1 = (s1[n*64+lane] - stats[64+lane]) * rinv;
  float t0 = sem_b1[lane], t1 = t0;
  #pragma unroll
  for (int k = 0; k < 64; ++k){
    float w = wtsem[k*64 + lane];
    t0 += __shfl(a0, k, 64) * w;
    t1 += __shfl(a1, k, 64) * w;
  }
  t0 = tanh_fast(t0); t1 = tanh_fast(t1);
  float w2 = sem_w2[lane];
  float w0 = t0*w2, w1 = t1*w2;
  #pragma unroll
  for (int s = 1; s < 64; s <<= 1){
    w0 += __shfl_xor(w0, s, 64);
    w1 += __shfl_xor(w1, s, 64);
  }
  float mx = fmaxf(w0, w1);
  float e0 = __expf(w0 - mx), e1 = __expf(w1 - mx);
  float denom = e0 + e1 + 1e-10f;
  float b0 = e0/denom, b1 = e1/denom;
  float emb = b0*a0 + b1*a1;
  float pl = emb * pred_w[lane];
  #pragma unroll
  for (int s = 1; s < 64; s <<= 1) pl += __shfl_xor(pl, s, 64);
  if (lane == 0) out[n] = sigm(pl + pred_b[0]);
}

extern "C" void kernel_launch(void* const* d_in, const int* in_sizes, int n_in,
                              void* d_out, int out_size, void* d_ws, size_t ws_size,
                              hipStream_t stream)
{
  (void)in_sizes; (void)n_in; (void)out_size; (void)ws_size;
  const float* x         = (const float*)d_in[0];
  const int*   adj       = (const int*)d_in[1];
  const float* W_ih      = (const float*)d_in[2];
  const float* W_hh      = (const float*)d_in[3];
  const float* b_ih      = (const float*)d_in[4];
  const float* b_hh      = (const float*)d_in[5];
  const float* gat_w     = (const float*)d_in[6];
  const float* gat_wu    = (const float*)d_in[7];
  const float* gat_wv    = (const float*)d_in[8];
  const float* gat_bias  = (const float*)d_in[9];
  const float* proj_w    = (const float*)d_in[10];
  const float* proj_b    = (const float*)d_in[11];
  const float* mlp_self_w= (const float*)d_in[12];
  const float* mlp_self_b= (const float*)d_in[13];
  const float* mlp_pos_w = (const float*)d_in[14];
  const float* mlp_pos_b = (const float*)d_in[15];
  const float* sem_w1    = (const float*)d_in[16];
  const float* sem_b1    = (const float*)d_in[17];
  const float* sem_w2    = (const float*)d_in[18];
  const float* pred_w    = (const float*)d_in[19];
  const float* pred_b    = (const float*)d_in[20];
  float* out = (float*)d_out;
  float* ws  = (float*)d_ws;

  float* h     = ws + 0;         // 262144
  float* supt  = ws + 262144;    // 262144  [64][4096]
  float* f1t   = ws + 524288;    // 32768   [8][4096]
  float* f2    = ws + 557056;    // 32768   [4096][8]
  float* posg  = ws + 589824;    // 262144
  float* s0    = ws + 851968;    // 262144
  float* s1    = ws + 1114112;   // 262144
  // adjm overlays s0+s1 (2MB): written by k2c, consumed by k3, dead before k4 writes s0/s1
  unsigned long long* adjm = (unsigned long long*)(ws + 851968);
  float* part  = ws + 1376256;   // 1024*130
  float* bmax  = ws + 1509376;   // 1024*8
  float* maxf1 = ws + 1517568;   // 8
  float* stats = ws + 1517576;   // 129
  float* wtproj= ws + 1517712;   // 4096
  float* wtself= wtproj + 4096;
  float* wtpos = wtself + 4096;
  float* wtsem = wtpos  + 4096;

  k0_prep<<<16, 256, 0, stream>>>(proj_w, mlp_self_w, mlp_pos_w, sem_w1,
                                  wtproj, wtself, wtpos, wtsem);
  k1_gru<<<256, 256, 0, stream>>>(x, W_ih, W_hh, b_ih, b_hh, h);
  k2_sup<<<1024, 256, 0, stream>>>(h, gat_w, gat_wu, gat_wv, supt, f1t, f2, bmax);
  k2b_max<<<1, 256, 0, stream>>>(bmax, maxf1);
  k2c_pack<<<1024, 256, 0, stream>>>(adj, adjm);
  k3_gat<<<1024, 256, 0, stream>>>(adjm, supt, f1t, f2, maxf1, posg);
  k4_mix<<<1024, 256, 0, stream>>>(h, posg, gat_bias, proj_b, wtproj, wtself, wtpos,
                                   mlp_self_b, mlp_pos_b, s0, s1, part);
  k5_stats<<<1, 1024, 0, stream>>>(part, stats);
  k6_sem<<<1024, 256, 0, stream>>>(s0, s1, stats, wtsem, sem_b1, sem_w2, pred_w, pred_b, out);
}

// Round 8
// 349.877 us; speedup vs baseline: 1.5350x; 1.5350x over previous
//
#include <hip/hip_runtime.h>
#include <math.h>

#define NN 4096
#define TT 32
#define FF 7
#define HH 64
#define NHEAD 8
#define DOUT 8

__device__ __forceinline__ float sigm(float x){
  x = fminf(fmaxf(x, -30.f), 30.f);
  return 1.f / (1.f + __expf(-x));
}
__device__ __forceinline__ float tanh_fast(float x){
  x = fminf(fmaxf(x, -15.f), 15.f);
  float e = __expf(2.f*x);
  return (e - 1.f) / (e + 1.f);
}

// ---------------- K0: transpose small 64x64 weights to k-major ----------------
__global__ void k0_prep(const float* __restrict__ pw, const float* __restrict__ msw,
                        const float* __restrict__ mpw, const float* __restrict__ sw1,
                        float* __restrict__ wtproj, float* __restrict__ wtself,
                        float* __restrict__ wtpos, float* __restrict__ wtsem)
{
  int tid = threadIdx.x + blockIdx.x*blockDim.x;
  if (tid < 4096){
    int d = tid >> 6, k = tid & 63;
    wtproj[k*64+d] = pw[tid];
    wtself[k*64+d] = msw[tid];
    wtpos[k*64+d]  = mpw[tid];
    wtsem[k*64+d]  = sw1[tid];
  }
}

// ---------------- K1: GRU encoder ----------------
// 512 blocks x 256 threads; wave owns 2 nodes; lane l owns gate rows {l,l+64,l+128}.
// W_hh in LDS (XOR-swizzled b128 reads); h broadcast via wave-private s_h rows.
// 57KB LDS -> 2 blocks/CU -> 2 waves/SIMD (the round-6 version was grid-limited
// to 1 wave/SIMD: zero latency overlap was the 153us cost).
__global__ __launch_bounds__(256) void k1_gru(
    const float* __restrict__ x,      // [N][T][F]
    const float* __restrict__ Wih,    // [192][7]
    const float* __restrict__ Whh,    // [192][64]
    const float* __restrict__ bih, const float* __restrict__ bhh,
    float* __restrict__ hout)         // [N][64]
{
  __shared__ float s_whh[192*64];     // swizzled, 48KB
  __shared__ float s_h[8][64];        // 2KB
  __shared__ float s_x[4][448];       // per-wave x staging (2 nodes x 32 t x 7 f), 7KB

  int tid = threadIdx.x;
  int lane = tid & 63, wave = tid >> 6;

  for (int i = tid; i < 192*64; i += 256){
    int g = i >> 6, k = i & 63;
    s_whh[g*64 + (k ^ ((g & 7) << 2))] = Whh[i];
  }

  float wr_[7], wz_[7], wn_[7];
  #pragma unroll
  for (int f = 0; f < 7; ++f){
    wr_[f] = Wih[lane*7 + f];
    wz_[f] = Wih[(lane+64)*7 + f];
    wn_[f] = Wih[(lane+128)*7 + f];
  }
  float bir = bih[lane], biz = bih[lane+64], bin_ = bih[lane+128];
  float bhr = bhh[lane], bhz = bhh[lane+64], bhn = bhh[lane+128];

  int nb = blockIdx.x*8 + wave*2;     // first node of this wave
  #pragma unroll
  for (int n = 0; n < 2; ++n){
    s_h[wave*2+n][lane] = 0.f;
    for (int i = lane; i < 224; i += 64)
      s_x[wave][n*224 + i] = x[(size_t)(nb+n)*224 + i];
  }
  float hreg[2] = {0.f, 0.f};
  __syncthreads();                    // only barrier: s_whh staging

  int sw = (lane & 7) << 2;           // word swizzle for this lane's rows
  const float* rowr = s_whh + lane*64;
  const float* rowz = s_whh + (lane+64)*64;
  const float* rown = s_whh + (lane+128)*64;

  for (int tt = 0; tt < TT; ++tt){
    float accr[2] = {0.f,0.f};
    float accz[2] = {0.f,0.f};
    float accn[2] = {0.f,0.f};
    #pragma unroll
    for (int k4 = 0; k4 < 16; ++k4){
      int off = (k4*4) ^ sw;
      float4 w4r = *(const float4*)(rowr + off);
      float4 w4z = *(const float4*)(rowz + off);
      float4 w4n = *(const float4*)(rown + off);
      #pragma unroll
      for (int n = 0; n < 2; ++n){
        float4 h4 = *(const float4*)&s_h[wave*2+n][k4*4];   // uniform-addr broadcast
        accr[n] += w4r.x*h4.x + w4r.y*h4.y + w4r.z*h4.z + w4r.w*h4.w;
        accz[n] += w4z.x*h4.x + w4z.y*h4.y + w4z.z*h4.z + w4z.w*h4.w;
        accn[n] += w4n.x*h4.x + w4n.y*h4.y + w4n.z*h4.z + w4n.w*h4.w;
      }
    }
    #pragma unroll
    for (int n = 0; n < 2; ++n){
      const float* xp = &s_x[wave][n*224 + tt*7];
      float gr = bir, gz = biz, gn = bin_;
      #pragma unroll
      for (int f = 0; f < 7; ++f){
        float xv = xp[f];
        gr += wr_[f]*xv; gz += wz_[f]*xv; gn += wn_[f]*xv;
      }
      float rr = sigm(gr + bhr + accr[n]);
      float zz = sigm(gz + bhz + accz[n]);
      float nn = tanh_fast(gn + rr*(bhn + accn[n]));
      float hn = (1.f - zz)*nn + zz*hreg[n];
      hreg[n] = hn;
      s_h[wave*2+n][lane] = hn;       // wave-private row: no barrier needed
    }
  }
  #pragma unroll
  for (int n = 0; n < 2; ++n)
    hout[(size_t)(nb+n)*64 + lane] = hreg[n];
}

// ---------------- K2: sup (transposed) = h@gat_w, f1t/f2 head scalars, block f1 max ----------------
__global__ __launch_bounds__(256) void k2_sup(
    const float* __restrict__ h, const float* __restrict__ gat_w,
    const float* __restrict__ wu, const float* __restrict__ wv,
    float* __restrict__ supt,    // [64][N]  row = hh*8+o
    float* __restrict__ f1t,     // [8][N]
    float* __restrict__ f2,      // [N][8]
    float* __restrict__ bmax)
{
  int tid = threadIdx.x;
  int wave = tid >> 6, lane = tid & 63;
  int n = blockIdx.x*4 + wave;
  float hreg = h[n*64 + lane];
  float acc = 0.f;
  #pragma unroll
  for (int k = 0; k < 64; ++k){
    float hk = __shfl(hreg, k, 64);
    acc += hk * gat_w[k*64 + lane];
  }
  supt[(size_t)lane*NN + n] = acc;     // transposed write (j-major per head-out row)
  float p1 = acc * wu[lane];
  float p2 = acc * wv[lane];
  #pragma unroll
  for (int s = 1; s < 8; s <<= 1){
    p1 += __shfl_xor(p1, s, 64);
    p2 += __shfl_xor(p2, s, 64);
  }
  int hh = lane >> 3;
  __shared__ float s_m[4][8];
  if ((lane & 7) == 0){
    f1t[(size_t)hh*NN + n] = p1;
    f2[n*8 + hh] = p2;
    s_m[wave][hh] = p1;
  }
  __syncthreads();
  if (tid < 8){
    float mm = fmaxf(fmaxf(s_m[0][tid], s_m[1][tid]), fmaxf(s_m[2][tid], s_m[3][tid]));
    bmax[blockIdx.x*8 + tid] = mm;
  }
}

__global__ __launch_bounds__(256) void k2b_max(const float* __restrict__ bmax, float* __restrict__ maxf1)
{
  int tid = threadIdx.x;
  int hh = tid & 7, chunk = tid >> 3;   // 32 chunks of 32 blocks
  float m = -1e30f;
  for (int b = chunk*32; b < chunk*32+32; ++b) m = fmaxf(m, bmax[b*8 + hh]);
  __shared__ float sm[256];
  sm[tid] = m;
  __syncthreads();
  if (tid < 8){
    float mm = -1e30f;
    for (int c = 0; c < 32; ++c) mm = fmaxf(mm, sm[c*8 + tid]);
    maxf1[tid] = mm;
  }
}

// ---------------- K2c: pack adjacency rows into 64-bit masks ----------------
__global__ __launch_bounds__(256) void k2c_pack(const int* __restrict__ adj,
                                               unsigned long long* __restrict__ adjm)
{
  int lane = threadIdx.x & 63, wave = threadIdx.x >> 6;
  int row = blockIdx.x*4 + wave;
  const int* ap = adj + (size_t)row*NN;
  #pragma unroll 8
  for (int s = 0; s < 64; ++s){
    unsigned long long m = __ballot(ap[s*64 + lane] != 0);
    if (lane == 0) adjm[(size_t)row*64 + s] = m;
  }
}

// ---------------- K3: masked-softmax GAT, one wave per (8 rows, 1 head) ----------------
__global__ __launch_bounds__(256) void k3_gat(
    const unsigned long long* __restrict__ adjm,   // [N][64]
    const float* __restrict__ supt,                // [64][N]
    const float* __restrict__ f1t,                 // [8][N]
    const float* __restrict__ f2,                  // [N][8]
    const float* __restrict__ maxf1, float* __restrict__ posg)
{
  int tid = threadIdx.x;
  int lane = tid & 63, wave = tid >> 6;
  int gid = blockIdx.x*4 + wave;        // 0..4095
  int ib = gid >> 3, h = gid & 7;
  int i0 = ib*8;

  float mf = maxf1[h];
  float f2v[8], M[8];
  #pragma unroll
  for (int r = 0; r < 8; ++r){
    f2v[r] = f2[(size_t)(i0+r)*8 + h];
    float lg = mf + f2v[r];
    lg = fmaxf(lg, 0.2f*lg);
    M[r] = fmaxf(lg, 0.f);              // upper bound on reference rowmax
  }

  const float2* f1p = (const float2*)(f1t + (size_t)h*NN);
  const float2* sp0 = (const float2*)(supt + (size_t)(h*8+0)*NN);
  const float2* sp1 = (const float2*)(supt + (size_t)(h*8+1)*NN);
  const float2* sp2 = (const float2*)(supt + (size_t)(h*8+2)*NN);
  const float2* sp3 = (const float2*)(supt + (size_t)(h*8+3)*NN);
  const float2* sp4 = (const float2*)(supt + (size_t)(h*8+4)*NN);
  const float2* sp5 = (const float2*)(supt + (size_t)(h*8+5)*NN);
  const float2* sp6 = (const float2*)(supt + (size_t)(h*8+6)*NN);
  const float2* sp7 = (const float2*)(supt + (size_t)(h*8+7)*NN);
  const unsigned long long* mbase = adjm + (size_t)i0*64;

  int sh0 = (lane*2) & 63;              // bit position of this lane's first j
  int woff = (lane >> 5);               // which of the 2 words this iter

  float sum[8] = {0.f,0.f,0.f,0.f,0.f,0.f,0.f,0.f};
  float pos[8][8];
  #pragma unroll
  for (int r = 0; r < 8; ++r)
    #pragma unroll
    for (int o = 0; o < 8; ++o) pos[r][o] = 0.f;

  for (int b = 0; b < 32; ++b){         // 128 j per iter (2 j per lane)
    int idx = b*64 + lane;
    float2 f1v = f1p[idx];
    float2 s0 = sp0[idx], s1 = sp1[idx], s2 = sp2[idx], s3 = sp3[idx];
    float2 s4 = sp4[idx], s5 = sp5[idx], s6 = sp6[idx], s7 = sp7[idx];
    int w = b*2 + woff;
    unsigned long long mw[8];
    #pragma unroll
    for (int r = 0; r < 8; ++r) mw[r] = mbase[r*64 + w];

    #pragma unroll
    for (int r = 0; r < 8; ++r){
      float l0 = f1v.x + f2v[r];
      float l1 = f1v.y + f2v[r];
      l0 = fmaxf(l0, 0.2f*l0);
      l1 = fmaxf(l1, 0.2f*l1);
      float p0 = __expf(l0 - M[r]);
      float p1 = __expf(l1 - M[r]);
      p0 = ((mw[r] >> sh0) & 1ull) ? p0 : 0.f;
      p1 = ((mw[r] >> (sh0+1)) & 1ull) ? p1 : 0.f;
      sum[r] += p0 + p1;
      pos[r][0] += p0*s0.x + p1*s0.y;
      pos[r][1] += p0*s1.x + p1*s1.y;
      pos[r][2] += p0*s2.x + p1*s2.y;
      pos[r][3] += p0*s3.x + p1*s3.y;
      pos[r][4] += p0*s4.x + p1*s4.y;
      pos[r][5] += p0*s5.x + p1*s5.y;
      pos[r][6] += p0*s6.x + p1*s6.y;
      pos[r][7] += p0*s7.x + p1*s7.y;
    }
  }

  // butterfly reduce all 72 accumulators across the wave
  #pragma unroll
  for (int s = 1; s < 64; s <<= 1){
    #pragma unroll
    for (int r = 0; r < 8; ++r){
      sum[r] += __shfl_xor(sum[r], s, 64);
      #pragma unroll
      for (int o = 0; o < 8; ++o) pos[r][o] += __shfl_xor(pos[r][o], s, 64);
    }
  }

  // lane (r*8+o) stores pos[r][o]/sum[r]  (static-index selection, rule #20)
  int lr = lane >> 3, lo = lane & 7;
  float sv = sum[0];
  #pragma unroll
  for (int r = 1; r < 8; ++r) sv = (lr == r) ? sum[r] : sv;
  float val = pos[0][0];
  #pragma unroll
  for (int r = 0; r < 8; ++r)
    #pragma unroll
    for (int o = 0; o < 8; ++o)
      if (r + o) val = (lane == r*8+o) ? pos[r][o] : val;
  float inv = 1.f / fmaxf(sv, 1e-10f);
  posg[(size_t)(i0 + lr)*64 + h*8 + lo] = val * inv;
}

// ---------------- K4: residual proj + the two MLP channels + PairNorm partials ----------------
__global__ __launch_bounds__(256) void k4_mix(
    const float* __restrict__ h, const float* __restrict__ posg,
    const float* __restrict__ gat_bias, const float* __restrict__ proj_b,
    const float* __restrict__ wtproj, const float* __restrict__ wtself,
    const float* __restrict__ wtpos,
    const float* __restrict__ mlp_self_b, const float* __restrict__ mlp_pos_b,
    float* __restrict__ s0, float* __restrict__ s1, float* __restrict__ part)
{
  int tid = threadIdx.x;
  int wave = tid >> 6, lane = tid & 63;
  int n = blockIdx.x*4 + wave;
  float hreg = h[n*64 + lane];
  float pr = proj_b[lane];
  float se = mlp_self_b[lane];
  #pragma unroll
  for (int k = 0; k < 64; ++k){
    float hk = __shfl(hreg, k, 64);
    pr += hk * wtproj[k*64 + lane];
    se += hk * wtself[k*64 + lane];
  }
  float posf = posg[n*64 + lane] + gat_bias[lane] + pr;
  float s1v = mlp_pos_b[lane];
  #pragma unroll
  for (int k = 0; k < 64; ++k){
    float pk = __shfl(posf, k, 64);
    s1v += pk * wtpos[k*64 + lane];
  }
  s0[n*64+lane] = se;
  s1[n*64+lane] = s1v;

  __shared__ float sb0[4][64];
  __shared__ float sb1[4][64];
  __shared__ float sq[4];
  sb0[wave][lane] = se;
  sb1[wave][lane] = s1v;
  float q = se*se + s1v*s1v;
  #pragma unroll
  for (int s = 1; s < 64; s <<= 1) q += __shfl_xor(q, s, 64);
  if (lane == 0) sq[wave] = q;
  __syncthreads();
  if (tid < 64){
    part[blockIdx.x*130 + tid] = sb0[0][tid]+sb0[1][tid]+sb0[2][tid]+sb0[3][tid];
  } else if (tid < 128){
    int d = tid - 64;
    part[blockIdx.x*130 + 64 + d] = sb1[0][d]+sb1[1][d]+sb1[2][d]+sb1[3][d];
  } else if (tid == 128){
    part[blockIdx.x*130 + 128] = sq[0]+sq[1]+sq[2]+sq[3];
  }
}

// ---------------- K5: PairNorm stats (1024-thread two-stage reduce) ----------------
__global__ __launch_bounds__(1024) void k5_stats(const float* __restrict__ part, float* __restrict__ stats)
{
  int tid = threadIdx.x;
  __shared__ float s_mu[8][128];
  __shared__ float s_sq[8];
  int c = tid & 127, ch = tid >> 7;
  float a = 0.f;
  for (int b = ch*128; b < ch*128+128; ++b) a += part[b*130 + c];
  s_mu[ch][c] = a;
  if (tid < 8){
    float q = 0.f;
    for (int b = tid*128; b < tid*128+128; ++b) q += part[b*130 + 128];
    s_sq[tid] = q;
  }
  __syncthreads();
  if (tid < 128){
    float m = 0.f;
    #pragma unroll
    for (int j = 0; j < 8; ++j) m += s_mu[j][tid];
    s_mu[0][tid] = m;
    stats[tid] = m / 4096.f;
  }
  __syncthreads();
  if (tid == 0){
    float sq = 0.f;
    #pragma unroll
    for (int j = 0; j < 8; ++j) sq += s_sq[j];
    float mu2 = 0.f;
    for (int i = 0; i < 128; ++i){ float m = s_mu[0][i] / 4096.f; mu2 += m*m; }
    float msq = sq/(4096.f*64.f) - mu2/64.f;
    stats[128] = 1.f / sqrtf(1e-6f + msq);
  }
}

// ---------------- K6: semantic attention + predictor ----------------
__global__ __launch_bounds__(256) void k6_sem(
    const float* __restrict__ s0, const float* __restrict__ s1,
    const float* __restrict__ stats, const float* __restrict__ wtsem,
    const float* __restrict__ sem_b1, const float* __restrict__ sem_w2,
    const float* __restrict__ pred_w, const float* __restrict__ pred_b,
    float* __restrict__ out)
{
  int tid = threadIdx.x;
  int wave = tid >> 6, lane = tid & 63;
  int n = blockIdx.x*4 + wave;
  float rinv = stats[128];
  float a0 = (s0[n*64+lane] - stats[lane]) * rinv;
  float a1 = (s1[n*64+lane] - stats[64+lane]) * rinv;
  float t0 = sem_b1[lane], t1 = t0;
  #pragma unroll
  for (int k = 0; k < 64; ++k){
    float w = wtsem[k*64 + lane];
    t0 += __shfl(a0, k, 64) * w;
    t1 += __shfl(a1, k, 64) * w;
  }
  t0 = tanh_fast(t0); t1 = tanh_fast(t1);
  float w2 = sem_w2[lane];
  float w0 = t0*w2, w1 = t1*w2;
  #pragma unroll
  for (int s = 1; s < 64; s <<= 1){
    w0 += __shfl_xor(w0, s, 64);
    w1 += __shfl_xor(w1, s, 64);
  }
  float mx = fmaxf(w0, w1);
  float e0 = __expf(w0 - mx), e1 = __expf(w1 - mx);
  float denom = e0 + e1 + 1e-10f;
  float b0 = e0/denom, b1 = e1/denom;
  float emb = b0*a0 + b1*a1;
  float pl = emb * pred_w[lane];
  #pragma unroll
  for (int s = 1; s < 64; s <<= 1) pl += __shfl_xor(pl, s, 64);
  if (lane == 0) out[n] = sigm(pl + pred_b[0]);
}

extern "C" void kernel_launch(void* const* d_in, const int* in_sizes, int n_in,
                              void* d_out, int out_size, void* d_ws, size_t ws_size,
                              hipStream_t stream)
{
  (void)in_sizes; (void)n_in; (void)out_size; (void)ws_size;
  const float* x         = (const float*)d_in[0];
  const int*   adj       = (const int*)d_in[1];
  const float* W_ih      = (const float*)d_in[2];
  const float* W_hh      = (const float*)d_in[3];
  const float* b_ih      = (const float*)d_in[4];
  const float* b_hh      = (const float*)d_in[5];
  const float* gat_w     = (const float*)d_in[6];
  const float* gat_wu    = (const float*)d_in[7];
  const float* gat_wv    = (const float*)d_in[8];
  const float* gat_bias  = (const float*)d_in[9];
  const float* proj_w    = (const float*)d_in[10];
  const float* proj_b    = (const float*)d_in[11];
  const float* mlp_self_w= (const float*)d_in[12];
  const float* mlp_self_b= (const float*)d_in[13];
  const float* mlp_pos_w = (const float*)d_in[14];
  const float* mlp_pos_b = (const float*)d_in[15];
  const float* sem_w1    = (const float*)d_in[16];
  const float* sem_b1    = (const float*)d_in[17];
  const float* sem_w2    = (const float*)d_in[18];
  const float* pred_w    = (const float*)d_in[19];
  const float* pred_b    = (const float*)d_in[20];
  float* out = (float*)d_out;
  float* ws  = (float*)d_ws;

  float* h     = ws + 0;         // 262144
  float* supt  = ws + 262144;    // 262144  [64][4096]
  float* f1t   = ws + 524288;    // 32768   [8][4096]
  float* f2    = ws + 557056;    // 32768   [4096][8]
  float* posg  = ws + 589824;    // 262144
  float* s0    = ws + 851968;    // 262144
  float* s1    = ws + 1114112;   // 262144
  // adjm overlays s0+s1 (2MB): written by k2c, consumed by k3, dead before k4 writes s0/s1
  unsigned long long* adjm = (unsigned long long*)(ws + 851968);
  float* part  = ws + 1376256;   // 1024*130
  float* bmax  = ws + 1509376;   // 1024*8
  float* maxf1 = ws + 1517568;   // 8
  float* stats = ws + 1517576;   // 129
  float* wtproj= ws + 1517712;   // 4096
  float* wtself= wtproj + 4096;
  float* wtpos = wtself + 4096;
  float* wtsem = wtpos  + 4096;

  k0_prep<<<16, 256, 0, stream>>>(proj_w, mlp_self_w, mlp_pos_w, sem_w1,
                                  wtproj, wtself, wtpos, wtsem);
  k1_gru<<<512, 256, 0, stream>>>(x, W_ih, W_hh, b_ih, b_hh, h);
  k2_sup<<<1024, 256, 0, stream>>>(h, gat_w, gat_wu, gat_wv, supt, f1t, f2, bmax);
  k2b_max<<<1, 256, 0, stream>>>(bmax, maxf1);
  k2c_pack<<<1024, 256, 0, stream>>>(adj, adjm);
  k3_gat<<<1024, 256, 0, stream>>>(adjm, supt, f1t, f2, maxf1, posg);
  k4_mix<<<1024, 256, 0, stream>>>(h, posg, gat_bias, proj_b, wtproj, wtself, wtpos,
                                   mlp_self_b, mlp_pos_b, s0, s1, part);
  k5_stats<<<1, 1024, 0, stream>>>(part, stats);
  k6_sem<<<1024, 256, 0, stream>>>(s0, s1, stats, wtsem, sem_b1, sem_w2, pred_w, pred_b, out);
}

// Round 10
// 300.875 us; speedup vs baseline: 1.7850x; 1.1629x over previous
//
#include <hip/hip_runtime.h>
#include <math.h>

#define NN 4096
#define TT 32
#define FF 7
#define HH 64
#define NHEAD 8
#define DOUT 8

typedef short bf16x8 __attribute__((ext_vector_type(8)));
typedef float f32x4 __attribute__((ext_vector_type(4)));

__device__ __forceinline__ float sigm(float x){
  x = fminf(fmaxf(x, -30.f), 30.f);
  return 1.f / (1.f + __expf(-x));
}
__device__ __forceinline__ float tanh_fast(float x){
  x = fminf(fmaxf(x, -15.f), 15.f);
  float e = __expf(2.f*x);
  return (e - 1.f) / (e + 1.f);
}
__device__ __forceinline__ unsigned short bf16rne(float f){
  unsigned u = __float_as_uint(f);
  u += 0x7fffu + ((u >> 16) & 1u);
  return (unsigned short)(u >> 16);
}
__device__ __forceinline__ unsigned bfpack2(float a, float b){
  return (unsigned)bf16rne(a) | ((unsigned)bf16rne(b) << 16);
}

// ---------------- K0: transpose small 64x64 weights to k-major ----------------
__global__ void k0_prep(const float* __restrict__ pw, const float* __restrict__ msw,
                        const float* __restrict__ mpw, const float* __restrict__ sw1,
                        float* __restrict__ wtproj, float* __restrict__ wtself,
                        float* __restrict__ wtpos, float* __restrict__ wtsem)
{
  int tid = threadIdx.x + blockIdx.x*blockDim.x;
  if (tid < 4096){
    int d = tid >> 6, k = tid & 63;
    wtproj[k*64+d] = pw[tid];
    wtself[k*64+d] = msw[tid];
    wtpos[k*64+d]  = mpw[tid];
    wtsem[k*64+d]  = sw1[tid];
  }
}

// ---------------- K1: GRU encoder via MFMA (bf16 inputs, f32 recurrence) ----------------
// 256 blocks x 1 wave; wave owns 16 nodes. Per t: gh[192x16] = W_hh[192x64]@h[64x16]
// as 12 gate-tiles x 2 K-chunks of mfma_f32_16x16x32_bf16; gx via one K-chunk with
// bias folded at k=7 (B_x k=7 == 1.0). D layout (col=lane&15=node, row=kg*4+reg)
// makes gate math lane-local; h stays f32 in regs; bf16 repack via 2.3KB LDS.
// Single wave per block: zero barriers.
// (Round-9 bug: fragment READS were missing the *64+lane stride -- fixed.)
__global__ __launch_bounds__(64) void k1_gru(
    const float* __restrict__ x,      // [N][T][F]
    const float* __restrict__ Wih,    // [192][7]
    const float* __restrict__ Whh,    // [192][64]
    const float* __restrict__ bih, const float* __restrict__ bhh,
    float* __restrict__ hout)         // [N][64]
{
  __shared__ uint4 s_whhf[24*64];                 // 24KB  [T(12)][c(2)] A-frag lines
  __shared__ uint4 s_wihf[12*64];                 // 12KB  [T(12)] A-frag lines
  __shared__ __align__(16) short s_xb[32][16][8]; // 8KB   bf16 x (k=7 -> 1.0)
  __shared__ __align__(16) short s_hb[16][72];    // 2.25KB bf16 h (pad 72)

  int lane = threadIdx.x;
  int nb = blockIdx.x * 16;
  int row = lane & 15;          // A: gate row within tile / B,D: node column
  int kg  = lane >> 4;          // k-group (8 elements each)

  // ---- stage W_hh A-fragments (bf16) ----
  #pragma unroll
  for (int T = 0; T < 12; ++T){
    #pragma unroll
    for (int c = 0; c < 2; ++c){
      int g = T*16 + row;
      const float* wp = Whh + g*64 + c*32 + kg*8;
      uint4 v;
      v.x = bfpack2(wp[0], wp[1]);
      v.y = bfpack2(wp[2], wp[3]);
      v.z = bfpack2(wp[4], wp[5]);
      v.w = bfpack2(wp[6], wp[7]);
      s_whhf[(T*2 + c)*64 + lane] = v;
    }
  }
  // ---- stage W_ih A-fragments: k<7 weights, k==7 folded bias, k>=8 zero ----
  #pragma unroll
  for (int T = 0; T < 12; ++T){
    int g = T*16 + row;
    float bias = (T < 8) ? (bih[g] + bhh[g]) : bih[g];   // b_hhn NOT folded (inside r*())
    float f[8];
    #pragma unroll
    for (int j = 0; j < 8; ++j){
      int k = kg*8 + j;
      f[j] = (k < 7) ? Wih[g*7 + k] : ((k == 7) ? bias : 0.f);
    }
    uint4 v;
    v.x = bfpack2(f[0], f[1]); v.y = bfpack2(f[2], f[3]);
    v.z = bfpack2(f[4], f[5]); v.w = bfpack2(f[6], f[7]);
    s_wihf[T*64 + lane] = v;
  }
  // ---- stage x as bf16 B-lines (k==7 -> 1.0) ----
  for (int s = lane; s < 4096; s += 64){
    int t = s >> 7, node = (s >> 3) & 15, k = s & 7;
    float v = (k < 7) ? x[(size_t)(nb + node)*224 + t*7 + k] : ((k == 7) ? 1.f : 0.f);
    s_xb[t][node][k] = (short)bf16rne(v);
  }
  // ---- zero h buffer (t=0 reads h=0) ----
  for (int i = lane; i < 576; i += 64) ((unsigned*)s_hb)[i] = 0u;

  float bhn_[4][4];
  #pragma unroll
  for (int T = 0; T < 4; ++T)
    #pragma unroll
    for (int j = 0; j < 4; ++j)
      bhn_[T][j] = bhh[128 + T*16 + kg*4 + j];

  float hreg[4][4];
  #pragma unroll
  for (int T = 0; T < 4; ++T)
    #pragma unroll
    for (int j = 0; j < 4; ++j) hreg[T][j] = 0.f;

  const bf16x8* whhf = (const bf16x8*)s_whhf;
  const bf16x8* wihf = (const bf16x8*)s_wihf;
  f32x4 z4 = {0.f, 0.f, 0.f, 0.f};

  for (int t = 0; t < TT; ++t){
    bf16x8 bx = {0,0,0,0,0,0,0,0};
    if (lane < 16) bx = *(const bf16x8*)&s_xb[t][row][0];  // kg==0 lanes carry k 0..7
    bf16x8 bh0 = *(const bf16x8*)&s_hb[row][kg*8];
    bf16x8 bh1 = *(const bf16x8*)&s_hb[row][32 + kg*8];

    #pragma unroll
    for (int Tr = 0; Tr < 4; ++Tr){
      f32x4 aR = __builtin_amdgcn_mfma_f32_16x16x32_bf16(wihf[Tr*64 + lane], bx, z4, 0, 0, 0);
      aR = __builtin_amdgcn_mfma_f32_16x16x32_bf16(whhf[(Tr*2+0)*64 + lane], bh0, aR, 0, 0, 0);
      aR = __builtin_amdgcn_mfma_f32_16x16x32_bf16(whhf[(Tr*2+1)*64 + lane], bh1, aR, 0, 0, 0);
      f32x4 aZ = __builtin_amdgcn_mfma_f32_16x16x32_bf16(wihf[(4+Tr)*64 + lane], bx, z4, 0, 0, 0);
      aZ = __builtin_amdgcn_mfma_f32_16x16x32_bf16(whhf[((4+Tr)*2+0)*64 + lane], bh0, aZ, 0, 0, 0);
      aZ = __builtin_amdgcn_mfma_f32_16x16x32_bf16(whhf[((4+Tr)*2+1)*64 + lane], bh1, aZ, 0, 0, 0);
      f32x4 aNx = __builtin_amdgcn_mfma_f32_16x16x32_bf16(wihf[(8+Tr)*64 + lane], bx, z4, 0, 0, 0);
      f32x4 aNh = __builtin_amdgcn_mfma_f32_16x16x32_bf16(whhf[((8+Tr)*2+0)*64 + lane], bh0, z4, 0, 0, 0);
      aNh = __builtin_amdgcn_mfma_f32_16x16x32_bf16(whhf[((8+Tr)*2+1)*64 + lane], bh1, aNh, 0, 0, 0);
      #pragma unroll
      for (int j = 0; j < 4; ++j){
        float rr = sigm(aR[j]);
        float zz = sigm(aZ[j]);
        float nn = tanh_fast(aNx[j] + rr*(aNh[j] + bhn_[Tr][j]));
        hreg[Tr][j] = (1.f - zz)*nn + zz*hreg[Tr][j];
      }
    }
    // repack h -> bf16 B-layout for next t (in-wave DS ordering: no barrier)
    #pragma unroll
    for (int Tr = 0; Tr < 4; ++Tr){
      uint2 p;
      p.x = bfpack2(hreg[Tr][0], hreg[Tr][1]);
      p.y = bfpack2(hreg[Tr][2], hreg[Tr][3]);
      *(uint2*)&s_hb[row][Tr*16 + kg*4] = p;
    }
  }

  #pragma unroll
  for (int Tr = 0; Tr < 4; ++Tr)
    #pragma unroll
    for (int j = 0; j < 4; ++j)
      hout[(size_t)(nb + row)*64 + Tr*16 + kg*4 + j] = hreg[Tr][j];
}

// ---------------- K2: sup (transposed) = h@gat_w, f1t/f2 head scalars, block f1 max ----------------
__global__ __launch_bounds__(256) void k2_sup(
    const float* __restrict__ h, const float* __restrict__ gat_w,
    const float* __restrict__ wu, const float* __restrict__ wv,
    float* __restrict__ supt,    // [64][N]  row = hh*8+o
    float* __restrict__ f1t,     // [8][N]
    float* __restrict__ f2,      // [N][8]
    float* __restrict__ bmax)
{
  int tid = threadIdx.x;
  int wave = tid >> 6, lane = tid & 63;
  int n = blockIdx.x*4 + wave;
  float hreg = h[n*64 + lane];
  float acc = 0.f;
  #pragma unroll
  for (int k = 0; k < 64; ++k){
    float hk = __shfl(hreg, k, 64);
    acc += hk * gat_w[k*64 + lane];
  }
  supt[(size_t)lane*NN + n] = acc;     // transposed write (j-major per head-out row)
  float p1 = acc * wu[lane];
  float p2 = acc * wv[lane];
  #pragma unroll
  for (int s = 1; s < 8; s <<= 1){
    p1 += __shfl_xor(p1, s, 64);
    p2 += __shfl_xor(p2, s, 64);
  }
  int hh = lane >> 3;
  __shared__ float s_m[4][8];
  if ((lane & 7) == 0){
    f1t[(size_t)hh*NN + n] = p1;
    f2[n*8 + hh] = p2;
    s_m[wave][hh] = p1;
  }
  __syncthreads();
  if (tid < 8){
    float mm = fmaxf(fmaxf(s_m[0][tid], s_m[1][tid]), fmaxf(s_m[2][tid], s_m[3][tid]));
    bmax[blockIdx.x*8 + tid] = mm;
  }
}

__global__ __launch_bounds__(256) void k2b_max(const float* __restrict__ bmax, float* __restrict__ maxf1)
{
  int tid = threadIdx.x;
  int hh = tid & 7, chunk = tid >> 3;   // 32 chunks of 32 blocks
  float m = -1e30f;
  for (int b = chunk*32; b < chunk*32+32; ++b) m = fmaxf(m, bmax[b*8 + hh]);
  __shared__ float sm[256];
  sm[tid] = m;
  __syncthreads();
  if (tid < 8){
    float mm = -1e30f;
    for (int c = 0; c < 32; ++c) mm = fmaxf(mm, sm[c*8 + tid]);
    maxf1[tid] = mm;
  }
}

// ---------------- K2c: pack adjacency rows into 64-bit masks ----------------
__global__ __launch_bounds__(256) void k2c_pack(const int* __restrict__ adj,
                                               unsigned long long* __restrict__ adjm)
{
  int lane = threadIdx.x & 63, wave = threadIdx.x >> 6;
  int row = blockIdx.x*4 + wave;
  const int* ap = adj + (size_t)row*NN;
  #pragma unroll 8
  for (int s = 0; s < 64; ++s){
    unsigned long long m = __ballot(ap[s*64 + lane] != 0);
    if (lane == 0) adjm[(size_t)row*64 + s] = m;
  }
}

// ---------------- K3: masked-softmax GAT, one wave per (8 rows, 1 head) ----------------
__global__ __launch_bounds__(256) void k3_gat(
    const unsigned long long* __restrict__ adjm,   // [N][64]
    const float* __restrict__ supt,                // [64][N]
    const float* __restrict__ f1t,                 // [8][N]
    const float* __restrict__ f2,                  // [N][8]
    const float* __restrict__ maxf1, float* __restrict__ posg)
{
  int tid = threadIdx.x;
  int lane = tid & 63, wave = tid >> 6;
  int gid = blockIdx.x*4 + wave;        // 0..4095
  int ib = gid >> 3, h = gid & 7;
  int i0 = ib*8;

  float mf = maxf1[h];
  float f2v[8], M[8];
  #pragma unroll
  for (int r = 0; r < 8; ++r){
    f2v[r] = f2[(size_t)(i0+r)*8 + h];
    float lg = mf + f2v[r];
    lg = fmaxf(lg, 0.2f*lg);
    M[r] = fmaxf(lg, 0.f);              // upper bound on reference rowmax
  }

  const float2* f1p = (const float2*)(f1t + (size_t)h*NN);
  const float2* sp0 = (const float2*)(supt + (size_t)(h*8+0)*NN);
  const float2* sp1 = (const float2*)(supt + (size_t)(h*8+1)*NN);
  const float2* sp2 = (const float2*)(supt + (size_t)(h*8+2)*NN);
  const float2* sp3 = (const float2*)(supt + (size_t)(h*8+3)*NN);
  const float2* sp4 = (const float2*)(supt + (size_t)(h*8+4)*NN);
  const float2* sp5 = (const float2*)(supt + (size_t)(h*8+5)*NN);
  const float2* sp6 = (const float2*)(supt + (size_t)(h*8+6)*NN);
  const float2* sp7 = (const float2*)(supt + (size_t)(h*8+7)*NN);
  const unsigned long long* mbase = adjm + (size_t)i0*64;

  int sh0 = (lane*2) & 63;              // bit position of this lane's first j
  int woff = (lane >> 5);               // which of the 2 words this iter

  float sum[8] = {0.f,0.f,0.f,0.f,0.f,0.f,0.f,0.f};
  float pos[8][8];
  #pragma unroll
  for (int r = 0; r < 8; ++r)
    #pragma unroll
    for (int o = 0; o < 8; ++o) pos[r][o] = 0.f;

  for (int b = 0; b < 32; ++b){         // 128 j per iter (2 j per lane)
    int idx = b*64 + lane;
    float2 f1v = f1p[idx];
    float2 s0 = sp0[idx], s1 = sp1[idx], s2 = sp2[idx], s3 = sp3[idx];
    float2 s4 = sp4[idx], s5 = sp5[idx], s6 = sp6[idx], s7 = sp7[idx];
    int w = b*2 + woff;
    unsigned long long mw[8];
    #pragma unroll
    for (int r = 0; r < 8; ++r) mw[r] = mbase[r*64 + w];

    #pragma unroll
    for (int r = 0; r < 8; ++r){
      float l0 = f1v.x + f2v[r];
      float l1 = f1v.y + f2v[r];
      l0 = fmaxf(l0, 0.2f*l0);
      l1 = fmaxf(l1, 0.2f*l1);
      float p0 = __expf(l0 - M[r]);
      float p1 = __expf(l1 - M[r]);
      p0 = ((mw[r] >> sh0) & 1ull) ? p0 : 0.f;
      p1 = ((mw[r] >> (sh0+1)) & 1ull) ? p1 : 0.f;
      sum[r] += p0 + p1;
      pos[r][0] += p0*s0.x + p1*s0.y;
      pos[r][1] += p0*s1.x + p1*s1.y;
      pos[r][2] += p0*s2.x + p1*s2.y;
      pos[r][3] += p0*s3.x + p1*s3.y;
      pos[r][4] += p0*s4.x + p1*s4.y;
      pos[r][5] += p0*s5.x + p1*s5.y;
      pos[r][6] += p0*s6.x + p1*s6.y;
      pos[r][7] += p0*s7.x + p1*s7.y;
    }
  }

  // butterfly reduce all 72 accumulators across the wave
  #pragma unroll
  for (int s = 1; s < 64; s <<= 1){
    #pragma unroll
    for (int r = 0; r < 8; ++r){
      sum[r] += __shfl_xor(sum[r], s, 64);
      #pragma unroll
      for (int o = 0; o < 8; ++o) pos[r][o] += __shfl_xor(pos[r][o], s, 64);
    }
  }

  // lane (r*8+o) stores pos[r][o]/sum[r]  (static-index selection, rule #20)
  int lr = lane >> 3, lo = lane & 7;
  float sv = sum[0];
  #pragma unroll
  for (int r = 1; r < 8; ++r) sv = (lr == r) ? sum[r] : sv;
  float val = pos[0][0];
  #pragma unroll
  for (int r = 0; r < 8; ++r)
    #pragma unroll
    for (int o = 0; o < 8; ++o)
      if (r + o) val = (lane == r*8+o) ? pos[r][o] : val;
  float inv = 1.f / fmaxf(sv, 1e-10f);
  posg[(size_t)(i0 + lr)*64 + h*8 + lo] = val * inv;
}

// ---------------- K4: residual proj + the two MLP channels + PairNorm partials ----------------
__global__ __launch_bounds__(256) void k4_mix(
    const float* __restrict__ h, const float* __restrict__ posg,
    const float* __restrict__ gat_bias, const float* __restrict__ proj_b,
    const float* __restrict__ wtproj, const float* __restrict__ wtself,
    const float* __restrict__ wtpos,
    const float* __restrict__ mlp_self_b, const float* __restrict__ mlp_pos_b,
    float* __restrict__ s0, float* __restrict__ s1, float* __restrict__ part)
{
  int tid = threadIdx.x;
  int wave = tid >> 6, lane = tid & 63;
  int n = blockIdx.x*4 + wave;
  float hreg = h[n*64 + lane];
  float pr = proj_b[lane];
  float se = mlp_self_b[lane];
  #pragma unroll
  for (int k = 0; k < 64; ++k){
    float hk = __shfl(hreg, k, 64);
    pr += hk * wtproj[k*64 + lane];
    se += hk * wtself[k*64 + lane];
  }
  float posf = posg[n*64 + lane] + gat_bias[lane] + pr;
  float s1v = mlp_pos_b[lane];
  #pragma unroll
  for (int k = 0; k < 64; ++k){
    float pk = __shfl(posf, k, 64);
    s1v += pk * wtpos[k*64 + lane];
  }
  s0[n*64+lane] = se;
  s1[n*64+lane] = s1v;

  __shared__ float sb0[4][64];
  __shared__ float sb1[4][64];
  __shared__ float sq[4];
  sb0[wave][lane] = se;
  sb1[wave][lane] = s1v;
  float q = se*se + s1v*s1v;
  #pragma unroll
  for (int s = 1; s < 64; s <<= 1) q += __shfl_xor(q, s, 64);
  if (lane == 0) sq[wave] = q;
  __syncthreads();
  if (tid < 64){
    part[blockIdx.x*130 + tid] = sb0[0][tid]+sb0[1][tid]+sb0[2][tid]+sb0[3][tid];
  } else if (tid < 128){
    int d = tid - 64;
    part[blockIdx.x*130 + 64 + d] = sb1[0][d]+sb1[1][d]+sb1[2][d]+sb1[3][d];
  } else if (tid == 128){
    part[blockIdx.x*130 + 128] = sq[0]+sq[1]+sq[2]+sq[3];
  }
}

// ---------------- K5: PairNorm stats (1024-thread two-stage reduce) ----------------
__global__ __launch_bounds__(1024) void k5_stats(const float* __restrict__ part, float* __restrict__ stats)
{
  int tid = threadIdx.x;
  __shared__ float s_mu[8][128];
  __shared__ float s_sq[8];
  int c = tid & 127, ch = tid >> 7;
  float a = 0.f;
  for (int b = ch*128; b < ch*128+128; ++b) a += part[b*130 + c];
  s_mu[ch][c] = a;
  if (tid < 8){
    float q = 0.f;
    for (int b = tid*128; b < tid*128+128; ++b) q += part[b*130 + 128];
    s_sq[tid] = q;
  }
  __syncthreads();
  if (tid < 128){
    float m = 0.f;
    #pragma unroll
    for (int j = 0; j < 8; ++j) m += s_mu[j][tid];
    s_mu[0][tid] = m;
    stats[tid] = m / 4096.f;
  }
  __syncthreads();
  if (tid == 0){
    float sq = 0.f;
    #pragma unroll
    for (int j = 0; j < 8; ++j) sq += s_sq[j];
    float mu2 = 0.f;
    for (int i = 0; i < 128; ++i){ float m = s_mu[0][i] / 4096.f; mu2 += m*m; }
    float msq = sq/(4096.f*64.f) - mu2/64.f;
    stats[128] = 1.f / sqrtf(1e-6f + msq);
  }
}

// ---------------- K6: semantic attention + predictor ----------------
__global__ __launch_bounds__(256) void k6_sem(
    const float* __restrict__ s0, const float* __restrict__ s1,
    const float* __restrict__ stats, const float* __restrict__ wtsem,
    const float* __restrict__ sem_b1, const float* __restrict__ sem_w2,
    const float* __restrict__ pred_w, const float* __restrict__ pred_b,
    float* __restrict__ out)
{
  int tid = threadIdx.x;
  int wave = tid >> 6, lane = tid & 63;
  int n = blockIdx.x*4 + wave;
  float rinv = stats[128];
  float a0 = (s0[n*64+lane] - stats[lane]) * rinv;
  float a1 = (s1[n*64+lane] - stats[64+lane]) * rinv;
  float t0 = sem_b1[lane], t1 = t0;
  #pragma unroll
  for (int k = 0; k < 64; ++k){
    float w = wtsem[k*64 + lane];
    t0 += __shfl(a0, k, 64) * w;
    t1 += __shfl(a1, k, 64) * w;
  }
  t0 = tanh_fast(t0); t1 = tanh_fast(t1);
  float w2 = sem_w2[lane];
  float w0 = t0*w2, w1 = t1*w2;
  #pragma unroll
  for (int s = 1; s < 64; s <<= 1){
    w0 += __shfl_xor(w0, s, 64);
    w1 += __shfl_xor(w1, s, 64);
  }
  float mx = fmaxf(w0, w1);
  float e0 = __expf(w0 - mx), e1 = __expf(w1 - mx);
  float denom = e0 + e1 + 1e-10f;
  float b0 = e0/denom, b1 = e1/denom;
  float emb = b0*a0 + b1*a1;
  float pl = emb * pred_w[lane];
  #pragma unroll
  for (int s = 1; s < 64; s <<= 1) pl += __shfl_xor(pl, s, 64);
  if (lane == 0) out[n] = sigm(pl + pred_b[0]);
}

extern "C" void kernel_launch(void* const* d_in, const int* in_sizes, int n_in,
                              void* d_out, int out_size, void* d_ws, size_t ws_size,
                              hipStream_t stream)
{
  (void)in_sizes; (void)n_in; (void)out_size; (void)ws_size;
  const float* x         = (const float*)d_in[0];
  const int*   adj       = (const int*)d_in[1];
  const float* W_ih      = (const float*)d_in[2];
  const float* W_hh      = (const float*)d_in[3];
  const float* b_ih      = (const float*)d_in[4];
  const float* b_hh      = (const float*)d_in[5];
  const float* gat_w     = (const float*)d_in[6];
  const float* gat_wu    = (const float*)d_in[7];
  const float* gat_wv    = (const float*)d_in[8];
  const float* gat_bias  = (const float*)d_in[9];
  const float* proj_w    = (const float*)d_in[10];
  const float* proj_b    = (const float*)d_in[11];
  const float* mlp_self_w= (const float*)d_in[12];
  const float* mlp_self_b= (const float*)d_in[13];
  const float* mlp_pos_w = (const float*)d_in[14];
  const float* mlp_pos_b = (const float*)d_in[15];
  const float* sem_w1    = (const float*)d_in[16];
  const float* sem_b1    = (const float*)d_in[17];
  const float* sem_w2    = (const float*)d_in[18];
  const float* pred_w    = (const float*)d_in[19];
  const float* pred_b    = (const float*)d_in[20];
  float* out = (float*)d_out;
  float* ws  = (float*)d_ws;

  float* h     = ws + 0;         // 262144
  float* supt  = ws + 262144;    // 262144  [64][4096]
  float* f1t   = ws + 524288;    // 32768   [8][4096]
  float* f2    = ws + 557056;    // 32768   [4096][8]
  float* posg  = ws + 589824;    // 262144
  float* s0    = ws + 851968;    // 262144
  float* s1    = ws + 1114112;   // 262144
  // adjm overlays s0+s1 (2MB): written by k2c, consumed by k3, dead before k4 writes s0/s1
  unsigned long long* adjm = (unsigned long long*)(ws + 851968);
  float* part  = ws + 1376256;   // 1024*130
  float* bmax  = ws + 1509376;   // 1024*8
  float* maxf1 = ws + 1517568;   // 8
  float* stats = ws + 1517576;   // 129
  float* wtproj= ws + 1517712;   // 4096
  float* wtself= wtproj + 4096;
  float* wtpos = wtself + 4096;
  float* wtsem = wtpos  + 4096;

  k0_prep<<<16, 256, 0, stream>>>(proj_w, mlp_self_w, mlp_pos_w, sem_w1,
                                  wtproj, wtself, wtpos, wtsem);
  k1_gru<<<256, 64, 0, stream>>>(x, W_ih, W_hh, b_ih, b_hh, h);
  k2_sup<<<1024, 256, 0, stream>>>(h, gat_w, gat_wu, gat_wv, supt, f1t, f2, bmax);
  k2b_max<<<1, 256, 0, stream>>>(bmax, maxf1);
  k2c_pack<<<1024, 256, 0, stream>>>(adj, adjm);
  k3_gat<<<1024, 256, 0, stream>>>(adjm, supt, f1t, f2, maxf1, posg);
  k4_mix<<<1024, 256, 0, stream>>>(h, posg, gat_bias, proj_b, wtproj, wtself, wtpos,
                                   mlp_self_b, mlp_pos_b, s0, s1, part);
  k5_stats<<<1, 1024, 0, stream>>>(part, stats);
  k6_sem<<<1024, 256, 0, stream>>>(s0, s1, stats, wtsem, sem_b1, sem_w2, pred_w, pred_b, out);
}

// Round 11
// 264.350 us; speedup vs baseline: 2.0317x; 1.1382x over previous
//
#include <hip/hip_runtime.h>
#include <math.h>

#define NN 4096
#define TT 32
#define FF 7
#define HH 64
#define NHEAD 8
#define DOUT 8

typedef short bf16x8 __attribute__((ext_vector_type(8)));
typedef float f32x4 __attribute__((ext_vector_type(4)));

__device__ __forceinline__ float sigm(float x){
  x = fminf(fmaxf(x, -30.f), 30.f);
  return 1.f / (1.f + __expf(-x));
}
__device__ __forceinline__ float tanh_fast(float x){
  x = fminf(fmaxf(x, -15.f), 15.f);
  float e = __expf(2.f*x);
  return (e - 1.f) / (e + 1.f);
}
__device__ __forceinline__ unsigned short bf16rne(float f){
  unsigned u = __float_as_uint(f);
  u += 0x7fffu + ((u >> 16) & 1u);
  return (unsigned short)(u >> 16);
}
__device__ __forceinline__ unsigned bfpack2(float a, float b){
  return (unsigned)bf16rne(a) | ((unsigned)bf16rne(b) << 16);
}
__device__ __forceinline__ unsigned cvtpk_bf16(float a, float b){
  unsigned r;
  asm("v_cvt_pk_bf16_f32 %0, %1, %2" : "=v"(r) : "v"(a), "v"(b));
  return r;
}

// ---------------- K0: transpose small 64x64 weights to k-major ----------------
__global__ void k0_prep(const float* __restrict__ pw, const float* __restrict__ msw,
                        const float* __restrict__ mpw, const float* __restrict__ sw1,
                        float* __restrict__ wtproj, float* __restrict__ wtself,
                        float* __restrict__ wtpos, float* __restrict__ wtsem)
{
  int tid = threadIdx.x + blockIdx.x*blockDim.x;
  if (tid < 4096){
    int d = tid >> 6, k = tid & 63;
    wtproj[k*64+d] = pw[tid];
    wtself[k*64+d] = msw[tid];
    wtpos[k*64+d]  = mpw[tid];
    wtsem[k*64+d]  = sw1[tid];
  }
}

// ---------------- K1: GRU encoder via MFMA (bf16 inputs, f32 recurrence) ----------------
__global__ __launch_bounds__(64) void k1_gru(
    const float* __restrict__ x,      // [N][T][F]
    const float* __restrict__ Wih,    // [192][7]
    const float* __restrict__ Whh,    // [192][64]
    const float* __restrict__ bih, const float* __restrict__ bhh,
    float* __restrict__ hout)         // [N][64]
{
  __shared__ uint4 s_whhf[24*64];                 // 24KB  [T(12)][c(2)] A-frag lines
  __shared__ uint4 s_wihf[12*64];                 // 12KB  [T(12)] A-frag lines
  __shared__ __align__(16) short s_xb[32][16][8]; // 8KB   bf16 x (k=7 -> 1.0)
  __shared__ __align__(16) short s_hb[16][72];    // 2.25KB bf16 h (pad 72)

  int lane = threadIdx.x;
  int nb = blockIdx.x * 16;
  int row = lane & 15;          // A: gate row within tile / B,D: node column
  int kg  = lane >> 4;          // k-group (8 elements each)

  #pragma unroll
  for (int T = 0; T < 12; ++T){
    #pragma unroll
    for (int c = 0; c < 2; ++c){
      int g = T*16 + row;
      const float* wp = Whh + g*64 + c*32 + kg*8;
      uint4 v;
      v.x = bfpack2(wp[0], wp[1]);
      v.y = bfpack2(wp[2], wp[3]);
      v.z = bfpack2(wp[4], wp[5]);
      v.w = bfpack2(wp[6], wp[7]);
      s_whhf[(T*2 + c)*64 + lane] = v;
    }
  }
  #pragma unroll
  for (int T = 0; T < 12; ++T){
    int g = T*16 + row;
    float bias = (T < 8) ? (bih[g] + bhh[g]) : bih[g];   // b_hhn NOT folded (inside r*())
    float f[8];
    #pragma unroll
    for (int j = 0; j < 8; ++j){
      int k = kg*8 + j;
      f[j] = (k < 7) ? Wih[g*7 + k] : ((k == 7) ? bias : 0.f);
    }
    uint4 v;
    v.x = bfpack2(f[0], f[1]); v.y = bfpack2(f[2], f[3]);
    v.z = bfpack2(f[4], f[5]); v.w = bfpack2(f[6], f[7]);
    s_wihf[T*64 + lane] = v;
  }
  for (int s = lane; s < 4096; s += 64){
    int t = s >> 7, node = (s >> 3) & 15, k = s & 7;
    float v = (k < 7) ? x[(size_t)(nb + node)*224 + t*7 + k] : ((k == 7) ? 1.f : 0.f);
    s_xb[t][node][k] = (short)bf16rne(v);
  }
  for (int i = lane; i < 576; i += 64) ((unsigned*)s_hb)[i] = 0u;

  float bhn_[4][4];
  #pragma unroll
  for (int T = 0; T < 4; ++T)
    #pragma unroll
    for (int j = 0; j < 4; ++j)
      bhn_[T][j] = bhh[128 + T*16 + kg*4 + j];

  float hreg[4][4];
  #pragma unroll
  for (int T = 0; T < 4; ++T)
    #pragma unroll
    for (int j = 0; j < 4; ++j) hreg[T][j] = 0.f;

  const bf16x8* whhf = (const bf16x8*)s_whhf;
  const bf16x8* wihf = (const bf16x8*)s_wihf;
  f32x4 z4 = {0.f, 0.f, 0.f, 0.f};

  for (int t = 0; t < TT; ++t){
    bf16x8 bx = {0,0,0,0,0,0,0,0};
    if (lane < 16) bx = *(const bf16x8*)&s_xb[t][row][0];
    bf16x8 bh0 = *(const bf16x8*)&s_hb[row][kg*8];
    bf16x8 bh1 = *(const bf16x8*)&s_hb[row][32 + kg*8];

    #pragma unroll
    for (int Tr = 0; Tr < 4; ++Tr){
      f32x4 aR = __builtin_amdgcn_mfma_f32_16x16x32_bf16(wihf[Tr*64 + lane], bx, z4, 0, 0, 0);
      aR = __builtin_amdgcn_mfma_f32_16x16x32_bf16(whhf[(Tr*2+0)*64 + lane], bh0, aR, 0, 0, 0);
      aR = __builtin_amdgcn_mfma_f32_16x16x32_bf16(whhf[(Tr*2+1)*64 + lane], bh1, aR, 0, 0, 0);
      f32x4 aZ = __builtin_amdgcn_mfma_f32_16x16x32_bf16(wihf[(4+Tr)*64 + lane], bx, z4, 0, 0, 0);
      aZ = __builtin_amdgcn_mfma_f32_16x16x32_bf16(whhf[((4+Tr)*2+0)*64 + lane], bh0, aZ, 0, 0, 0);
      aZ = __builtin_amdgcn_mfma_f32_16x16x32_bf16(whhf[((4+Tr)*2+1)*64 + lane], bh1, aZ, 0, 0, 0);
      f32x4 aNx = __builtin_amdgcn_mfma_f32_16x16x32_bf16(wihf[(8+Tr)*64 + lane], bx, z4, 0, 0, 0);
      f32x4 aNh = __builtin_amdgcn_mfma_f32_16x16x32_bf16(whhf[((8+Tr)*2+0)*64 + lane], bh0, z4, 0, 0, 0);
      aNh = __builtin_amdgcn_mfma_f32_16x16x32_bf16(whhf[((8+Tr)*2+1)*64 + lane], bh1, aNh, 0, 0, 0);
      #pragma unroll
      for (int j = 0; j < 4; ++j){
        float rr = sigm(aR[j]);
        float zz = sigm(aZ[j]);
        float nn = tanh_fast(aNx[j] + rr*(aNh[j] + bhn_[Tr][j]));
        hreg[Tr][j] = (1.f - zz)*nn + zz*hreg[Tr][j];
      }
    }
    #pragma unroll
    for (int Tr = 0; Tr < 4; ++Tr){
      uint2 p;
      p.x = bfpack2(hreg[Tr][0], hreg[Tr][1]);
      p.y = bfpack2(hreg[Tr][2], hreg[Tr][3]);
      *(uint2*)&s_hb[row][Tr*16 + kg*4] = p;
    }
  }

  #pragma unroll
  for (int Tr = 0; Tr < 4; ++Tr)
    #pragma unroll
    for (int j = 0; j < 4; ++j)
      hout[(size_t)(nb + row)*64 + Tr*16 + kg*4 + j] = hreg[Tr][j];
}

// ---------------- K2: supb (bf16, transposed) = h@gat_w, f1t/f2, block f1 max ----------------
__global__ __launch_bounds__(256) void k2_sup(
    const float* __restrict__ h, const float* __restrict__ gat_w,
    const float* __restrict__ wu, const float* __restrict__ wv,
    unsigned short* __restrict__ supb,  // [64][N] bf16, row = hh*8+o
    float* __restrict__ f1t,            // [8][N]
    float* __restrict__ f2,             // [N][8]
    float* __restrict__ bmax)
{
  int tid = threadIdx.x;
  int wave = tid >> 6, lane = tid & 63;
  int n = blockIdx.x*4 + wave;
  float hreg = h[n*64 + lane];
  float acc = 0.f;
  #pragma unroll
  for (int k = 0; k < 64; ++k){
    float hk = __shfl(hreg, k, 64);
    acc += hk * gat_w[k*64 + lane];
  }
  supb[(size_t)lane*NN + n] = bf16rne(acc);   // bf16: k3 consumes as MFMA B-operand
  float p1 = acc * wu[lane];
  float p2 = acc * wv[lane];
  #pragma unroll
  for (int s = 1; s < 8; s <<= 1){
    p1 += __shfl_xor(p1, s, 64);
    p2 += __shfl_xor(p2, s, 64);
  }
  int hh = lane >> 3;
  __shared__ float s_m[4][8];
  if ((lane & 7) == 0){
    f1t[(size_t)hh*NN + n] = p1;
    f2[n*8 + hh] = p2;
    s_m[wave][hh] = p1;
  }
  __syncthreads();
  if (tid < 8){
    float mm = fmaxf(fmaxf(s_m[0][tid], s_m[1][tid]), fmaxf(s_m[2][tid], s_m[3][tid]));
    bmax[blockIdx.x*8 + tid] = mm;
  }
}

__global__ __launch_bounds__(256) void k2b_max(const float* __restrict__ bmax, float* __restrict__ maxf1)
{
  int tid = threadIdx.x;
  int hh = tid & 7, chunk = tid >> 3;   // 32 chunks of 32 blocks
  float m = -1e30f;
  for (int b = chunk*32; b < chunk*32+32; ++b) m = fmaxf(m, bmax[b*8 + hh]);
  __shared__ float sm[256];
  sm[tid] = m;
  __syncthreads();
  if (tid < 8){
    float mm = -1e30f;
    for (int c = 0; c < 32; ++c) mm = fmaxf(mm, sm[c*8 + tid]);
    maxf1[tid] = mm;
  }
}

// ---------------- K2c: pack adjacency rows into 64-bit masks ----------------
__global__ __launch_bounds__(256) void k2c_pack(const int* __restrict__ adj,
                                               unsigned long long* __restrict__ adjm)
{
  int lane = threadIdx.x & 63, wave = threadIdx.x >> 6;
  int row = blockIdx.x*4 + wave;
  const int* ap = adj + (size_t)row*NN;
  #pragma unroll 8
  for (int s = 0; s < 64; ++s){
    unsigned long long m = __ballot(ap[s*64 + lane] != 0);
    if (lane == 0) adjm[(size_t)row*64 + s] = m;
  }
}

// ---------------- K3: flash-style MFMA GAT ----------------
// 1024 blocks x 128 threads (2 waves); wave = (16-row tile, 1 head).
// Per 32-j chunk: lane computes 8 P values (A-frag: row=lane&15, k=kg*8+e),
// packs bf16, B-frag from bf16 supb (col=lane&15 -> out o; col 8 = constant 1.0
// so D[.][8] accumulates the softmax denominator). One MFMA per chunk.
// Zero LDS, zero barriers; P and sum share identical bf16 rounding.
__global__ __launch_bounds__(128) void k3_gat(
    const unsigned long long* __restrict__ adjm,   // [N][64]
    const unsigned short* __restrict__ supb,       // [64][N] bf16
    const float* __restrict__ f1t,                 // [8][N]
    const float* __restrict__ f2,                  // [N][8]
    const float* __restrict__ maxf1, float* __restrict__ posg)
{
  int tid = threadIdx.x;
  int lane = tid & 63, wave = tid >> 6;
  int gid = blockIdx.x*2 + wave;        // 0..2047
  int ib = gid >> 3, h = gid & 7;
  int i0 = ib*16;
  int col = lane & 15;                  // A-row during build; B/D column after
  int kg  = lane >> 4;

  float f2v = f2[(size_t)(i0+col)*8 + h];
  float lg = maxf1[h] + f2v;
  lg = fmaxf(lg, 0.2f*lg);
  float M = fmaxf(lg, 0.f);             // upper bound on reference rowmax

  const unsigned long long* mrow = adjm + (size_t)(i0+col)*64;
  const float* f1p = f1t + (size_t)h*NN;
  const unsigned short* bsrc = supb + (size_t)(h*8 + (col & 7))*NN;
  unsigned bge8 = (col >= 8) ? 0xffffffffu : 0u;   // lanes feeding the sum column

  f32x4 acc = {0.f, 0.f, 0.f, 0.f};

  #pragma unroll 2
  for (int c = 0; c < 128; ++c){
    int j8 = c*32 + kg*8;
    unsigned long long mw = mrow[c >> 1];
    unsigned mb = (unsigned)(mw >> (((c & 1) << 5) + (kg << 3)));
    float4 fa = *(const float4*)(f1p + j8);
    float4 fb = *(const float4*)(f1p + j8 + 4);

    float p[8];
    p[0]=fa.x; p[1]=fa.y; p[2]=fa.z; p[3]=fa.w;
    p[4]=fb.x; p[5]=fb.y; p[6]=fb.z; p[7]=fb.w;
    #pragma unroll
    for (int e = 0; e < 8; ++e){
      float logit = p[e] + f2v;
      float lr = fmaxf(logit, 0.2f*logit);
      float pe = __expf(lr - M);
      p[e] = (mb & (1u << e)) ? pe : 0.f;
    }
    union { bf16x8 v; unsigned u[4]; } A;
    A.u[0] = cvtpk_bf16(p[0], p[1]);
    A.u[1] = cvtpk_bf16(p[2], p[3]);
    A.u[2] = cvtpk_bf16(p[4], p[5]);
    A.u[3] = cvtpk_bf16(p[6], p[7]);

    union { bf16x8 v; unsigned u[4]; } B;
    uint4 ld = *(const uint4*)(bsrc + j8);
    B.u[0] = bge8 ? 0x3f803f80u : ld.x;   // col>=8: bf16 1.0 (col 8 = denominator)
    B.u[1] = bge8 ? 0x3f803f80u : ld.y;
    B.u[2] = bge8 ? 0x3f803f80u : ld.z;
    B.u[3] = bge8 ? 0x3f803f80u : ld.w;

    acc = __builtin_amdgcn_mfma_f32_16x16x32_bf16(A.v, B.v, acc, 0, 0, 0);
  }

  // denominator lives in column 8 of this kg-group: lane (lane&48)+8
  int slane = (lane & 48) + 8;
  #pragma unroll
  for (int r4 = 0; r4 < 4; ++r4){
    float sv = __shfl(acc[r4], slane, 64);
    float inv = 1.f / fmaxf(sv, 1e-10f);
    if (col < 8)
      posg[(size_t)(i0 + kg*4 + r4)*64 + h*8 + col] = acc[r4] * inv;
  }
}

// ---------------- K4: residual proj + the two MLP channels + PairNorm partials ----------------
__global__ __launch_bounds__(256) void k4_mix(
    const float* __restrict__ h, const float* __restrict__ posg,
    const float* __restrict__ gat_bias, const float* __restrict__ proj_b,
    const float* __restrict__ wtproj, const float* __restrict__ wtself,
    const float* __restrict__ wtpos,
    const float* __restrict__ mlp_self_b, const float* __restrict__ mlp_pos_b,
    float* __restrict__ s0, float* __restrict__ s1, float* __restrict__ part)
{
  int tid = threadIdx.x;
  int wave = tid >> 6, lane = tid & 63;
  int n = blockIdx.x*4 + wave;
  float hreg = h[n*64 + lane];
  float pr = proj_b[lane];
  float se = mlp_self_b[lane];
  #pragma unroll
  for (int k = 0; k < 64; ++k){
    float hk = __shfl(hreg, k, 64);
    pr += hk * wtproj[k*64 + lane];
    se += hk * wtself[k*64 + lane];
  }
  float posf = posg[n*64 + lane] + gat_bias[lane] + pr;
  float s1v = mlp_pos_b[lane];
  #pragma unroll
  for (int k = 0; k < 64; ++k){
    float pk = __shfl(posf, k, 64);
    s1v += pk * wtpos[k*64 + lane];
  }
  s0[n*64+lane] = se;
  s1[n*64+lane] = s1v;

  __shared__ float sb0[4][64];
  __shared__ float sb1[4][64];
  __shared__ float sq[4];
  sb0[wave][lane] = se;
  sb1[wave][lane] = s1v;
  float q = se*se + s1v*s1v;
  #pragma unroll
  for (int s = 1; s < 64; s <<= 1) q += __shfl_xor(q, s, 64);
  if (lane == 0) sq[wave] = q;
  __syncthreads();
  if (tid < 64){
    part[blockIdx.x*130 + tid] = sb0[0][tid]+sb0[1][tid]+sb0[2][tid]+sb0[3][tid];
  } else if (tid < 128){
    int d = tid - 64;
    part[blockIdx.x*130 + 64 + d] = sb1[0][d]+sb1[1][d]+sb1[2][d]+sb1[3][d];
  } else if (tid == 128){
    part[blockIdx.x*130 + 128] = sq[0]+sq[1]+sq[2]+sq[3];
  }
}

// ---------------- K5: PairNorm stats (1024-thread two-stage reduce) ----------------
__global__ __launch_bounds__(1024) void k5_stats(const float* __restrict__ part, float* __restrict__ stats)
{
  int tid = threadIdx.x;
  __shared__ float s_mu[8][128];
  __shared__ float s_sq[8];
  int c = tid & 127, ch = tid >> 7;
  float a = 0.f;
  for (int b = ch*128; b < ch*128+128; ++b) a += part[b*130 + c];
  s_mu[ch][c] = a;
  if (tid < 8){
    float q = 0.f;
    for (int b = tid*128; b < tid*128+128; ++b) q += part[b*130 + 128];
    s_sq[tid] = q;
  }
  __syncthreads();
  if (tid < 128){
    float m = 0.f;
    #pragma unroll
    for (int j = 0; j < 8; ++j) m += s_mu[j][tid];
    s_mu[0][tid] = m;
    stats[tid] = m / 4096.f;
  }
  __syncthreads();
  if (tid == 0){
    float sq = 0.f;
    #pragma unroll
    for (int j = 0; j < 8; ++j) sq += s_sq[j];
    float mu2 = 0.f;
    for (int i = 0; i < 128; ++i){ float m = s_mu[0][i] / 4096.f; mu2 += m*m; }
    float msq = sq/(4096.f*64.f) - mu2/64.f;
    stats[128] = 1.f / sqrtf(1e-6f + msq);
  }
}

// ---------------- K6: semantic attention + predictor ----------------
__global__ __launch_bounds__(256) void k6_sem(
    const float* __restrict__ s0, const float* __restrict__ s1,
    const float* __restrict__ stats, const float* __restrict__ wtsem,
    const float* __restrict__ sem_b1, const float* __restrict__ sem_w2,
    const float* __restrict__ pred_w, const float* __restrict__ pred_b,
    float* __restrict__ out)
{
  int tid = threadIdx.x;
  int wave = tid >> 6, lane = tid & 63;
  int n = blockIdx.x*4 + wave;
  float rinv = stats[128];
  float a0 = (s0[n*64+lane] - stats[lane]) * rinv;
  float a1 = (s1[n*64+lane] - stats[64+lane]) * rinv;
  float t0 = sem_b1[lane], t1 = t0;
  #pragma unroll
  for (int k = 0; k < 64; ++k){
    float w = wtsem[k*64 + lane];
    t0 += __shfl(a0, k, 64) * w;
    t1 += __shfl(a1, k, 64) * w;
  }
  t0 = tanh_fast(t0); t1 = tanh_fast(t1);
  float w2 = sem_w2[lane];
  float w0 = t0*w2, w1 = t1*w2;
  #pragma unroll
  for (int s = 1; s < 64; s <<= 1){
    w0 += __shfl_xor(w0, s, 64);
    w1 += __shfl_xor(w1, s, 64);
  }
  float mx = fmaxf(w0, w1);
  float e0 = __expf(w0 - mx), e1 = __expf(w1 - mx);
  float denom = e0 + e1 + 1e-10f;
  float b0 = e0/denom, b1 = e1/denom;
  float emb = b0*a0 + b1*a1;
  float pl = emb * pred_w[lane];
  #pragma unroll
  for (int s = 1; s < 64; s <<= 1) pl += __shfl_xor(pl, s, 64);
  if (lane == 0) out[n] = sigm(pl + pred_b[0]);
}

extern "C" void kernel_launch(void* const* d_in, const int* in_sizes, int n_in,
                              void* d_out, int out_size, void* d_ws, size_t ws_size,
                              hipStream_t stream)
{
  (void)in_sizes; (void)n_in; (void)out_size; (void)ws_size;
  const float* x         = (const float*)d_in[0];
  const int*   adj       = (const int*)d_in[1];
  const float* W_ih      = (const float*)d_in[2];
  const float* W_hh      = (const float*)d_in[3];
  const float* b_ih      = (const float*)d_in[4];
  const float* b_hh      = (const float*)d_in[5];
  const float* gat_w     = (const float*)d_in[6];
  const float* gat_wu    = (const float*)d_in[7];
  const float* gat_wv    = (const float*)d_in[8];
  const float* gat_bias  = (const float*)d_in[9];
  const float* proj_w    = (const float*)d_in[10];
  const float* proj_b    = (const float*)d_in[11];
  const float* mlp_self_w= (const float*)d_in[12];
  const float* mlp_self_b= (const float*)d_in[13];
  const float* mlp_pos_w = (const float*)d_in[14];
  const float* mlp_pos_b = (const float*)d_in[15];
  const float* sem_w1    = (const float*)d_in[16];
  const float* sem_b1    = (const float*)d_in[17];
  const float* sem_w2    = (const float*)d_in[18];
  const float* pred_w    = (const float*)d_in[19];
  const float* pred_b    = (const float*)d_in[20];
  float* out = (float*)d_out;
  float* ws  = (float*)d_ws;

  float* h     = ws + 0;         // 262144
  // supb (bf16 [64][4096] = 512KB) overlays the old f32 supt region (1MB)
  unsigned short* supb = (unsigned short*)(ws + 262144);
  float* f1t   = ws + 524288;    // 32768   [8][4096]
  float* f2    = ws + 557056;    // 32768   [4096][8]
  float* posg  = ws + 589824;    // 262144
  float* s0    = ws + 851968;    // 262144
  float* s1    = ws + 1114112;   // 262144
  // adjm overlays s0+s1 (2MB): written by k2c, consumed by k3, dead before k4 writes s0/s1
  unsigned long long* adjm = (unsigned long long*)(ws + 851968);
  float* part  = ws + 1376256;   // 1024*130
  float* bmax  = ws + 1509376;   // 1024*8
  float* maxf1 = ws + 1517568;   // 8
  float* stats = ws + 1517576;   // 129
  float* wtproj= ws + 1517712;   // 4096
  float* wtself= wtproj + 4096;
  float* wtpos = wtself + 4096;
  float* wtsem = wtpos  + 4096;

  k0_prep<<<16, 256, 0, stream>>>(proj_w, mlp_self_w, mlp_pos_w, sem_w1,
                                  wtproj, wtself, wtpos, wtsem);
  k1_gru<<<256, 64, 0, stream>>>(x, W_ih, W_hh, b_ih, b_hh, h);
  k2_sup<<<1024, 256, 0, stream>>>(h, gat_w, gat_wu, gat_wv, supb, f1t, f2, bmax);
  k2b_max<<<1, 256, 0, stream>>>(bmax, maxf1);
  k2c_pack<<<1024, 256, 0, stream>>>(adj, adjm);
  k3_gat<<<1024, 128, 0, stream>>>(adjm, supb, f1t, f2, maxf1, posg);
  k4_mix<<<1024, 256, 0, stream>>>(h, posg, gat_bias, proj_b, wtproj, wtself, wtpos,
                                   mlp_self_b, mlp_pos_b, s0, s1, part);
  k5_stats<<<1, 1024, 0, stream>>>(part, stats);
  k6_sem<<<1024, 256, 0, stream>>>(s0, s1, stats, wtsem, sem_b1, sem_w2, pred_w, pred_b, out);
}

// Round 12
// 260.321 us; speedup vs baseline: 2.0631x; 1.0155x over previous
//
#include <hip/hip_runtime.h>
#include <math.h>

#define NN 4096
#define TT 32
#define FF 7
#define HH 64
#define NHEAD 8
#define DOUT 8

typedef short bf16x8 __attribute__((ext_vector_type(8)));
typedef float f32x4 __attribute__((ext_vector_type(4)));

__device__ __forceinline__ float sigm(float x){
  x = fminf(fmaxf(x, -30.f), 30.f);
  return 1.f / (1.f + __expf(-x));
}
__device__ __forceinline__ float tanh_fast(float x){
  x = fminf(fmaxf(x, -15.f), 15.f);
  float e = __expf(2.f*x);
  return (e - 1.f) / (e + 1.f);
}
__device__ __forceinline__ unsigned short bf16rne(float f){
  unsigned u = __float_as_uint(f);
  u += 0x7fffu + ((u >> 16) & 1u);
  return (unsigned short)(u >> 16);
}
__device__ __forceinline__ unsigned bfpack2(float a, float b){
  return (unsigned)bf16rne(a) | ((unsigned)bf16rne(b) << 16);
}
__device__ __forceinline__ unsigned cvtpk_bf16(float a, float b){
  unsigned r;
  asm("v_cvt_pk_bf16_f32 %0, %1, %2" : "=v"(r) : "v"(a), "v"(b));
  return r;
}

// ---------------- K0: transpose small 64x64 weights to k-major ----------------
__global__ void k0_prep(const float* __restrict__ pw, const float* __restrict__ msw,
                        const float* __restrict__ mpw, const float* __restrict__ sw1,
                        float* __restrict__ wtproj, float* __restrict__ wtself,
                        float* __restrict__ wtpos, float* __restrict__ wtsem)
{
  int tid = threadIdx.x + blockIdx.x*blockDim.x;
  if (tid < 4096){
    int d = tid >> 6, k = tid & 63;
    wtproj[k*64+d] = pw[tid];
    wtself[k*64+d] = msw[tid];
    wtpos[k*64+d]  = mpw[tid];
    wtsem[k*64+d]  = sw1[tid];
  }
}

// ---------------- K1: GRU encoder via MFMA, weights resident in VGPRs ----------------
// 256 blocks x 1 wave; wave owns 16 nodes. All 36 A-fragments (W_hh 24 + W_ih 12)
// are built from global into REGISTERS once -- the t-loop does zero LDS reads for
// weights (round-11: 38 ds_read_b128/t with fully-exposed lgkmcnt = 6700 cyc/t).
// Per t: 36 MFMA + lane-local activations + tiny h repack through 2.25KB LDS.
__global__ __launch_bounds__(64) void k1_gru(
    const float* __restrict__ x,      // [N][T][F]
    const float* __restrict__ Wih,    // [192][7]
    const float* __restrict__ Whh,    // [192][64]
    const float* __restrict__ bih, const float* __restrict__ bhh,
    float* __restrict__ hout)         // [N][64]
{
  __shared__ __align__(16) short s_xb[32][16][8]; // 8KB   bf16 x (k=7 -> 1.0)
  __shared__ __align__(16) short s_hb[16][72];    // 2.25KB bf16 h (pad 72)

  int lane = threadIdx.x;
  int nb = blockIdx.x * 16;
  int row = lane & 15;          // A: gate row within tile / B,D: node column
  int kg  = lane >> 4;          // k-group (8 elements each)

  union U { bf16x8 v; uint4 q; };

  // ---- W_hh A-fragments -> registers ----
  bf16x8 whh_f[24];
  #pragma unroll
  for (int T = 0; T < 12; ++T){
    #pragma unroll
    for (int c = 0; c < 2; ++c){
      int g = T*16 + row;
      const float* wp = Whh + g*64 + c*32 + kg*8;
      U u;
      u.q.x = bfpack2(wp[0], wp[1]);
      u.q.y = bfpack2(wp[2], wp[3]);
      u.q.z = bfpack2(wp[4], wp[5]);
      u.q.w = bfpack2(wp[6], wp[7]);
      whh_f[T*2 + c] = u.v;
    }
  }
  // ---- W_ih A-fragments (k<7 weights, k==7 folded bias, k>=8 zero) -> registers ----
  bf16x8 wih_f[12];
  #pragma unroll
  for (int T = 0; T < 12; ++T){
    int g = T*16 + row;
    float bias = (T < 8) ? (bih[g] + bhh[g]) : bih[g];   // b_hhn NOT folded (inside r*())
    float f[8];
    #pragma unroll
    for (int j = 0; j < 8; ++j){
      int k = kg*8 + j;
      f[j] = (k < 7) ? Wih[g*7 + k] : ((k == 7) ? bias : 0.f);
    }
    U u;
    u.q.x = bfpack2(f[0], f[1]); u.q.y = bfpack2(f[2], f[3]);
    u.q.z = bfpack2(f[4], f[5]); u.q.w = bfpack2(f[6], f[7]);
    wih_f[T] = u.v;
  }
  // ---- stage x as bf16 B-lines (k==7 -> 1.0) ----
  for (int s = lane; s < 4096; s += 64){
    int t = s >> 7, node = (s >> 3) & 15, k = s & 7;
    float v = (k < 7) ? x[(size_t)(nb + node)*224 + t*7 + k] : ((k == 7) ? 1.f : 0.f);
    s_xb[t][node][k] = (short)bf16rne(v);
  }
  for (int i = lane; i < 576; i += 64) ((unsigned*)s_hb)[i] = 0u;

  float bhn_[4][4];
  #pragma unroll
  for (int T = 0; T < 4; ++T)
    #pragma unroll
    for (int j = 0; j < 4; ++j)
      bhn_[T][j] = bhh[128 + T*16 + kg*4 + j];

  float hreg[4][4];
  #pragma unroll
  for (int T = 0; T < 4; ++T)
    #pragma unroll
    for (int j = 0; j < 4; ++j) hreg[T][j] = 0.f;

  f32x4 z4 = {0.f, 0.f, 0.f, 0.f};

  for (int t = 0; t < TT; ++t){
    bf16x8 bx = {0,0,0,0,0,0,0,0};
    if (lane < 16) bx = *(const bf16x8*)&s_xb[t][row][0];
    bf16x8 bh0 = *(const bf16x8*)&s_hb[row][kg*8];
    bf16x8 bh1 = *(const bf16x8*)&s_hb[row][32 + kg*8];

    #pragma unroll
    for (int Tr = 0; Tr < 4; ++Tr){
      f32x4 aR = __builtin_amdgcn_mfma_f32_16x16x32_bf16(wih_f[Tr], bx, z4, 0, 0, 0);
      aR = __builtin_amdgcn_mfma_f32_16x16x32_bf16(whh_f[Tr*2+0], bh0, aR, 0, 0, 0);
      aR = __builtin_amdgcn_mfma_f32_16x16x32_bf16(whh_f[Tr*2+1], bh1, aR, 0, 0, 0);
      f32x4 aZ = __builtin_amdgcn_mfma_f32_16x16x32_bf16(wih_f[4+Tr], bx, z4, 0, 0, 0);
      aZ = __builtin_amdgcn_mfma_f32_16x16x32_bf16(whh_f[(4+Tr)*2+0], bh0, aZ, 0, 0, 0);
      aZ = __builtin_amdgcn_mfma_f32_16x16x32_bf16(whh_f[(4+Tr)*2+1], bh1, aZ, 0, 0, 0);
      f32x4 aNx = __builtin_amdgcn_mfma_f32_16x16x32_bf16(wih_f[8+Tr], bx, z4, 0, 0, 0);
      f32x4 aNh = __builtin_amdgcn_mfma_f32_16x16x32_bf16(whh_f[(8+Tr)*2+0], bh0, z4, 0, 0, 0);
      aNh = __builtin_amdgcn_mfma_f32_16x16x32_bf16(whh_f[(8+Tr)*2+1], bh1, aNh, 0, 0, 0);
      #pragma unroll
      for (int j = 0; j < 4; ++j){
        float rr = sigm(aR[j]);
        float zz = sigm(aZ[j]);
        float nn = tanh_fast(aNx[j] + rr*(aNh[j] + bhn_[Tr][j]));
        hreg[Tr][j] = (1.f - zz)*nn + zz*hreg[Tr][j];
      }
    }
    #pragma unroll
    for (int Tr = 0; Tr < 4; ++Tr){
      uint2 p;
      p.x = bfpack2(hreg[Tr][0], hreg[Tr][1]);
      p.y = bfpack2(hreg[Tr][2], hreg[Tr][3]);
      *(uint2*)&s_hb[row][Tr*16 + kg*4] = p;
    }
  }

  #pragma unroll
  for (int Tr = 0; Tr < 4; ++Tr)
    #pragma unroll
    for (int j = 0; j < 4; ++j)
      hout[(size_t)(nb + row)*64 + Tr*16 + kg*4 + j] = hreg[Tr][j];
}

// ---------------- K2: supb (bf16, transposed) = h@gat_w, f1t/f2, block f1 max ----------------
__global__ __launch_bounds__(256) void k2_sup(
    const float* __restrict__ h, const float* __restrict__ gat_w,
    const float* __restrict__ wu, const float* __restrict__ wv,
    unsigned short* __restrict__ supb,  // [64][N] bf16, row = hh*8+o
    float* __restrict__ f1t,            // [8][N]
    float* __restrict__ f2,             // [N][8]
    float* __restrict__ bmax)
{
  int tid = threadIdx.x;
  int wave = tid >> 6, lane = tid & 63;
  int n = blockIdx.x*4 + wave;
  float hreg = h[n*64 + lane];
  float acc = 0.f;
  #pragma unroll
  for (int k = 0; k < 64; ++k){
    float hk = __shfl(hreg, k, 64);
    acc += hk * gat_w[k*64 + lane];
  }
  supb[(size_t)lane*NN + n] = bf16rne(acc);   // bf16: k3 consumes as MFMA B-operand
  float p1 = acc * wu[lane];
  float p2 = acc * wv[lane];
  #pragma unroll
  for (int s = 1; s < 8; s <<= 1){
    p1 += __shfl_xor(p1, s, 64);
    p2 += __shfl_xor(p2, s, 64);
  }
  int hh = lane >> 3;
  __shared__ float s_m[4][8];
  if ((lane & 7) == 0){
    f1t[(size_t)hh*NN + n] = p1;
    f2[n*8 + hh] = p2;
    s_m[wave][hh] = p1;
  }
  __syncthreads();
  if (tid < 8){
    float mm = fmaxf(fmaxf(s_m[0][tid], s_m[1][tid]), fmaxf(s_m[2][tid], s_m[3][tid]));
    bmax[blockIdx.x*8 + tid] = mm;
  }
}

__global__ __launch_bounds__(256) void k2b_max(const float* __restrict__ bmax, float* __restrict__ maxf1)
{
  int tid = threadIdx.x;
  int hh = tid & 7, chunk = tid >> 3;   // 32 chunks of 32 blocks
  float m = -1e30f;
  for (int b = chunk*32; b < chunk*32+32; ++b) m = fmaxf(m, bmax[b*8 + hh]);
  __shared__ float sm[256];
  sm[tid] = m;
  __syncthreads();
  if (tid < 8){
    float mm = -1e30f;
    for (int c = 0; c < 32; ++c) mm = fmaxf(mm, sm[c*8 + tid]);
    maxf1[tid] = mm;
  }
}

// ---------------- K2c: pack adjacency rows into 64-bit masks ----------------
__global__ __launch_bounds__(256) void k2c_pack(const int* __restrict__ adj,
                                               unsigned long long* __restrict__ adjm)
{
  int lane = threadIdx.x & 63, wave = threadIdx.x >> 6;
  int row = blockIdx.x*4 + wave;
  const int* ap = adj + (size_t)row*NN;
  #pragma unroll 8
  for (int s = 0; s < 64; ++s){
    unsigned long long m = __ballot(ap[s*64 + lane] != 0);
    if (lane == 0) adjm[(size_t)row*64 + s] = m;
  }
}

// ---------------- K3: flash-style MFMA GAT ----------------
// 1024 blocks x 128 threads (2 waves); wave = (16-row tile, 1 head).
// Per 32-j chunk: lane computes 8 P values (A-frag: row=lane&15, k=kg*8+e),
// packs bf16, B-frag from bf16 supb (col 8 = constant 1.0 -> D[.][8] = denominator).
__global__ __launch_bounds__(128) void k3_gat(
    const unsigned long long* __restrict__ adjm,   // [N][64]
    const unsigned short* __restrict__ supb,       // [64][N] bf16
    const float* __restrict__ f1t,                 // [8][N]
    const float* __restrict__ f2,                  // [N][8]
    const float* __restrict__ maxf1, float* __restrict__ posg)
{
  int tid = threadIdx.x;
  int lane = tid & 63, wave = tid >> 6;
  int gid = blockIdx.x*2 + wave;        // 0..2047
  int ib = gid >> 3, h = gid & 7;
  int i0 = ib*16;
  int col = lane & 15;                  // A-row during build; B/D column after
  int kg  = lane >> 4;

  float f2v = f2[(size_t)(i0+col)*8 + h];
  float lg = maxf1[h] + f2v;
  lg = fmaxf(lg, 0.2f*lg);
  float M = fmaxf(lg, 0.f);             // upper bound on reference rowmax

  const unsigned long long* mrow = adjm + (size_t)(i0+col)*64;
  const float* f1p = f1t + (size_t)h*NN;
  const unsigned short* bsrc = supb + (size_t)(h*8 + (col & 7))*NN;
  unsigned bge8 = (col >= 8) ? 0xffffffffu : 0u;   // lanes feeding the sum column

  f32x4 acc = {0.f, 0.f, 0.f, 0.f};

  #pragma unroll 2
  for (int c = 0; c < 128; ++c){
    int j8 = c*32 + kg*8;
    unsigned long long mw = mrow[c >> 1];
    unsigned mb = (unsigned)(mw >> (((c & 1) << 5) + (kg << 3)));
    float4 fa = *(const float4*)(f1p + j8);
    float4 fb = *(const float4*)(f1p + j8 + 4);

    float p[8];
    p[0]=fa.x; p[1]=fa.y; p[2]=fa.z; p[3]=fa.w;
    p[4]=fb.x; p[5]=fb.y; p[6]=fb.z; p[7]=fb.w;
    #pragma unroll
    for (int e = 0; e < 8; ++e){
      float logit = p[e] + f2v;
      float lr = fmaxf(logit, 0.2f*logit);
      float pe = __expf(lr - M);
      p[e] = (mb & (1u << e)) ? pe : 0.f;
    }
    union { bf16x8 v; unsigned u[4]; } A;
    A.u[0] = cvtpk_bf16(p[0], p[1]);
    A.u[1] = cvtpk_bf16(p[2], p[3]);
    A.u[2] = cvtpk_bf16(p[4], p[5]);
    A.u[3] = cvtpk_bf16(p[6], p[7]);

    union { bf16x8 v; unsigned u[4]; } B;
    uint4 ld = *(const uint4*)(bsrc + j8);
    B.u[0] = bge8 ? 0x3f803f80u : ld.x;   // col>=8: bf16 1.0 (col 8 = denominator)
    B.u[1] = bge8 ? 0x3f803f80u : ld.y;
    B.u[2] = bge8 ? 0x3f803f80u : ld.z;
    B.u[3] = bge8 ? 0x3f803f80u : ld.w;

    acc = __builtin_amdgcn_mfma_f32_16x16x32_bf16(A.v, B.v, acc, 0, 0, 0);
  }

  // denominator lives in column 8 of this kg-group: lane (lane&48)+8
  int slane = (lane & 48) + 8;
  #pragma unroll
  for (int r4 = 0; r4 < 4; ++r4){
    float sv = __shfl(acc[r4], slane, 64);
    float inv = 1.f / fmaxf(sv, 1e-10f);
    if (col < 8)
      posg[(size_t)(i0 + kg*4 + r4)*64 + h*8 + col] = acc[r4] * inv;
  }
}

// ---------------- K4: residual proj + the two MLP channels + PairNorm partials ----------------
__global__ __launch_bounds__(256) void k4_mix(
    const float* __restrict__ h, const float* __restrict__ posg,
    const float* __restrict__ gat_bias, const float* __restrict__ proj_b,
    const float* __restrict__ wtproj, const float* __restrict__ wtself,
    const float* __restrict__ wtpos,
    const float* __restrict__ mlp_self_b, const float* __restrict__ mlp_pos_b,
    float* __restrict__ s0, float* __restrict__ s1, float* __restrict__ part)
{
  int tid = threadIdx.x;
  int wave = tid >> 6, lane = tid & 63;
  int n = blockIdx.x*4 + wave;
  float hreg = h[n*64 + lane];
  float pr = proj_b[lane];
  float se = mlp_self_b[lane];
  #pragma unroll
  for (int k = 0; k < 64; ++k){
    float hk = __shfl(hreg, k, 64);
    pr += hk * wtproj[k*64 + lane];
    se += hk * wtself[k*64 + lane];
  }
  float posf = posg[n*64 + lane] + gat_bias[lane] + pr;
  float s1v = mlp_pos_b[lane];
  #pragma unroll
  for (int k = 0; k < 64; ++k){
    float pk = __shfl(posf, k, 64);
    s1v += pk * wtpos[k*64 + lane];
  }
  s0[n*64+lane] = se;
  s1[n*64+lane] = s1v;

  __shared__ float sb0[4][64];
  __shared__ float sb1[4][64];
  __shared__ float sq[4];
  sb0[wave][lane] = se;
  sb1[wave][lane] = s1v;
  float q = se*se + s1v*s1v;
  #pragma unroll
  for (int s = 1; s < 64; s <<= 1) q += __shfl_xor(q, s, 64);
  if (lane == 0) sq[wave] = q;
  __syncthreads();
  if (tid < 64){
    part[blockIdx.x*130 + tid] = sb0[0][tid]+sb0[1][tid]+sb0[2][tid]+sb0[3][tid];
  } else if (tid < 128){
    int d = tid - 64;
    part[blockIdx.x*130 + 64 + d] = sb1[0][d]+sb1[1][d]+sb1[2][d]+sb1[3][d];
  } else if (tid == 128){
    part[blockIdx.x*130 + 128] = sq[0]+sq[1]+sq[2]+sq[3];
  }
}

// ---------------- K5: PairNorm stats (1024-thread two-stage reduce) ----------------
__global__ __launch_bounds__(1024) void k5_stats(const float* __restrict__ part, float* __restrict__ stats)
{
  int tid = threadIdx.x;
  __shared__ float s_mu[8][128];
  __shared__ float s_sq[8];
  int c = tid & 127, ch = tid >> 7;
  float a = 0.f;
  for (int b = ch*128; b < ch*128+128; ++b) a += part[b*130 + c];
  s_mu[ch][c] = a;
  if (tid < 8){
    float q = 0.f;
    for (int b = tid*128; b < tid*128+128; ++b) q += part[b*130 + 128];
    s_sq[tid] = q;
  }
  __syncthreads();
  if (tid < 128){
    float m = 0.f;
    #pragma unroll
    for (int j = 0; j < 8; ++j) m += s_mu[j][tid];
    s_mu[0][tid] = m;
    stats[tid] = m / 4096.f;
  }
  __syncthreads();
  if (tid == 0){
    float sq = 0.f;
    #pragma unroll
    for (int j = 0; j < 8; ++j) sq += s_sq[j];
    float mu2 = 0.f;
    for (int i = 0; i < 128; ++i){ float m = s_mu[0][i] / 4096.f; mu2 += m*m; }
    float msq = sq/(4096.f*64.f) - mu2/64.f;
    stats[128] = 1.f / sqrtf(1e-6f + msq);
  }
}

// ---------------- K6: semantic attention + predictor ----------------
__global__ __launch_bounds__(256) void k6_sem(
    const float* __restrict__ s0, const float* __restrict__ s1,
    const float* __restrict__ stats, const float* __restrict__ wtsem,
    const float* __restrict__ sem_b1, const float* __restrict__ sem_w2,
    const float* __restrict__ pred_w, const float* __restrict__ pred_b,
    float* __restrict__ out)
{
  int tid = threadIdx.x;
  int wave = tid >> 6, lane = tid & 63;
  int n = blockIdx.x*4 + wave;
  float rinv = stats[128];
  float a0 = (s0[n*64+lane] - stats[lane]) * rinv;
  float a1 = (s1[n*64+lane] - stats[64+lane]) * rinv;
  float t0 = sem_b1[lane], t1 = t0;
  #pragma unroll
  for (int k = 0; k < 64; ++k){
    float w = wtsem[k*64 + lane];
    t0 += __shfl(a0, k, 64) * w;
    t1 += __shfl(a1, k, 64) * w;
  }
  t0 = tanh_fast(t0); t1 = tanh_fast(t1);
  float w2 = sem_w2[lane];
  float w0 = t0*w2, w1 = t1*w2;
  #pragma unroll
  for (int s = 1; s < 64; s <<= 1){
    w0 += __shfl_xor(w0, s, 64);
    w1 += __shfl_xor(w1, s, 64);
  }
  float mx = fmaxf(w0, w1);
  float e0 = __expf(w0 - mx), e1 = __expf(w1 - mx);
  float denom = e0 + e1 + 1e-10f;
  float b0 = e0/denom, b1 = e1/denom;
  float emb = b0*a0 + b1*a1;
  float pl = emb * pred_w[lane];
  #pragma unroll
  for (int s = 1; s < 64; s <<= 1) pl += __shfl_xor(pl, s, 64);
  if (lane == 0) out[n] = sigm(pl + pred_b[0]);
}

extern "C" void kernel_launch(void* const* d_in, const int* in_sizes, int n_in,
                              void* d_out, int out_size, void* d_ws, size_t ws_size,
                              hipStream_t stream)
{
  (void)in_sizes; (void)n_in; (void)out_size; (void)ws_size;
  const float* x         = (const float*)d_in[0];
  const int*   adj       = (const int*)d_in[1];
  const float* W_ih      = (const float*)d_in[2];
  const float* W_hh      = (const float*)d_in[3];
  const float* b_ih      = (const float*)d_in[4];
  const float* b_hh      = (const float*)d_in[5];
  const float* gat_w     = (const float*)d_in[6];
  const float* gat_wu    = (const float*)d_in[7];
  const float* gat_wv    = (const float*)d_in[8];
  const float* gat_bias  = (const float*)d_in[9];
  const float* proj_w    = (const float*)d_in[10];
  const float* proj_b    = (const float*)d_in[11];
  const float* mlp_self_w= (const float*)d_in[12];
  const float* mlp_self_b= (const float*)d_in[13];
  const float* mlp_pos_w = (const float*)d_in[14];
  const float* mlp_pos_b = (const float*)d_in[15];
  const float* sem_w1    = (const float*)d_in[16];
  const float* sem_b1    = (const float*)d_in[17];
  const float* sem_w2    = (const float*)d_in[18];
  const float* pred_w    = (const float*)d_in[19];
  const float* pred_b    = (const float*)d_in[20];
  float* out = (float*)d_out;
  float* ws  = (float*)d_ws;

  float* h     = ws + 0;         // 262144
  // supb (bf16 [64][4096] = 512KB) overlays the old f32 supt region (1MB)
  unsigned short* supb = (unsigned short*)(ws + 262144);
  float* f1t   = ws + 524288;    // 32768   [8][4096]
  float* f2    = ws + 557056;    // 32768   [4096][8]
  float* posg  = ws + 589824;    // 262144
  float* s0    = ws + 851968;    // 262144
  float* s1    = ws + 1114112;   // 262144
  // adjm overlays s0+s1 (2MB): written by k2c, consumed by k3, dead before k4 writes s0/s1
  unsigned long long* adjm = (unsigned long long*)(ws + 851968);
  float* part  = ws + 1376256;   // 1024*130
  float* bmax  = ws + 1509376;   // 1024*8
  float* maxf1 = ws + 1517568;   // 8
  float* stats = ws + 1517576;   // 129
  float* wtproj= ws + 1517712;   // 4096
  float* wtself= wtproj + 4096;
  float* wtpos = wtself + 4096;
  float* wtsem = wtpos  + 4096;

  k0_prep<<<16, 256, 0, stream>>>(proj_w, mlp_self_w, mlp_pos_w, sem_w1,
                                  wtproj, wtself, wtpos, wtsem);
  k1_gru<<<256, 64, 0, stream>>>(x, W_ih, W_hh, b_ih, b_hh, h);
  k2_sup<<<1024, 256, 0, stream>>>(h, gat_w, gat_wu, gat_wv, supb, f1t, f2, bmax);
  k2b_max<<<1, 256, 0, stream>>>(bmax, maxf1);
  k2c_pack<<<1024, 256, 0, stream>>>(adj, adjm);
  k3_gat<<<1024, 128, 0, stream>>>(adjm, supb, f1t, f2, maxf1, posg);
  k4_mix<<<1024, 256, 0, stream>>>(h, posg, gat_bias, proj_b, wtproj, wtself, wtpos,
                                   mlp_self_b, mlp_pos_b, s0, s1, part);
  k5_stats<<<1, 1024, 0, stream>>>(part, stats);
  k6_sem<<<1024, 256, 0, stream>>>(s0, s1, stats, wtsem, sem_b1, sem_w2, pred_w, pred_b, out);
}

// Round 13
// 254.187 us; speedup vs baseline: 2.1129x; 1.0241x over previous
//
#include <hip/hip_runtime.h>
#include <math.h>

#define NN 4096
#define TT 32
#define FF 7
#define HH 64
#define NHEAD 8
#define DOUT 8

typedef short bf16x8 __attribute__((ext_vector_type(8)));
typedef float f32x4 __attribute__((ext_vector_type(4)));

__device__ __forceinline__ float sigm(float x){
  x = fminf(fmaxf(x, -30.f), 30.f);
  return 1.f / (1.f + __expf(-x));
}
__device__ __forceinline__ float tanh_fast(float x){
  x = fminf(fmaxf(x, -15.f), 15.f);
  float e = __expf(2.f*x);
  return (e - 1.f) / (e + 1.f);
}
__device__ __forceinline__ unsigned short bf16rne(float f){
  unsigned u = __float_as_uint(f);
  u += 0x7fffu + ((u >> 16) & 1u);
  return (unsigned short)(u >> 16);
}
__device__ __forceinline__ unsigned bfpack2(float a, float b){
  return (unsigned)bf16rne(a) | ((unsigned)bf16rne(b) << 16);
}
__device__ __forceinline__ unsigned cvtpk_bf16(float a, float b){
  unsigned r;
  asm("v_cvt_pk_bf16_f32 %0, %1, %2" : "=v"(r) : "v"(a), "v"(b));
  return r;
}

// ---------------- K0: transpose small 64x64 weights to k-major ----------------
__global__ void k0_prep(const float* __restrict__ pw, const float* __restrict__ msw,
                        const float* __restrict__ mpw, const float* __restrict__ sw1,
                        float* __restrict__ wtproj, float* __restrict__ wtself,
                        float* __restrict__ wtpos, float* __restrict__ wtsem)
{
  int tid = threadIdx.x + blockIdx.x*blockDim.x;
  if (tid < 4096){
    int d = tid >> 6, k = tid & 63;
    wtproj[k*64+d] = pw[tid];
    wtself[k*64+d] = msw[tid];
    wtpos[k*64+d]  = mpw[tid];
    wtsem[k*64+d]  = sw1[tid];
  }
}

// ---------------- K1: GRU encoder via MFMA, weights resident in VGPRs ----------------
__global__ __launch_bounds__(64) void k1_gru(
    const float* __restrict__ x,      // [N][T][F]
    const float* __restrict__ Wih,    // [192][7]
    const float* __restrict__ Whh,    // [192][64]
    const float* __restrict__ bih, const float* __restrict__ bhh,
    float* __restrict__ hout)         // [N][64]
{
  __shared__ __align__(16) short s_xb[32][16][8]; // 8KB   bf16 x (k=7 -> 1.0)
  __shared__ __align__(16) short s_hb[16][72];    // 2.25KB bf16 h (pad 72)

  int lane = threadIdx.x;
  int nb = blockIdx.x * 16;
  int row = lane & 15;          // A: gate row within tile / B,D: node column
  int kg  = lane >> 4;          // k-group (8 elements each)

  union U { bf16x8 v; uint4 q; };

  // ---- W_hh A-fragments -> registers ----
  bf16x8 whh_f[24];
  #pragma unroll
  for (int T = 0; T < 12; ++T){
    #pragma unroll
    for (int c = 0; c < 2; ++c){
      int g = T*16 + row;
      const float* wp = Whh + g*64 + c*32 + kg*8;
      U u;
      u.q.x = bfpack2(wp[0], wp[1]);
      u.q.y = bfpack2(wp[2], wp[3]);
      u.q.z = bfpack2(wp[4], wp[5]);
      u.q.w = bfpack2(wp[6], wp[7]);
      whh_f[T*2 + c] = u.v;
    }
  }
  // ---- W_ih A-fragments (k<7 weights, k==7 folded bias, k>=8 zero) -> registers ----
  bf16x8 wih_f[12];
  #pragma unroll
  for (int T = 0; T < 12; ++T){
    int g = T*16 + row;
    float bias = (T < 8) ? (bih[g] + bhh[g]) : bih[g];   // b_hhn NOT folded (inside r*())
    float f[8];
    #pragma unroll
    for (int j = 0; j < 8; ++j){
      int k = kg*8 + j;
      f[j] = (k < 7) ? Wih[g*7 + k] : ((k == 7) ? bias : 0.f);
    }
    U u;
    u.q.x = bfpack2(f[0], f[1]); u.q.y = bfpack2(f[2], f[3]);
    u.q.z = bfpack2(f[4], f[5]); u.q.w = bfpack2(f[6], f[7]);
    wih_f[T] = u.v;
  }
  // ---- stage x as bf16 B-lines (k==7 -> 1.0) ----
  for (int s = lane; s < 4096; s += 64){
    int t = s >> 7, node = (s >> 3) & 15, k = s & 7;
    float v = (k < 7) ? x[(size_t)(nb + node)*224 + t*7 + k] : ((k == 7) ? 1.f : 0.f);
    s_xb[t][node][k] = (short)bf16rne(v);
  }
  for (int i = lane; i < 576; i += 64) ((unsigned*)s_hb)[i] = 0u;

  float bhn_[4][4];
  #pragma unroll
  for (int T = 0; T < 4; ++T)
    #pragma unroll
    for (int j = 0; j < 4; ++j)
      bhn_[T][j] = bhh[128 + T*16 + kg*4 + j];

  float hreg[4][4];
  #pragma unroll
  for (int T = 0; T < 4; ++T)
    #pragma unroll
    for (int j = 0; j < 4; ++j) hreg[T][j] = 0.f;

  f32x4 z4 = {0.f, 0.f, 0.f, 0.f};

  for (int t = 0; t < TT; ++t){
    bf16x8 bx = {0,0,0,0,0,0,0,0};
    if (lane < 16) bx = *(const bf16x8*)&s_xb[t][row][0];
    bf16x8 bh0 = *(const bf16x8*)&s_hb[row][kg*8];
    bf16x8 bh1 = *(const bf16x8*)&s_hb[row][32 + kg*8];

    #pragma unroll
    for (int Tr = 0; Tr < 4; ++Tr){
      f32x4 aR = __builtin_amdgcn_mfma_f32_16x16x32_bf16(wih_f[Tr], bx, z4, 0, 0, 0);
      aR = __builtin_amdgcn_mfma_f32_16x16x32_bf16(whh_f[Tr*2+0], bh0, aR, 0, 0, 0);
      aR = __builtin_amdgcn_mfma_f32_16x16x32_bf16(whh_f[Tr*2+1], bh1, aR, 0, 0, 0);
      f32x4 aZ = __builtin_amdgcn_mfma_f32_16x16x32_bf16(wih_f[4+Tr], bx, z4, 0, 0, 0);
      aZ = __builtin_amdgcn_mfma_f32_16x16x32_bf16(whh_f[(4+Tr)*2+0], bh0, aZ, 0, 0, 0);
      aZ = __builtin_amdgcn_mfma_f32_16x16x32_bf16(whh_f[(4+Tr)*2+1], bh1, aZ, 0, 0, 0);
      f32x4 aNx = __builtin_amdgcn_mfma_f32_16x16x32_bf16(wih_f[8+Tr], bx, z4, 0, 0, 0);
      f32x4 aNh = __builtin_amdgcn_mfma_f32_16x16x32_bf16(whh_f[(8+Tr)*2+0], bh0, z4, 0, 0, 0);
      aNh = __builtin_amdgcn_mfma_f32_16x16x32_bf16(whh_f[(8+Tr)*2+1], bh1, aNh, 0, 0, 0);
      #pragma unroll
      for (int j = 0; j < 4; ++j){
        float rr = sigm(aR[j]);
        float zz = sigm(aZ[j]);
        float nn = tanh_fast(aNx[j] + rr*(aNh[j] + bhn_[Tr][j]));
        hreg[Tr][j] = (1.f - zz)*nn + zz*hreg[Tr][j];
      }
    }
    #pragma unroll
    for (int Tr = 0; Tr < 4; ++Tr){
      uint2 p;
      p.x = bfpack2(hreg[Tr][0], hreg[Tr][1]);
      p.y = bfpack2(hreg[Tr][2], hreg[Tr][3]);
      *(uint2*)&s_hb[row][Tr*16 + kg*4] = p;
    }
  }

  #pragma unroll
  for (int Tr = 0; Tr < 4; ++Tr)
    #pragma unroll
    for (int j = 0; j < 4; ++j)
      hout[(size_t)(nb + row)*64 + Tr*16 + kg*4 + j] = hreg[Tr][j];
}

// ---------------- K2: supb (bf16, transposed) = h@gat_w, f1t/f2, block f1 max ----------------
__global__ __launch_bounds__(256) void k2_sup(
    const float* __restrict__ h, const float* __restrict__ gat_w,
    const float* __restrict__ wu, const float* __restrict__ wv,
    unsigned short* __restrict__ supb,  // [64][N] bf16, row = hh*8+o
    float* __restrict__ f1t,            // [8][N]
    float* __restrict__ f2,             // [N][8]
    float* __restrict__ bmax)
{
  int tid = threadIdx.x;
  int wave = tid >> 6, lane = tid & 63;
  int n = blockIdx.x*4 + wave;
  float hreg = h[n*64 + lane];
  float acc = 0.f;
  #pragma unroll
  for (int k = 0; k < 64; ++k){
    float hk = __shfl(hreg, k, 64);
    acc += hk * gat_w[k*64 + lane];
  }
  supb[(size_t)lane*NN + n] = bf16rne(acc);   // bf16: k3 consumes as MFMA B-operand
  float p1 = acc * wu[lane];
  float p2 = acc * wv[lane];
  #pragma unroll
  for (int s = 1; s < 8; s <<= 1){
    p1 += __shfl_xor(p1, s, 64);
    p2 += __shfl_xor(p2, s, 64);
  }
  int hh = lane >> 3;
  __shared__ float s_m[4][8];
  if ((lane & 7) == 0){
    f1t[(size_t)hh*NN + n] = p1;
    f2[n*8 + hh] = p2;
    s_m[wave][hh] = p1;
  }
  __syncthreads();
  if (tid < 8){
    float mm = fmaxf(fmaxf(s_m[0][tid], s_m[1][tid]), fmaxf(s_m[2][tid], s_m[3][tid]));
    bmax[blockIdx.x*8 + tid] = mm;
  }
}

__global__ __launch_bounds__(256) void k2b_max(const float* __restrict__ bmax, float* __restrict__ maxf1)
{
  int tid = threadIdx.x;
  int hh = tid & 7, chunk = tid >> 3;   // 32 chunks of 32 blocks
  float m = -1e30f;
  for (int b = chunk*32; b < chunk*32+32; ++b) m = fmaxf(m, bmax[b*8 + hh]);
  __shared__ float sm[256];
  sm[tid] = m;
  __syncthreads();
  if (tid < 8){
    float mm = -1e30f;
    for (int c = 0; c < 32; ++c) mm = fmaxf(mm, sm[c*8 + tid]);
    maxf1[tid] = mm;
  }
}

// ---------------- K2c: pack adjacency rows into 64-bit masks ----------------
__global__ __launch_bounds__(256) void k2c_pack(const int* __restrict__ adj,
                                               unsigned long long* __restrict__ adjm)
{
  int lane = threadIdx.x & 63, wave = threadIdx.x >> 6;
  int row = blockIdx.x*4 + wave;
  const int* ap = adj + (size_t)row*NN;
  #pragma unroll 8
  for (int s = 0; s < 64; ++s){
    unsigned long long m = __ballot(ap[s*64 + lane] != 0);
    if (lane == 0) adjm[(size_t)row*64 + s] = m;
  }
}

// ---------------- K3: flash-style MFMA GAT, 4-way j-split ----------------
// 2048 blocks x 256 threads (4 waves); block = (16-row tile, 1 head); wave js
// handles j in [js*1024, (js+1)*1024) as 32 chunks of 32 j. Partial accumulators
// (incl. col-8 denominator) merged through 4KB LDS; wave 0 normalizes+stores.
// Round-12: 2 waves/SIMD left VALU 44% busy (latency-exposed); 8 waves/SIMD saturates.
__global__ __launch_bounds__(256) void k3_gat(
    const unsigned long long* __restrict__ adjm,   // [N][64]
    const unsigned short* __restrict__ supb,       // [64][N] bf16
    const float* __restrict__ f1t,                 // [8][N]
    const float* __restrict__ f2,                  // [N][8]
    const float* __restrict__ maxf1, float* __restrict__ posg)
{
  __shared__ f32x4 s_acc[4][64];        // 4KB merge buffer
  int tid = threadIdx.x;
  int lane = tid & 63, js = tid >> 6;
  int gid = blockIdx.x;                 // 0..2047
  int ib = gid >> 3, h = gid & 7;
  int i0 = ib*16;
  int col = lane & 15;                  // A-row during build; B/D column after
  int kg  = lane >> 4;

  float f2v = f2[(size_t)(i0+col)*8 + h];
  float lg = maxf1[h] + f2v;
  lg = fmaxf(lg, 0.2f*lg);
  float M = fmaxf(lg, 0.f);             // upper bound on reference rowmax

  const unsigned long long* mrow = adjm + (size_t)(i0+col)*64;
  const float* f1p = f1t + (size_t)h*NN;
  const unsigned short* bsrc = supb + (size_t)(h*8 + (col & 7))*NN;
  unsigned bge8 = (col >= 8) ? 0xffffffffu : 0u;   // lanes feeding the sum column

  f32x4 acc = {0.f, 0.f, 0.f, 0.f};

  #pragma unroll 2
  for (int cc = 0; cc < 32; ++cc){
    int c = js*32 + cc;
    int j8 = c*32 + kg*8;
    unsigned long long mw = mrow[c >> 1];
    unsigned mb = (unsigned)(mw >> (((c & 1) << 5) + (kg << 3)));
    float4 fa = *(const float4*)(f1p + j8);
    float4 fb = *(const float4*)(f1p + j8 + 4);

    float p[8];
    p[0]=fa.x; p[1]=fa.y; p[2]=fa.z; p[3]=fa.w;
    p[4]=fb.x; p[5]=fb.y; p[6]=fb.z; p[7]=fb.w;
    #pragma unroll
    for (int e = 0; e < 8; ++e){
      float logit = p[e] + f2v;
      float lr = fmaxf(logit, 0.2f*logit);
      float pe = __expf(lr - M);
      p[e] = (mb & (1u << e)) ? pe : 0.f;
    }
    union { bf16x8 v; unsigned u[4]; } A;
    A.u[0] = cvtpk_bf16(p[0], p[1]);
    A.u[1] = cvtpk_bf16(p[2], p[3]);
    A.u[2] = cvtpk_bf16(p[4], p[5]);
    A.u[3] = cvtpk_bf16(p[6], p[7]);

    union { bf16x8 v; unsigned u[4]; } B;
    uint4 ld = *(const uint4*)(bsrc + j8);
    B.u[0] = bge8 ? 0x3f803f80u : ld.x;   // col>=8: bf16 1.0 (col 8 = denominator)
    B.u[1] = bge8 ? 0x3f803f80u : ld.y;
    B.u[2] = bge8 ? 0x3f803f80u : ld.z;
    B.u[3] = bge8 ? 0x3f803f80u : ld.w;

    acc = __builtin_amdgcn_mfma_f32_16x16x32_bf16(A.v, B.v, acc, 0, 0, 0);
  }

  s_acc[js][lane] = acc;
  __syncthreads();
  if (js == 0){
    f32x4 a1 = s_acc[1][lane], a2 = s_acc[2][lane], a3 = s_acc[3][lane];
    #pragma unroll
    for (int j = 0; j < 4; ++j) acc[j] += a1[j] + a2[j] + a3[j];

    // denominator lives in column 8 of this kg-group: lane (lane&48)+8
    int slane = (lane & 48) + 8;
    #pragma unroll
    for (int r4 = 0; r4 < 4; ++r4){
      float sv = __shfl(acc[r4], slane, 64);
      float inv = 1.f / fmaxf(sv, 1e-10f);
      if (col < 8)
        posg[(size_t)(i0 + kg*4 + r4)*64 + h*8 + col] = acc[r4] * inv;
    }
  }
}

// ---------------- K4: residual proj + the two MLP channels + PairNorm partials ----------------
__global__ __launch_bounds__(256) void k4_mix(
    const float* __restrict__ h, const float* __restrict__ posg,
    const float* __restrict__ gat_bias, const float* __restrict__ proj_b,
    const float* __restrict__ wtproj, const float* __restrict__ wtself,
    const float* __restrict__ wtpos,
    const float* __restrict__ mlp_self_b, const float* __restrict__ mlp_pos_b,
    float* __restrict__ s0, float* __restrict__ s1, float* __restrict__ part)
{
  int tid = threadIdx.x;
  int wave = tid >> 6, lane = tid & 63;
  int n = blockIdx.x*4 + wave;
  float hreg = h[n*64 + lane];
  float pr = proj_b[lane];
  float se = mlp_self_b[lane];
  #pragma unroll
  for (int k = 0; k < 64; ++k){
    float hk = __shfl(hreg, k, 64);
    pr += hk * wtproj[k*64 + lane];
    se += hk * wtself[k*64 + lane];
  }
  float posf = posg[n*64 + lane] + gat_bias[lane] + pr;
  float s1v = mlp_pos_b[lane];
  #pragma unroll
  for (int k = 0; k < 64; ++k){
    float pk = __shfl(posf, k, 64);
    s1v += pk * wtpos[k*64 + lane];
  }
  s0[n*64+lane] = se;
  s1[n*64+lane] = s1v;

  __shared__ float sb0[4][64];
  __shared__ float sb1[4][64];
  __shared__ float sq[4];
  sb0[wave][lane] = se;
  sb1[wave][lane] = s1v;
  float q = se*se + s1v*s1v;
  #pragma unroll
  for (int s = 1; s < 64; s <<= 1) q += __shfl_xor(q, s, 64);
  if (lane == 0) sq[wave] = q;
  __syncthreads();
  if (tid < 64){
    part[blockIdx.x*130 + tid] = sb0[0][tid]+sb0[1][tid]+sb0[2][tid]+sb0[3][tid];
  } else if (tid < 128){
    int d = tid - 64;
    part[blockIdx.x*130 + 64 + d] = sb1[0][d]+sb1[1][d]+sb1[2][d]+sb1[3][d];
  } else if (tid == 128){
    part[blockIdx.x*130 + 128] = sq[0]+sq[1]+sq[2]+sq[3];
  }
}

// ---------------- K5: PairNorm stats (1024-thread two-stage reduce) ----------------
__global__ __launch_bounds__(1024) void k5_stats(const float* __restrict__ part, float* __restrict__ stats)
{
  int tid = threadIdx.x;
  __shared__ float s_mu[8][128];
  __shared__ float s_sq[8];
  int c = tid & 127, ch = tid >> 7;
  float a = 0.f;
  for (int b = ch*128; b < ch*128+128; ++b) a += part[b*130 + c];
  s_mu[ch][c] = a;
  if (tid < 8){
    float q = 0.f;
    for (int b = tid*128; b < tid*128+128; ++b) q += part[b*130 + 128];
    s_sq[tid] = q;
  }
  __syncthreads();
  if (tid < 128){
    float m = 0.f;
    #pragma unroll
    for (int j = 0; j < 8; ++j) m += s_mu[j][tid];
    s_mu[0][tid] = m;
    stats[tid] = m / 4096.f;
  }
  __syncthreads();
  if (tid == 0){
    float sq = 0.f;
    #pragma unroll
    for (int j = 0; j < 8; ++j) sq += s_sq[j];
    float mu2 = 0.f;
    for (int i = 0; i < 128; ++i){ float m = s_mu[0][i] / 4096.f; mu2 += m*m; }
    float msq = sq/(4096.f*64.f) - mu2/64.f;
    stats[128] = 1.f / sqrtf(1e-6f + msq);
  }
}

// ---------------- K6: semantic attention + predictor ----------------
__global__ __launch_bounds__(256) void k6_sem(
    const float* __restrict__ s0, const float* __restrict__ s1,
    const float* __restrict__ stats, const float* __restrict__ wtsem,
    const float* __restrict__ sem_b1, const float* __restrict__ sem_w2,
    const float* __restrict__ pred_w, const float* __restrict__ pred_b,
    float* __restrict__ out)
{
  int tid = threadIdx.x;
  int wave = tid >> 6, lane = tid & 63;
  int n = blockIdx.x*4 + wave;
  float rinv = stats[128];
  float a0 = (s0[n*64+lane] - stats[lane]) * rinv;
  float a1 = (s1[n*64+lane] - stats[64+lane]) * rinv;
  float t0 = sem_b1[lane], t1 = t0;
  #pragma unroll
  for (int k = 0; k < 64; ++k){
    float w = wtsem[k*64 + lane];
    t0 += __shfl(a0, k, 64) * w;
    t1 += __shfl(a1, k, 64) * w;
  }
  t0 = tanh_fast(t0); t1 = tanh_fast(t1);
  float w2 = sem_w2[lane];
  float w0 = t0*w2, w1 = t1*w2;
  #pragma unroll
  for (int s = 1; s < 64; s <<= 1){
    w0 += __shfl_xor(w0, s, 64);
    w1 += __shfl_xor(w1, s, 64);
  }
  float mx = fmaxf(w0, w1);
  float e0 = __expf(w0 - mx), e1 = __expf(w1 - mx);
  float denom = e0 + e1 + 1e-10f;
  float b0 = e0/denom, b1 = e1/denom;
  float emb = b0*a0 + b1*a1;
  float pl = emb * pred_w[lane];
  #pragma unroll
  for (int s = 1; s < 64; s <<= 1) pl += __shfl_xor(pl, s, 64);
  if (lane == 0) out[n] = sigm(pl + pred_b[0]);
}

extern "C" void kernel_launch(void* const* d_in, const int* in_sizes, int n_in,
                              void* d_out, int out_size, void* d_ws, size_t ws_size,
                              hipStream_t stream)
{
  (void)in_sizes; (void)n_in; (void)out_size; (void)ws_size;
  const float* x         = (const float*)d_in[0];
  const int*   adj       = (const int*)d_in[1];
  const float* W_ih      = (const float*)d_in[2];
  const float* W_hh      = (const float*)d_in[3];
  const float* b_ih      = (const float*)d_in[4];
  const float* b_hh      = (const float*)d_in[5];
  const float* gat_w     = (const float*)d_in[6];
  const float* gat_wu    = (const float*)d_in[7];
  const float* gat_wv    = (const float*)d_in[8];
  const float* gat_bias  = (const float*)d_in[9];
  const float* proj_w    = (const float*)d_in[10];
  const float* proj_b    = (const float*)d_in[11];
  const float* mlp_self_w= (const float*)d_in[12];
  const float* mlp_self_b= (const float*)d_in[13];
  const float* mlp_pos_w = (const float*)d_in[14];
  const float* mlp_pos_b = (const float*)d_in[15];
  const float* sem_w1    = (const float*)d_in[16];
  const float* sem_b1    = (const float*)d_in[17];
  const float* sem_w2    = (const float*)d_in[18];
  const float* pred_w    = (const float*)d_in[19];
  const float* pred_b    = (const float*)d_in[20];
  float* out = (float*)d_out;
  float* ws  = (float*)d_ws;

  float* h     = ws + 0;         // 262144
  // supb (bf16 [64][4096] = 512KB) overlays the old f32 supt region (1MB)
  unsigned short* supb = (unsigned short*)(ws + 262144);
  float* f1t   = ws + 524288;    // 32768   [8][4096]
  float* f2    = ws + 557056;    // 32768   [4096][8]
  float* posg  = ws + 589824;    // 262144
  float* s0    = ws + 851968;    // 262144
  float* s1    = ws + 1114112;   // 262144
  // adjm overlays s0+s1 (2MB): written by k2c, consumed by k3, dead before k4 writes s0/s1
  unsigned long long* adjm = (unsigned long long*)(ws + 851968);
  float* part  = ws + 1376256;   // 1024*130
  float* bmax  = ws + 1509376;   // 1024*8
  float* maxf1 = ws + 1517568;   // 8
  float* stats = ws + 1517576;   // 129
  float* wtproj= ws + 1517712;   // 4096
  float* wtself= wtproj + 4096;
  float* wtpos = wtself + 4096;
  float* wtsem = wtpos  + 4096;

  k0_prep<<<16, 256, 0, stream>>>(proj_w, mlp_self_w, mlp_pos_w, sem_w1,
                                  wtproj, wtself, wtpos, wtsem);
  k1_gru<<<256, 64, 0, stream>>>(x, W_ih, W_hh, b_ih, b_hh, h);
  k2_sup<<<1024, 256, 0, stream>>>(h, gat_w, gat_wu, gat_wv, supb, f1t, f2, bmax);
  k2b_max<<<1, 256, 0, stream>>>(bmax, maxf1);
  k2c_pack<<<1024, 256, 0, stream>>>(adj, adjm);
  k3_gat<<<2048, 256, 0, stream>>>(adjm, supb, f1t, f2, maxf1, posg);
  k4_mix<<<1024, 256, 0, stream>>>(h, posg, gat_bias, proj_b, wtproj, wtself, wtpos,
                                   mlp_self_b, mlp_pos_b, s0, s1, part);
  k5_stats<<<1, 1024, 0, stream>>>(part, stats);
  k6_sem<<<1024, 256, 0, stream>>>(s0, s1, stats, wtsem, sem_b1, sem_w2, pred_w, pred_b, out);
}

// Round 14
// 252.997 us; speedup vs baseline: 2.1228x; 1.0047x over previous
//
#include <hip/hip_runtime.h>
#include <math.h>

#define NN 4096
#define TT 32
#define FF 7
#define HH 64
#define NHEAD 8
#define DOUT 8

typedef short bf16x8 __attribute__((ext_vector_type(8)));
typedef float f32x4 __attribute__((ext_vector_type(4)));

__device__ __forceinline__ float sigm(float x){
  x = fminf(fmaxf(x, -30.f), 30.f);
  return 1.f / (1.f + __expf(-x));
}
__device__ __forceinline__ float tanh_fast(float x){
  x = fminf(fmaxf(x, -15.f), 15.f);
  float e = __expf(2.f*x);
  return (e - 1.f) / (e + 1.f);
}
__device__ __forceinline__ unsigned short bf16rne(float f){
  unsigned u = __float_as_uint(f);
  u += 0x7fffu + ((u >> 16) & 1u);
  return (unsigned short)(u >> 16);
}
__device__ __forceinline__ unsigned bfpack2(float a, float b){
  return (unsigned)bf16rne(a) | ((unsigned)bf16rne(b) << 16);
}
__device__ __forceinline__ unsigned cvtpk_bf16(float a, float b){
  unsigned r;
  asm("v_cvt_pk_bf16_f32 %0, %1, %2" : "=v"(r) : "v"(a), "v"(b));
  return r;
}

// ---------------- K0: transpose small 64x64 weights to k-major ----------------
__global__ void k0_prep(const float* __restrict__ pw, const float* __restrict__ msw,
                        const float* __restrict__ mpw, const float* __restrict__ sw1,
                        float* __restrict__ wtproj, float* __restrict__ wtself,
                        float* __restrict__ wtpos, float* __restrict__ wtsem)
{
  int tid = threadIdx.x + blockIdx.x*blockDim.x;
  if (tid < 4096){
    int d = tid >> 6, k = tid & 63;
    wtproj[k*64+d] = pw[tid];
    wtself[k*64+d] = msw[tid];
    wtpos[k*64+d]  = mpw[tid];
    wtsem[k*64+d]  = sw1[tid];
  }
}

// ---------------- K0b: pre-pack GRU weight MFMA fragments (bf16 lines) ----------------
// Layout exactly matches k1's per-lane fragment read: line f, lane l -> uint4.
// whhF: f = T*2+c (T gate-tile 0..11, c K-chunk 0..1), row=l&15, kg=l>>4.
// wihF: f = T; k<7 weights, k==7 folded bias, k>=8 zero.
__global__ __launch_bounds__(256) void k0b_frag(
    const float* __restrict__ Wih, const float* __restrict__ Whh,
    const float* __restrict__ bih, const float* __restrict__ bhh,
    uint4* __restrict__ whhF, uint4* __restrict__ wihF)
{
  int idx = blockIdx.x*256 + threadIdx.x;     // 0..2303
  if (idx < 24*64){
    int f = idx >> 6, lane = idx & 63;
    int T = f >> 1, c = f & 1;
    int g = T*16 + (lane & 15);
    const float* wp = Whh + g*64 + c*32 + (lane >> 4)*8;
    uint4 v;
    v.x = bfpack2(wp[0], wp[1]);
    v.y = bfpack2(wp[2], wp[3]);
    v.z = bfpack2(wp[4], wp[5]);
    v.w = bfpack2(wp[6], wp[7]);
    whhF[idx] = v;
  } else if (idx < 36*64){
    int i2 = idx - 24*64;
    int T = i2 >> 6, lane = i2 & 63;
    int g = T*16 + (lane & 15);
    int kg = lane >> 4;
    float bias = (T < 8) ? (bih[g] + bhh[g]) : bih[g];   // b_hhn NOT folded (inside r*())
    float f8[8];
    #pragma unroll
    for (int j = 0; j < 8; ++j){
      int k = kg*8 + j;
      f8[j] = (k < 7) ? Wih[g*7 + k] : ((k == 7) ? bias : 0.f);
    }
    uint4 v;
    v.x = bfpack2(f8[0], f8[1]); v.y = bfpack2(f8[2], f8[3]);
    v.z = bfpack2(f8[4], f8[5]); v.w = bfpack2(f8[6], f8[7]);
    wihF[i2] = v;
  }
}

// ---------------- K1: GRU encoder via MFMA, fragments loaded as single dwordx4 ----------------
// 256 blocks x 1 wave; wave owns 16 nodes. Round-13 failure: compiler refused 144
// live VGPRs (VGPR_Count 156) and REMATERIALIZED each fragment from global as
// 8 scalar loads + 4 packs per t (~288 loads/t = the 6500 cyc/t). Now fragments
// come from the k0b pre-packed buffer as ONE coalesced dwordx4 each, and
// __launch_bounds__(64,1) raises the register budget so they stay resident.
__global__ __launch_bounds__(64, 1) void k1_gru(
    const float* __restrict__ x,      // [N][T][F]
    const uint4* __restrict__ whhF,   // [24][64]
    const uint4* __restrict__ wihF,   // [12][64]
    const float* __restrict__ bhh,
    float* __restrict__ hout)         // [N][64]
{
  __shared__ __align__(16) short s_xb[32][16][8]; // 8KB   bf16 x (k=7 -> 1.0)
  __shared__ __align__(16) short s_hb[16][72];    // 2.25KB bf16 h (pad 72)

  int lane = threadIdx.x;
  int nb = blockIdx.x * 16;
  int row = lane & 15;          // A: gate row within tile / B,D: node column
  int kg  = lane >> 4;          // k-group (8 elements each)

  union U { bf16x8 v; uint4 q; };

  bf16x8 whh_f[24];
  #pragma unroll
  for (int i = 0; i < 24; ++i){ U u; u.q = whhF[i*64 + lane]; whh_f[i] = u.v; }
  bf16x8 wih_f[12];
  #pragma unroll
  for (int i = 0; i < 12; ++i){ U u; u.q = wihF[i*64 + lane]; wih_f[i] = u.v; }

  // ---- stage x as bf16 B-lines (k==7 -> 1.0) ----
  for (int s = lane; s < 4096; s += 64){
    int t = s >> 7, node = (s >> 3) & 15, k = s & 7;
    float v = (k < 7) ? x[(size_t)(nb + node)*224 + t*7 + k] : ((k == 7) ? 1.f : 0.f);
    s_xb[t][node][k] = (short)bf16rne(v);
  }
  for (int i = lane; i < 576; i += 64) ((unsigned*)s_hb)[i] = 0u;

  float bhn_[4][4];
  #pragma unroll
  for (int T = 0; T < 4; ++T)
    #pragma unroll
    for (int j = 0; j < 4; ++j)
      bhn_[T][j] = bhh[128 + T*16 + kg*4 + j];

  float hreg[4][4];
  #pragma unroll
  for (int T = 0; T < 4; ++T)
    #pragma unroll
    for (int j = 0; j < 4; ++j) hreg[T][j] = 0.f;

  f32x4 z4 = {0.f, 0.f, 0.f, 0.f};

  for (int t = 0; t < TT; ++t){
    bf16x8 bx = {0,0,0,0,0,0,0,0};
    if (lane < 16) bx = *(const bf16x8*)&s_xb[t][row][0];
    bf16x8 bh0 = *(const bf16x8*)&s_hb[row][kg*8];
    bf16x8 bh1 = *(const bf16x8*)&s_hb[row][32 + kg*8];

    #pragma unroll
    for (int Tr = 0; Tr < 4; ++Tr){
      f32x4 aR = __builtin_amdgcn_mfma_f32_16x16x32_bf16(wih_f[Tr], bx, z4, 0, 0, 0);
      aR = __builtin_amdgcn_mfma_f32_16x16x32_bf16(whh_f[Tr*2+0], bh0, aR, 0, 0, 0);
      aR = __builtin_amdgcn_mfma_f32_16x16x32_bf16(whh_f[Tr*2+1], bh1, aR, 0, 0, 0);
      f32x4 aZ = __builtin_amdgcn_mfma_f32_16x16x32_bf16(wih_f[4+Tr], bx, z4, 0, 0, 0);
      aZ = __builtin_amdgcn_mfma_f32_16x16x32_bf16(whh_f[(4+Tr)*2+0], bh0, aZ, 0, 0, 0);
      aZ = __builtin_amdgcn_mfma_f32_16x16x32_bf16(whh_f[(4+Tr)*2+1], bh1, aZ, 0, 0, 0);
      f32x4 aNx = __builtin_amdgcn_mfma_f32_16x16x32_bf16(wih_f[8+Tr], bx, z4, 0, 0, 0);
      f32x4 aNh = __builtin_amdgcn_mfma_f32_16x16x32_bf16(whh_f[(8+Tr)*2+0], bh0, z4, 0, 0, 0);
      aNh = __builtin_amdgcn_mfma_f32_16x16x32_bf16(whh_f[(8+Tr)*2+1], bh1, aNh, 0, 0, 0);
      #pragma unroll
      for (int j = 0; j < 4; ++j){
        float rr = sigm(aR[j]);
        float zz = sigm(aZ[j]);
        float nn = tanh_fast(aNx[j] + rr*(aNh[j] + bhn_[Tr][j]));
        hreg[Tr][j] = (1.f - zz)*nn + zz*hreg[Tr][j];
      }
    }
    #pragma unroll
    for (int Tr = 0; Tr < 4; ++Tr){
      uint2 p;
      p.x = bfpack2(hreg[Tr][0], hreg[Tr][1]);
      p.y = bfpack2(hreg[Tr][2], hreg[Tr][3]);
      *(uint2*)&s_hb[row][Tr*16 + kg*4] = p;
    }
  }

  #pragma unroll
  for (int Tr = 0; Tr < 4; ++Tr)
    #pragma unroll
    for (int j = 0; j < 4; ++j)
      hout[(size_t)(nb + row)*64 + Tr*16 + kg*4 + j] = hreg[Tr][j];
}

// ---------------- K2: supb (bf16, transposed) = h@gat_w, f1t/f2, block f1 max ----------------
__global__ __launch_bounds__(256) void k2_sup(
    const float* __restrict__ h, const float* __restrict__ gat_w,
    const float* __restrict__ wu, const float* __restrict__ wv,
    unsigned short* __restrict__ supb,  // [64][N] bf16, row = hh*8+o
    float* __restrict__ f1t,            // [8][N]
    float* __restrict__ f2,             // [N][8]
    float* __restrict__ bmax)
{
  int tid = threadIdx.x;
  int wave = tid >> 6, lane = tid & 63;
  int n = blockIdx.x*4 + wave;
  float hreg = h[n*64 + lane];
  float acc = 0.f;
  #pragma unroll
  for (int k = 0; k < 64; ++k){
    float hk = __shfl(hreg, k, 64);
    acc += hk * gat_w[k*64 + lane];
  }
  supb[(size_t)lane*NN + n] = bf16rne(acc);   // bf16: k3 consumes as MFMA B-operand
  float p1 = acc * wu[lane];
  float p2 = acc * wv[lane];
  #pragma unroll
  for (int s = 1; s < 8; s <<= 1){
    p1 += __shfl_xor(p1, s, 64);
    p2 += __shfl_xor(p2, s, 64);
  }
  int hh = lane >> 3;
  __shared__ float s_m[4][8];
  if ((lane & 7) == 0){
    f1t[(size_t)hh*NN + n] = p1;
    f2[n*8 + hh] = p2;
    s_m[wave][hh] = p1;
  }
  __syncthreads();
  if (tid < 8){
    float mm = fmaxf(fmaxf(s_m[0][tid], s_m[1][tid]), fmaxf(s_m[2][tid], s_m[3][tid]));
    bmax[blockIdx.x*8 + tid] = mm;
  }
}

__global__ __launch_bounds__(256) void k2b_max(const float* __restrict__ bmax, float* __restrict__ maxf1)
{
  int tid = threadIdx.x;
  int hh = tid & 7, chunk = tid >> 3;   // 32 chunks of 32 blocks
  float m = -1e30f;
  for (int b = chunk*32; b < chunk*32+32; ++b) m = fmaxf(m, bmax[b*8 + hh]);
  __shared__ float sm[256];
  sm[tid] = m;
  __syncthreads();
  if (tid < 8){
    float mm = -1e30f;
    for (int c = 0; c < 32; ++c) mm = fmaxf(mm, sm[c*8 + tid]);
    maxf1[tid] = mm;
  }
}

// ---------------- K2c: pack adjacency rows into 64-bit masks ----------------
__global__ __launch_bounds__(256) void k2c_pack(const int* __restrict__ adj,
                                               unsigned long long* __restrict__ adjm)
{
  int lane = threadIdx.x & 63, wave = threadIdx.x >> 6;
  int row = blockIdx.x*4 + wave;
  const int* ap = adj + (size_t)row*NN;
  #pragma unroll 8
  for (int s = 0; s < 64; ++s){
    unsigned long long m = __ballot(ap[s*64 + lane] != 0);
    if (lane == 0) adjm[(size_t)row*64 + s] = m;
  }
}

// ---------------- K3: flash-style MFMA GAT, 4-way j-split ----------------
__global__ __launch_bounds__(256) void k3_gat(
    const unsigned long long* __restrict__ adjm,   // [N][64]
    const unsigned short* __restrict__ supb,       // [64][N] bf16
    const float* __restrict__ f1t,                 // [8][N]
    const float* __restrict__ f2,                  // [N][8]
    const float* __restrict__ maxf1, float* __restrict__ posg)
{
  __shared__ f32x4 s_acc[4][64];        // 4KB merge buffer
  int tid = threadIdx.x;
  int lane = tid & 63, js = tid >> 6;
  int gid = blockIdx.x;                 // 0..2047
  int ib = gid >> 3, h = gid & 7;
  int i0 = ib*16;
  int col = lane & 15;                  // A-row during build; B/D column after
  int kg  = lane >> 4;

  float f2v = f2[(size_t)(i0+col)*8 + h];
  float lg = maxf1[h] + f2v;
  lg = fmaxf(lg, 0.2f*lg);
  float M = fmaxf(lg, 0.f);             // upper bound on reference rowmax

  const unsigned long long* mrow = adjm + (size_t)(i0+col)*64;
  const float* f1p = f1t + (size_t)h*NN;
  const unsigned short* bsrc = supb + (size_t)(h*8 + (col & 7))*NN;
  unsigned bge8 = (col >= 8) ? 0xffffffffu : 0u;   // lanes feeding the sum column

  f32x4 acc = {0.f, 0.f, 0.f, 0.f};

  #pragma unroll 2
  for (int cc = 0; cc < 32; ++cc){
    int c = js*32 + cc;
    int j8 = c*32 + kg*8;
    unsigned long long mw = mrow[c >> 1];
    unsigned mb = (unsigned)(mw >> (((c & 1) << 5) + (kg << 3)));
    float4 fa = *(const float4*)(f1p + j8);
    float4 fb = *(const float4*)(f1p + j8 + 4);

    float p[8];
    p[0]=fa.x; p[1]=fa.y; p[2]=fa.z; p[3]=fa.w;
    p[4]=fb.x; p[5]=fb.y; p[6]=fb.z; p[7]=fb.w;
    #pragma unroll
    for (int e = 0; e < 8; ++e){
      float logit = p[e] + f2v;
      float lr = fmaxf(logit, 0.2f*logit);
      float pe = __expf(lr - M);
      p[e] = (mb & (1u << e)) ? pe : 0.f;
    }
    union { bf16x8 v; unsigned u[4]; } A;
    A.u[0] = cvtpk_bf16(p[0], p[1]);
    A.u[1] = cvtpk_bf16(p[2], p[3]);
    A.u[2] = cvtpk_bf16(p[4], p[5]);
    A.u[3] = cvtpk_bf16(p[6], p[7]);

    union { bf16x8 v; unsigned u[4]; } B;
    uint4 ld = *(const uint4*)(bsrc + j8);
    B.u[0] = bge8 ? 0x3f803f80u : ld.x;   // col>=8: bf16 1.0 (col 8 = denominator)
    B.u[1] = bge8 ? 0x3f803f80u : ld.y;
    B.u[2] = bge8 ? 0x3f803f80u : ld.z;
    B.u[3] = bge8 ? 0x3f803f80u : ld.w;

    acc = __builtin_amdgcn_mfma_f32_16x16x32_bf16(A.v, B.v, acc, 0, 0, 0);
  }

  s_acc[js][lane] = acc;
  __syncthreads();
  if (js == 0){
    f32x4 a1 = s_acc[1][lane], a2 = s_acc[2][lane], a3 = s_acc[3][lane];
    #pragma unroll
    for (int j = 0; j < 4; ++j) acc[j] += a1[j] + a2[j] + a3[j];

    // denominator lives in column 8 of this kg-group: lane (lane&48)+8
    int slane = (lane & 48) + 8;
    #pragma unroll
    for (int r4 = 0; r4 < 4; ++r4){
      float sv = __shfl(acc[r4], slane, 64);
      float inv = 1.f / fmaxf(sv, 1e-10f);
      if (col < 8)
        posg[(size_t)(i0 + kg*4 + r4)*64 + h*8 + col] = acc[r4] * inv;
    }
  }
}

// ---------------- K4: residual proj + the two MLP channels + PairNorm partials ----------------
__global__ __launch_bounds__(256) void k4_mix(
    const float* __restrict__ h, const float* __restrict__ posg,
    const float* __restrict__ gat_bias, const float* __restrict__ proj_b,
    const float* __restrict__ wtproj, const float* __restrict__ wtself,
    const float* __restrict__ wtpos,
    const float* __restrict__ mlp_self_b, const float* __restrict__ mlp_pos_b,
    float* __restrict__ s0, float* __restrict__ s1, float* __restrict__ part)
{
  int tid = threadIdx.x;
  int wave = tid >> 6, lane = tid & 63;
  int n = blockIdx.x*4 + wave;
  float hreg = h[n*64 + lane];
  float pr = proj_b[lane];
  float se = mlp_self_b[lane];
  #pragma unroll
  for (int k = 0; k < 64; ++k){
    float hk = __shfl(hreg, k, 64);
    pr += hk * wtproj[k*64 + lane];
    se += hk * wtself[k*64 + lane];
  }
  float posf = posg[n*64 + lane] + gat_bias[lane] + pr;
  float s1v = mlp_pos_b[lane];
  #pragma unroll
  for (int k = 0; k < 64; ++k){
    float pk = __shfl(posf, k, 64);
    s1v += pk * wtpos[k*64 + lane];
  }
  s0[n*64+lane] = se;
  s1[n*64+lane] = s1v;

  __shared__ float sb0[4][64];
  __shared__ float sb1[4][64];
  __shared__ float sq[4];
  sb0[wave][lane] = se;
  sb1[wave][lane] = s1v;
  float q = se*se + s1v*s1v;
  #pragma unroll
  for (int s = 1; s < 64; s <<= 1) q += __shfl_xor(q, s, 64);
  if (lane == 0) sq[wave] = q;
  __syncthreads();
  if (tid < 64){
    part[blockIdx.x*130 + tid] = sb0[0][tid]+sb0[1][tid]+sb0[2][tid]+sb0[3][tid];
  } else if (tid < 128){
    int d = tid - 64;
    part[blockIdx.x*130 + 64 + d] = sb1[0][d]+sb1[1][d]+sb1[2][d]+sb1[3][d];
  } else if (tid == 128){
    part[blockIdx.x*130 + 128] = sq[0]+sq[1]+sq[2]+sq[3];
  }
}

// ---------------- K5: PairNorm stats (1024-thread two-stage reduce) ----------------
__global__ __launch_bounds__(1024) void k5_stats(const float* __restrict__ part, float* __restrict__ stats)
{
  int tid = threadIdx.x;
  __shared__ float s_mu[8][128];
  __shared__ float s_sq[8];
  int c = tid & 127, ch = tid >> 7;
  float a = 0.f;
  for (int b = ch*128; b < ch*128+128; ++b) a += part[b*130 + c];
  s_mu[ch][c] = a;
  if (tid < 8){
    float q = 0.f;
    for (int b = tid*128; b < tid*128+128; ++b) q += part[b*130 + 128];
    s_sq[tid] = q;
  }
  __syncthreads();
  if (tid < 128){
    float m = 0.f;
    #pragma unroll
    for (int j = 0; j < 8; ++j) m += s_mu[j][tid];
    s_mu[0][tid] = m;
    stats[tid] = m / 4096.f;
  }
  __syncthreads();
  if (tid == 0){
    float sq = 0.f;
    #pragma unroll
    for (int j = 0; j < 8; ++j) sq += s_sq[j];
    float mu2 = 0.f;
    for (int i = 0; i < 128; ++i){ float m = s_mu[0][i] / 4096.f; mu2 += m*m; }
    float msq = sq/(4096.f*64.f) - mu2/64.f;
    stats[128] = 1.f / sqrtf(1e-6f + msq);
  }
}

// ---------------- K6: semantic attention + predictor ----------------
__global__ __launch_bounds__(256) void k6_sem(
    const float* __restrict__ s0, const float* __restrict__ s1,
    const float* __restrict__ stats, const float* __restrict__ wtsem,
    const float* __restrict__ sem_b1, const float* __restrict__ sem_w2,
    const float* __restrict__ pred_w, const float* __restrict__ pred_b,
    float* __restrict__ out)
{
  int tid = threadIdx.x;
  int wave = tid >> 6, lane = tid & 63;
  int n = blockIdx.x*4 + wave;
  float rinv = stats[128];
  float a0 = (s0[n*64+lane] - stats[lane]) * rinv;
  float a1 = (s1[n*64+lane] - stats[64+lane]) * rinv;
  float t0 = sem_b1[lane], t1 = t0;
  #pragma unroll
  for (int k = 0; k < 64; ++k){
    float w = wtsem[k*64 + lane];
    t0 += __shfl(a0, k, 64) * w;
    t1 += __shfl(a1, k, 64) * w;
  }
  t0 = tanh_fast(t0); t1 = tanh_fast(t1);
  float w2 = sem_w2[lane];
  float w0 = t0*w2, w1 = t1*w2;
  #pragma unroll
  for (int s = 1; s < 64; s <<= 1){
    w0 += __shfl_xor(w0, s, 64);
    w1 += __shfl_xor(w1, s, 64);
  }
  float mx = fmaxf(w0, w1);
  float e0 = __expf(w0 - mx), e1 = __expf(w1 - mx);
  float denom = e0 + e1 + 1e-10f;
  float b0 = e0/denom, b1 = e1/denom;
  float emb = b0*a0 + b1*a1;
  float pl = emb * pred_w[lane];
  #pragma unroll
  for (int s = 1; s < 64; s <<= 1) pl += __shfl_xor(pl, s, 64);
  if (lane == 0) out[n] = sigm(pl + pred_b[0]);
}

extern "C" void kernel_launch(void* const* d_in, const int* in_sizes, int n_in,
                              void* d_out, int out_size, void* d_ws, size_t ws_size,
                              hipStream_t stream)
{
  (void)in_sizes; (void)n_in; (void)out_size; (void)ws_size;
  const float* x         = (const float*)d_in[0];
  const int*   adj       = (const int*)d_in[1];
  const float* W_ih      = (const float*)d_in[2];
  const float* W_hh      = (const float*)d_in[3];
  const float* b_ih      = (const float*)d_in[4];
  const float* b_hh      = (const float*)d_in[5];
  const float* gat_w     = (const float*)d_in[6];
  const float* gat_wu    = (const float*)d_in[7];
  const float* gat_wv    = (const float*)d_in[8];
  const float* gat_bias  = (const float*)d_in[9];
  const float* proj_w    = (const float*)d_in[10];
  const float* proj_b    = (const float*)d_in[11];
  const float* mlp_self_w= (const float*)d_in[12];
  const float* mlp_self_b= (const float*)d_in[13];
  const float* mlp_pos_w = (const float*)d_in[14];
  const float* mlp_pos_b = (const float*)d_in[15];
  const float* sem_w1    = (const float*)d_in[16];
  const float* sem_b1    = (const float*)d_in[17];
  const float* sem_w2    = (const float*)d_in[18];
  const float* pred_w    = (const float*)d_in[19];
  const float* pred_b    = (const float*)d_in[20];
  float* out = (float*)d_out;
  float* ws  = (float*)d_ws;

  float* h     = ws + 0;         // 262144
  // supb (bf16 [64][4096] = 512KB) overlays the old f32 supt region (1MB)
  unsigned short* supb = (unsigned short*)(ws + 262144);
  float* f1t   = ws + 524288;    // 32768   [8][4096]
  float* f2    = ws + 557056;    // 32768   [4096][8]
  float* posg  = ws + 589824;    // 262144
  float* s0    = ws + 851968;    // 262144
  float* s1    = ws + 1114112;   // 262144
  // adjm overlays s0+s1 (2MB): written by k2c, consumed by k3, dead before k4 writes s0/s1.
  // GRU fragment buffers (36KB) overlay the TAIL of the adjm region: k0b writes them,
  // k1 reads them, both complete before k2c overwrites (stream-ordered).
  unsigned long long* adjm = (unsigned long long*)(ws + 851968);
  uint4* whhF = (uint4*)(ws + 1114112 + 200000);  // 24*64 uint4 = 6144 uint4
  uint4* wihF = whhF + 24*64;                      // 12*64
  float* part  = ws + 1376256;   // 1024*130
  float* bmax  = ws + 1509376;   // 1024*8
  float* maxf1 = ws + 1517568;   // 8
  float* stats = ws + 1517576;   // 129
  float* wtproj= ws + 1517712;   // 4096
  float* wtself= wtproj + 4096;
  float* wtpos = wtself + 4096;
  float* wtsem = wtpos  + 4096;

  k0_prep<<<16, 256, 0, stream>>>(proj_w, mlp_self_w, mlp_pos_w, sem_w1,
                                  wtproj, wtself, wtpos, wtsem);
  k0b_frag<<<9, 256, 0, stream>>>(W_ih, W_hh, b_ih, b_hh, whhF, wihF);
  k1_gru<<<256, 64, 0, stream>>>(x, whhF, wihF, b_hh, h);
  k2_sup<<<1024, 256, 0, stream>>>(h, gat_w, gat_wu, gat_wv, supb, f1t, f2, bmax);
  k2b_max<<<1, 256, 0, stream>>>(bmax, maxf1);
  k2c_pack<<<1024, 256, 0, stream>>>(adj, adjm);
  k3_gat<<<2048, 256, 0, stream>>>(adjm, supb, f1t, f2, maxf1, posg);
  k4_mix<<<1024, 256, 0, stream>>>(h, posg, gat_bias, proj_b, wtproj, wtself, wtpos,
                                   mlp_self_b, mlp_pos_b, s0, s1, part);
  k5_stats<<<1, 1024, 0, stream>>>(part, stats);
  k6_sem<<<1024, 256, 0, stream>>>(s0, s1, stats, wtsem, sem_b1, sem_w2, pred_w, pred_b, out);
}

// Round 15
// 200.984 us; speedup vs baseline: 2.6722x; 1.2588x over previous
//
#include <hip/hip_runtime.h>
#include <math.h>

#define NN 4096
#define TT 32
#define FF 7
#define HH 64
#define NHEAD 8
#define DOUT 8
#define LOG2E 1.44269504f

typedef short bf16x8 __attribute__((ext_vector_type(8)));
typedef float f32x4 __attribute__((ext_vector_type(4)));

__device__ __forceinline__ float sigm(float x){
  x = fminf(fmaxf(x, -30.f), 30.f);
  return 1.f / (1.f + __expf(-x));
}
__device__ __forceinline__ float tanh_fast(float x){
  x = fminf(fmaxf(x, -15.f), 15.f);
  float e = __expf(2.f*x);
  return (e - 1.f) / (e + 1.f);
}
__device__ __forceinline__ unsigned short bf16rne(float f){
  unsigned u = __float_as_uint(f);
  u += 0x7fffu + ((u >> 16) & 1u);
  return (unsigned short)(u >> 16);
}
__device__ __forceinline__ unsigned bfpack2(float a, float b){
  return (unsigned)bf16rne(a) | ((unsigned)bf16rne(b) << 16);
}
__device__ __forceinline__ unsigned cvtpk_bf16(float a, float b){
  unsigned r;
  asm("v_cvt_pk_bf16_f32 %0, %1, %2" : "=v"(r) : "v"(a), "v"(b));
  return r;
}

// ---------------- K0: transpose small 64x64 weights to k-major ----------------
__global__ void k0_prep(const float* __restrict__ pw, const float* __restrict__ msw,
                        const float* __restrict__ mpw, const float* __restrict__ sw1,
                        float* __restrict__ wtproj, float* __restrict__ wtself,
                        float* __restrict__ wtpos, float* __restrict__ wtsem)
{
  int tid = threadIdx.x + blockIdx.x*blockDim.x;
  if (tid < 4096){
    int d = tid >> 6, k = tid & 63;
    wtproj[k*64+d] = pw[tid];
    wtself[k*64+d] = msw[tid];
    wtpos[k*64+d]  = mpw[tid];
    wtsem[k*64+d]  = sw1[tid];
  }
}

// ---------------- K0b: pre-pack GRU weight MFMA fragments (bf16 lines) ----------------
__global__ __launch_bounds__(256) void k0b_frag(
    const float* __restrict__ Wih, const float* __restrict__ Whh,
    const float* __restrict__ bih, const float* __restrict__ bhh,
    uint4* __restrict__ whhF, uint4* __restrict__ wihF)
{
  int idx = blockIdx.x*256 + threadIdx.x;     // 0..2303
  if (idx < 24*64){
    int f = idx >> 6, lane = idx & 63;
    int T = f >> 1, c = f & 1;
    int g = T*16 + (lane & 15);
    const float* wp = Whh + g*64 + c*32 + (lane >> 4)*8;
    uint4 v;
    v.x = bfpack2(wp[0], wp[1]);
    v.y = bfpack2(wp[2], wp[3]);
    v.z = bfpack2(wp[4], wp[5]);
    v.w = bfpack2(wp[6], wp[7]);
    whhF[idx] = v;
  } else if (idx < 36*64){
    int i2 = idx - 24*64;
    int T = i2 >> 6, lane = i2 & 63;
    int g = T*16 + (lane & 15);
    int kg = lane >> 4;
    float bias = (T < 8) ? (bih[g] + bhh[g]) : bih[g];   // b_hhn NOT folded (inside r*())
    float f8[8];
    #pragma unroll
    for (int j = 0; j < 8; ++j){
      int k = kg*8 + j;
      f8[j] = (k < 7) ? Wih[g*7 + k] : ((k == 7) ? bias : 0.f);
    }
    uint4 v;
    v.x = bfpack2(f8[0], f8[1]); v.y = bfpack2(f8[2], f8[3]);
    v.z = bfpack2(f8[4], f8[5]); v.w = bfpack2(f8[6], f8[7]);
    wihF[i2] = v;
  }
}

// ---------------- K1: GRU encoder via MFMA, gates split across 4 waves ----------------
// 256 blocks x 256 threads (4 waves); block owns 16 nodes. Wave w owns gate-tiles
// {w, 4+w, 8+w} = r/z/n for gate rows [w*16, w*16+16): 9 resident fragments
// (36 VGPR -- no remat pressure, unlike the 36-fragment single-wave version),
// 9 MFMAs + 4-element activation per t. h exchanged via double-buffered LDS,
// ONE barrier per t. Serial per-t work ~4x smaller than rounds 11-14.
__global__ __launch_bounds__(256) void k1_gru(
    const float* __restrict__ x,      // [N][T][F]
    const uint4* __restrict__ whhF,   // [24][64]
    const uint4* __restrict__ wihF,   // [12][64]
    const float* __restrict__ bhh,
    float* __restrict__ hout)         // [N][64]
{
  __shared__ __align__(16) short s_xb[32][16][8];   // 8KB   bf16 x (k=7 -> 1.0)
  __shared__ __align__(16) short s_hb[2][16][72];   // 4.5KB bf16 h, double-buffered

  int tid = threadIdx.x;
  int lane = tid & 63, w = tid >> 6;    // wave = gate-tile group
  int nb = blockIdx.x * 16;
  int row = lane & 15;                  // B/D: node column
  int kg  = lane >> 4;                  // k-group

  union U { bf16x8 v; uint4 q; };
  U u;
  u.q = wihF[w*64 + lane];           bf16x8 fRx  = u.v;
  u.q = whhF[(w*2+0)*64 + lane];     bf16x8 fRh0 = u.v;
  u.q = whhF[(w*2+1)*64 + lane];     bf16x8 fRh1 = u.v;
  u.q = wihF[(4+w)*64 + lane];       bf16x8 fZx  = u.v;
  u.q = whhF[((4+w)*2+0)*64 + lane]; bf16x8 fZh0 = u.v;
  u.q = whhF[((4+w)*2+1)*64 + lane]; bf16x8 fZh1 = u.v;
  u.q = wihF[(8+w)*64 + lane];       bf16x8 fNx  = u.v;
  u.q = whhF[((8+w)*2+0)*64 + lane]; bf16x8 fNh0 = u.v;
  u.q = whhF[((8+w)*2+1)*64 + lane]; bf16x8 fNh1 = u.v;

  for (int s = tid; s < 4096; s += 256){
    int t = s >> 7, node = (s >> 3) & 15, k = s & 7;
    float v = (k < 7) ? x[(size_t)(nb + node)*224 + t*7 + k] : ((k == 7) ? 1.f : 0.f);
    s_xb[t][node][k] = (short)bf16rne(v);
  }
  for (int i = tid; i < 576; i += 256) ((unsigned*)&s_hb[0][0][0])[i] = 0u;

  float bhn_[4];
  #pragma unroll
  for (int j = 0; j < 4; ++j) bhn_[j] = bhh[128 + w*16 + kg*4 + j];
  float hreg[4] = {0.f, 0.f, 0.f, 0.f};
  f32x4 z4 = {0.f, 0.f, 0.f, 0.f};

  __syncthreads();
  int cur = 0;
  for (int t = 0; t < TT; ++t){
    bf16x8 bx = {0,0,0,0,0,0,0,0};
    if (lane < 16) bx = *(const bf16x8*)&s_xb[t][row][0];
    bf16x8 bh0 = *(const bf16x8*)&s_hb[cur][row][kg*8];
    bf16x8 bh1 = *(const bf16x8*)&s_hb[cur][row][32 + kg*8];

    f32x4 aR = __builtin_amdgcn_mfma_f32_16x16x32_bf16(fRx, bx, z4, 0, 0, 0);
    aR = __builtin_amdgcn_mfma_f32_16x16x32_bf16(fRh0, bh0, aR, 0, 0, 0);
    aR = __builtin_amdgcn_mfma_f32_16x16x32_bf16(fRh1, bh1, aR, 0, 0, 0);
    f32x4 aZ = __builtin_amdgcn_mfma_f32_16x16x32_bf16(fZx, bx, z4, 0, 0, 0);
    aZ = __builtin_amdgcn_mfma_f32_16x16x32_bf16(fZh0, bh0, aZ, 0, 0, 0);
    aZ = __builtin_amdgcn_mfma_f32_16x16x32_bf16(fZh1, bh1, aZ, 0, 0, 0);
    f32x4 aNx = __builtin_amdgcn_mfma_f32_16x16x32_bf16(fNx, bx, z4, 0, 0, 0);
    f32x4 aNh = __builtin_amdgcn_mfma_f32_16x16x32_bf16(fNh0, bh0, z4, 0, 0, 0);
    aNh = __builtin_amdgcn_mfma_f32_16x16x32_bf16(fNh1, bh1, aNh, 0, 0, 0);

    #pragma unroll
    for (int j = 0; j < 4; ++j){
      float rr = sigm(aR[j]);
      float zz = sigm(aZ[j]);
      float nn = tanh_fast(aNx[j] + rr*(aNh[j] + bhn_[j]));
      hreg[j] = (1.f - zz)*nn + zz*hreg[j];
    }
    uint2 p;
    p.x = bfpack2(hreg[0], hreg[1]);
    p.y = bfpack2(hreg[2], hreg[3]);
    *(uint2*)&s_hb[cur^1][row][w*16 + kg*4] = p;
    __syncthreads();
    cur ^= 1;
  }

  #pragma unroll
  for (int j = 0; j < 4; ++j)
    hout[(size_t)(nb + row)*64 + w*16 + kg*4 + j] = hreg[j];
}

// ---------------- K2: supb (bf16) = h@gat_w; f1t/f2 pre-scaled by log2e ----------------
__global__ __launch_bounds__(256) void k2_sup(
    const float* __restrict__ h, const float* __restrict__ gat_w,
    const float* __restrict__ wu, const float* __restrict__ wv,
    unsigned short* __restrict__ supb,  // [64][N] bf16, row = hh*8+o
    float* __restrict__ f1t,            // [8][N]  (x log2e)
    float* __restrict__ f2)             // [N][8]  (x log2e)
{
  int tid = threadIdx.x;
  int wave = tid >> 6, lane = tid & 63;
  int n = blockIdx.x*4 + wave;
  float hreg = h[n*64 + lane];
  float acc = 0.f;
  #pragma unroll
  for (int k = 0; k < 64; ++k){
    float hk = __shfl(hreg, k, 64);
    acc += hk * gat_w[k*64 + lane];
  }
  supb[(size_t)lane*NN + n] = bf16rne(acc);   // bf16: k3 consumes as MFMA B-operand
  float p1 = acc * wu[lane];
  float p2 = acc * wv[lane];
  #pragma unroll
  for (int s = 1; s < 8; s <<= 1){
    p1 += __shfl_xor(p1, s, 64);
    p2 += __shfl_xor(p2, s, 64);
  }
  int hh = lane >> 3;
  if ((lane & 7) == 0){
    f1t[(size_t)hh*NN + n] = p1 * LOG2E;   // exp(x) == exp2(x*log2e): scale folded here
    f2[n*8 + hh] = p2 * LOG2E;
  }
}

// ---------------- K2c: pack adjacency rows into 64-bit masks ----------------
__global__ __launch_bounds__(256) void k2c_pack(const int* __restrict__ adj,
                                               unsigned long long* __restrict__ adjm)
{
  int lane = threadIdx.x & 63, wave = threadIdx.x >> 6;
  int row = blockIdx.x*4 + wave;
  const int* ap = adj + (size_t)row*NN;
  #pragma unroll 8
  for (int s = 0; s < 64; ++s){
    unsigned long long m = __ballot(ap[s*64 + lane] != 0);
    if (lane == 0) adjm[(size_t)row*64 + s] = m;
  }
}

// ---------------- K3: flash-style MFMA GAT, 4-way j-split, no max-shift ----------------
// Softmax ratios are shift-invariant and |logit| <= ~6 by construction (h in
// (-1,1), small weights), so exp2 never overflows: the rowmax subtraction and
// its whole maxf1/bmax pipeline are deleted. Per pair: add, mul, max, exp2, mask.
__global__ __launch_bounds__(256) void k3_gat(
    const unsigned long long* __restrict__ adjm,   // [N][64]
    const unsigned short* __restrict__ supb,       // [64][N] bf16
    const float* __restrict__ f1t,                 // [8][N]  (x log2e)
    const float* __restrict__ f2,                  // [N][8]  (x log2e)
    float* __restrict__ posg)
{
  __shared__ f32x4 s_acc[4][64];        // 4KB merge buffer
  int tid = threadIdx.x;
  int lane = tid & 63, js = tid >> 6;
  int gid = blockIdx.x;                 // 0..2047
  int ib = gid >> 3, h = gid & 7;
  int i0 = ib*16;
  int col = lane & 15;                  // A-row during build; B/D column after
  int kg  = lane >> 4;

  float f2v = f2[(size_t)(i0+col)*8 + h];   // already x log2e

  const unsigned long long* mrow = adjm + (size_t)(i0+col)*64;
  const float* f1p = f1t + (size_t)h*NN;
  const unsigned short* bsrc = supb + (size_t)(h*8 + (col & 7))*NN;
  unsigned bge8 = (col >= 8) ? 0xffffffffu : 0u;   // lanes feeding the sum column

  f32x4 acc = {0.f, 0.f, 0.f, 0.f};

  #pragma unroll 2
  for (int cc = 0; cc < 32; ++cc){
    int c = js*32 + cc;
    int j8 = c*32 + kg*8;
    unsigned long long mw = mrow[c >> 1];
    unsigned mb = (unsigned)(mw >> (((c & 1) << 5) + (kg << 3)));
    float4 fa = *(const float4*)(f1p + j8);
    float4 fb = *(const float4*)(f1p + j8 + 4);

    float p[8];
    p[0]=fa.x; p[1]=fa.y; p[2]=fa.z; p[3]=fa.w;
    p[4]=fb.x; p[5]=fb.y; p[6]=fb.z; p[7]=fb.w;
    #pragma unroll
    for (int e = 0; e < 8; ++e){
      float ls = p[e] + f2v;                 // (f1+f2)*log2e
      float lrs = fmaxf(ls, 0.2f*ls);        // leaky-relu commutes with +scale
      float pe = exp2f(lrs);                 // v_exp_f32 directly
      p[e] = (mb & (1u << e)) ? pe : 0.f;
    }
    union { bf16x8 v; unsigned u[4]; } A;
    A.u[0] = cvtpk_bf16(p[0], p[1]);
    A.u[1] = cvtpk_bf16(p[2], p[3]);
    A.u[2] = cvtpk_bf16(p[4], p[5]);
    A.u[3] = cvtpk_bf16(p[6], p[7]);

    union { bf16x8 v; unsigned u[4]; } B;
    uint4 ld = *(const uint4*)(bsrc + j8);
    B.u[0] = bge8 ? 0x3f803f80u : ld.x;   // col>=8: bf16 1.0 (col 8 = denominator)
    B.u[1] = bge8 ? 0x3f803f80u : ld.y;
    B.u[2] = bge8 ? 0x3f803f80u : ld.z;
    B.u[3] = bge8 ? 0x3f803f80u : ld.w;

    acc = __builtin_amdgcn_mfma_f32_16x16x32_bf16(A.v, B.v, acc, 0, 0, 0);
  }

  s_acc[js][lane] = acc;
  __syncthreads();
  if (js == 0){
    f32x4 a1 = s_acc[1][lane], a2 = s_acc[2][lane], a3 = s_acc[3][lane];
    #pragma unroll
    for (int j = 0; j < 4; ++j) acc[j] += a1[j] + a2[j] + a3[j];

    // denominator lives in column 8 of this kg-group: lane (lane&48)+8
    int slane = (lane & 48) + 8;
    #pragma unroll
    for (int r4 = 0; r4 < 4; ++r4){
      float sv = __shfl(acc[r4], slane, 64);
      float inv = 1.f / fmaxf(sv, 1e-10f);
      if (col < 8)
        posg[(size_t)(i0 + kg*4 + r4)*64 + h*8 + col] = acc[r4] * inv;
    }
  }
}

// ---------------- K4: residual proj + the two MLP channels + PairNorm partials ----------------
__global__ __launch_bounds__(256) void k4_mix(
    const float* __restrict__ h, const float* __restrict__ posg,
    const float* __restrict__ gat_bias, const float* __restrict__ proj_b,
    const float* __restrict__ wtproj, const float* __restrict__ wtself,
    const float* __restrict__ wtpos,
    const float* __restrict__ mlp_self_b, const float* __restrict__ mlp_pos_b,
    float* __restrict__ s0, float* __restrict__ s1, float* __restrict__ part)
{
  int tid = threadIdx.x;
  int wave = tid >> 6, lane = tid & 63;
  int n = blockIdx.x*4 + wave;
  float hreg = h[n*64 + lane];
  float pr = proj_b[lane];
  float se = mlp_self_b[lane];
  #pragma unroll
  for (int k = 0; k < 64; ++k){
    float hk = __shfl(hreg, k, 64);
    pr += hk * wtproj[k*64 + lane];
    se += hk * wtself[k*64 + lane];
  }
  float posf = posg[n*64 + lane] + gat_bias[lane] + pr;
  float s1v = mlp_pos_b[lane];
  #pragma unroll
  for (int k = 0; k < 64; ++k){
    float pk = __shfl(posf, k, 64);
    s1v += pk * wtpos[k*64 + lane];
  }
  s0[n*64+lane] = se;
  s1[n*64+lane] = s1v;

  __shared__ float sb0[4][64];
  __shared__ float sb1[4][64];
  __shared__ float sq[4];
  sb0[wave][lane] = se;
  sb1[wave][lane] = s1v;
  float q = se*se + s1v*s1v;
  #pragma unroll
  for (int s = 1; s < 64; s <<= 1) q += __shfl_xor(q, s, 64);
  if (lane == 0) sq[wave] = q;
  __syncthreads();
  if (tid < 64){
    part[blockIdx.x*130 + tid] = sb0[0][tid]+sb0[1][tid]+sb0[2][tid]+sb0[3][tid];
  } else if (tid < 128){
    int d = tid - 64;
    part[blockIdx.x*130 + 64 + d] = sb1[0][d]+sb1[1][d]+sb1[2][d]+sb1[3][d];
  } else if (tid == 128){
    part[blockIdx.x*130 + 128] = sq[0]+sq[1]+sq[2]+sq[3];
  }
}

// ---------------- K5: PairNorm stats (1024-thread two-stage reduce) ----------------
__global__ __launch_bounds__(1024) void k5_stats(const float* __restrict__ part, float* __restrict__ stats)
{
  int tid = threadIdx.x;
  __shared__ float s_mu[8][128];
  __shared__ float s_sq[8];
  int c = tid & 127, ch = tid >> 7;
  float a = 0.f;
  for (int b = ch*128; b < ch*128+128; ++b) a += part[b*130 + c];
  s_mu[ch][c] = a;
  if (tid < 8){
    float q = 0.f;
    for (int b = tid*128; b < tid*128+128; ++b) q += part[b*130 + 128];
    s_sq[tid] = q;
  }
  __syncthreads();
  if (tid < 128){
    float m = 0.f;
    #pragma unroll
    for (int j = 0; j < 8; ++j) m += s_mu[j][tid];
    s_mu[0][tid] = m;
    stats[tid] = m / 4096.f;
  }
  __syncthreads();
  if (tid == 0){
    float sq = 0.f;
    #pragma unroll
    for (int j = 0; j < 8; ++j) sq += s_sq[j];
    float mu2 = 0.f;
    for (int i = 0; i < 128; ++i){ float m = s_mu[0][i] / 4096.f; mu2 += m*m; }
    float msq = sq/(4096.f*64.f) - mu2/64.f;
    stats[128] = 1.f / sqrtf(1e-6f + msq);
  }
}

// ---------------- K6: semantic attention + predictor ----------------
__global__ __launch_bounds__(256) void k6_sem(
    const float* __restrict__ s0, const float* __restrict__ s1,
    const float* __restrict__ stats, const float* __restrict__ wtsem,
    const float* __restrict__ sem_b1, const float* __restrict__ sem_w2,
    const float* __restrict__ pred_w, const float* __restrict__ pred_b,
    float* __restrict__ out)
{
  int tid = threadIdx.x;
  int wave = tid >> 6, lane = tid & 63;
  int n = blockIdx.x*4 + wave;
  float rinv = stats[128];
  float a0 = (s0[n*64+lane] - stats[lane]) * rinv;
  float a1 = (s1[n*64+lane] - stats[64+lane]) * rinv;
  float t0 = sem_b1[lane], t1 = t0;
  #pragma unroll
  for (int k = 0; k < 64; ++k){
    float w = wtsem[k*64 + lane];
    t0 += __shfl(a0, k, 64) * w;
    t1 += __shfl(a1, k, 64) * w;
  }
  t0 = tanh_fast(t0); t1 = tanh_fast(t1);
  float w2 = sem_w2[lane];
  float w0 = t0*w2, w1 = t1*w2;
  #pragma unroll
  for (int s = 1; s < 64; s <<= 1){
    w0 += __shfl_xor(w0, s, 64);
    w1 += __shfl_xor(w1, s, 64);
  }
  float mx = fmaxf(w0, w1);
  float e0 = __expf(w0 - mx), e1 = __expf(w1 - mx);
  float denom = e0 + e1 + 1e-10f;
  float b0 = e0/denom, b1 = e1/denom;
  float emb = b0*a0 + b1*a1;
  float pl = emb * pred_w[lane];
  #pragma unroll
  for (int s = 1; s < 64; s <<= 1) pl += __shfl_xor(pl, s, 64);
  if (lane == 0) out[n] = sigm(pl + pred_b[0]);
}

extern "C" void kernel_launch(void* const* d_in, const int* in_sizes, int n_in,
                              void* d_out, int out_size, void* d_ws, size_t ws_size,
                              hipStream_t stream)
{
  (void)in_sizes; (void)n_in; (void)out_size; (void)ws_size;
  const float* x         = (const float*)d_in[0];
  const int*   adj       = (const int*)d_in[1];
  const float* W_ih      = (const float*)d_in[2];
  const float* W_hh      = (const float*)d_in[3];
  const float* b_ih      = (const float*)d_in[4];
  const float* b_hh      = (const float*)d_in[5];
  const float* gat_w     = (const float*)d_in[6];
  const float* gat_wu    = (const float*)d_in[7];
  const float* gat_wv    = (const float*)d_in[8];
  const float* gat_bias  = (const float*)d_in[9];
  const float* proj_w    = (const float*)d_in[10];
  const float* proj_b    = (const float*)d_in[11];
  const float* mlp_self_w= (const float*)d_in[12];
  const float* mlp_self_b= (const float*)d_in[13];
  const float* mlp_pos_w = (const float*)d_in[14];
  const float* mlp_pos_b = (const float*)d_in[15];
  const float* sem_w1    = (const float*)d_in[16];
  const float* sem_b1    = (const float*)d_in[17];
  const float* sem_w2    = (const float*)d_in[18];
  const float* pred_w    = (const float*)d_in[19];
  const float* pred_b    = (const float*)d_in[20];
  float* out = (float*)d_out;
  float* ws  = (float*)d_ws;

  float* h     = ws + 0;         // 262144
  // supb (bf16 [64][4096] = 512KB) overlays the old f32 supt region (1MB)
  unsigned short* supb = (unsigned short*)(ws + 262144);
  float* f1t   = ws + 524288;    // 32768   [8][4096]
  float* f2    = ws + 557056;    // 32768   [4096][8]
  float* posg  = ws + 589824;    // 262144
  float* s0    = ws + 851968;    // 262144
  float* s1    = ws + 1114112;   // 262144
  // adjm overlays s0+s1 (2MB): written by k2c, consumed by k3, dead before k4 writes s0/s1.
  // GRU fragment buffers (36KB) overlay the TAIL of the adjm region: k0b writes them,
  // k1 reads them, both complete before k2c overwrites (stream-ordered).
  unsigned long long* adjm = (unsigned long long*)(ws + 851968);
  uint4* whhF = (uint4*)(ws + 1114112 + 200000);  // 24*64 uint4
  uint4* wihF = whhF + 24*64;                      // 12*64
  float* part  = ws + 1376256;   // 1024*130
  float* stats = ws + 1517576;   // 129
  float* wtproj= ws + 1517712;   // 4096
  float* wtself= wtproj + 4096;
  float* wtpos = wtself + 4096;
  float* wtsem = wtpos  + 4096;

  k0_prep<<<16, 256, 0, stream>>>(proj_w, mlp_self_w, mlp_pos_w, sem_w1,
                                  wtproj, wtself, wtpos, wtsem);
  k0b_frag<<<9, 256, 0, stream>>>(W_ih, W_hh, b_ih, b_hh, whhF, wihF);
  k1_gru<<<256, 256, 0, stream>>>(x, whhF, wihF, b_hh, h);
  k2_sup<<<1024, 256, 0, stream>>>(h, gat_w, gat_wu, gat_wv, supb, f1t, f2);
  k2c_pack<<<1024, 256, 0, stream>>>(adj, adjm);
  k3_gat<<<2048, 256, 0, stream>>>(adjm, supb, f1t, f2, posg);
  k4_mix<<<1024, 256, 0, stream>>>(h, posg, gat_bias, proj_b, wtproj, wtself, wtpos,
                                   mlp_self_b, mlp_pos_b, s0, s1, part);
  k5_stats<<<1, 1024, 0, stream>>>(part, stats);
  k6_sem<<<1024, 256, 0, stream>>>(s0, s1, stats, wtsem, sem_b1, sem_w2, pred_w, pred_b, out);
}

// Round 16
// 197.595 us; speedup vs baseline: 2.7181x; 1.0172x over previous
//
#include <hip/hip_runtime.h>
#include <math.h>

#define NN 4096
#define TT 32
#define FF 7
#define HH 64
#define NHEAD 8
#define DOUT 8
#define LOG2E 1.44269504f

#if __has_builtin(__builtin_amdgcn_exp2f)
#define EXP2(x) __builtin_amdgcn_exp2f(x)
#else
#define EXP2(x) exp2f(x)
#endif

typedef short bf16x8 __attribute__((ext_vector_type(8)));
typedef float f32x4 __attribute__((ext_vector_type(4)));

__device__ __forceinline__ float sigm(float x){
  x = fminf(fmaxf(x, -30.f), 30.f);
  return 1.f / (1.f + __expf(-x));
}
__device__ __forceinline__ float tanh_fast(float x){
  x = fminf(fmaxf(x, -15.f), 15.f);
  float e = __expf(2.f*x);
  return (e - 1.f) / (e + 1.f);
}
__device__ __forceinline__ unsigned short bf16rne(float f){
  unsigned u = __float_as_uint(f);
  u += 0x7fffu + ((u >> 16) & 1u);
  return (unsigned short)(u >> 16);
}
__device__ __forceinline__ unsigned bfpack2(float a, float b){
  return (unsigned)bf16rne(a) | ((unsigned)bf16rne(b) << 16);
}
__device__ __forceinline__ unsigned cvtpk_bf16(float a, float b){
  unsigned r;
  asm("v_cvt_pk_bf16_f32 %0, %1, %2" : "=v"(r) : "v"(a), "v"(b));
  return r;
}

// ---------------- K0: weight transposes (blocks 0-15) + GRU frag pack (16-24) ----------------
__global__ __launch_bounds__(256) void k0_prep(
    const float* __restrict__ pw, const float* __restrict__ msw,
    const float* __restrict__ mpw, const float* __restrict__ sw1,
    const float* __restrict__ Wih, const float* __restrict__ Whh,
    const float* __restrict__ bih, const float* __restrict__ bhh,
    float* __restrict__ wtproj, float* __restrict__ wtself,
    float* __restrict__ wtpos, float* __restrict__ wtsem,
    uint4* __restrict__ whhF, uint4* __restrict__ wihF)
{
  if (blockIdx.x < 16){
    int tid = threadIdx.x + blockIdx.x*256;
    int d = tid >> 6, k = tid & 63;
    wtproj[k*64+d] = pw[tid];
    wtself[k*64+d] = msw[tid];
    wtpos[k*64+d]  = mpw[tid];
    wtsem[k*64+d]  = sw1[tid];
    return;
  }
  int idx = (blockIdx.x-16)*256 + threadIdx.x;     // 0..2303
  if (idx < 24*64){
    int f = idx >> 6, lane = idx & 63;
    int T = f >> 1, c = f & 1;
    int g = T*16 + (lane & 15);
    const float* wp = Whh + g*64 + c*32 + (lane >> 4)*8;
    uint4 v;
    v.x = bfpack2(wp[0], wp[1]);
    v.y = bfpack2(wp[2], wp[3]);
    v.z = bfpack2(wp[4], wp[5]);
    v.w = bfpack2(wp[6], wp[7]);
    whhF[idx] = v;
  } else if (idx < 36*64){
    int i2 = idx - 24*64;
    int T = i2 >> 6, lane = i2 & 63;
    int g = T*16 + (lane & 15);
    int kg = lane >> 4;
    float bias = (T < 8) ? (bih[g] + bhh[g]) : bih[g];   // b_hhn NOT folded (inside r*())
    float f8[8];
    #pragma unroll
    for (int j = 0; j < 8; ++j){
      int k = kg*8 + j;
      f8[j] = (k < 7) ? Wih[g*7 + k] : ((k == 7) ? bias : 0.f);
    }
    uint4 v;
    v.x = bfpack2(f8[0], f8[1]); v.y = bfpack2(f8[2], f8[3]);
    v.z = bfpack2(f8[4], f8[5]); v.w = bfpack2(f8[6], f8[7]);
    wihF[i2] = v;
  }
}

// ---------------- K1: GRU encoder via MFMA, gates split across 4 waves ----------------
__global__ __launch_bounds__(256) void k1_gru(
    const float* __restrict__ x,      // [N][T][F]
    const uint4* __restrict__ whhF,   // [24][64]
    const uint4* __restrict__ wihF,   // [12][64]
    const float* __restrict__ bhh,
    float* __restrict__ hout)         // [N][64]
{
  __shared__ __align__(16) short s_xb[32][16][8];   // 8KB   bf16 x (k=7 -> 1.0)
  __shared__ __align__(16) short s_hb[2][16][72];   // 4.5KB bf16 h, double-buffered

  int tid = threadIdx.x;
  int lane = tid & 63, w = tid >> 6;    // wave = gate-tile group
  int nb = blockIdx.x * 16;
  int row = lane & 15;                  // B/D: node column
  int kg  = lane >> 4;                  // k-group

  union U { bf16x8 v; uint4 q; };
  U u;
  u.q = wihF[w*64 + lane];           bf16x8 fRx  = u.v;
  u.q = whhF[(w*2+0)*64 + lane];     bf16x8 fRh0 = u.v;
  u.q = whhF[(w*2+1)*64 + lane];     bf16x8 fRh1 = u.v;
  u.q = wihF[(4+w)*64 + lane];       bf16x8 fZx  = u.v;
  u.q = whhF[((4+w)*2+0)*64 + lane]; bf16x8 fZh0 = u.v;
  u.q = whhF[((4+w)*2+1)*64 + lane]; bf16x8 fZh1 = u.v;
  u.q = wihF[(8+w)*64 + lane];       bf16x8 fNx  = u.v;
  u.q = whhF[((8+w)*2+0)*64 + lane]; bf16x8 fNh0 = u.v;
  u.q = whhF[((8+w)*2+1)*64 + lane]; bf16x8 fNh1 = u.v;

  for (int s = tid; s < 4096; s += 256){
    int t = s >> 7, node = (s >> 3) & 15, k = s & 7;
    float v = (k < 7) ? x[(size_t)(nb + node)*224 + t*7 + k] : ((k == 7) ? 1.f : 0.f);
    s_xb[t][node][k] = (short)bf16rne(v);
  }
  for (int i = tid; i < 576; i += 256) ((unsigned*)&s_hb[0][0][0])[i] = 0u;

  float bhn_[4];
  #pragma unroll
  for (int j = 0; j < 4; ++j) bhn_[j] = bhh[128 + w*16 + kg*4 + j];
  float hreg[4] = {0.f, 0.f, 0.f, 0.f};
  f32x4 z4 = {0.f, 0.f, 0.f, 0.f};

  __syncthreads();
  int cur = 0;
  for (int t = 0; t < TT; ++t){
    bf16x8 bx = {0,0,0,0,0,0,0,0};
    if (lane < 16) bx = *(const bf16x8*)&s_xb[t][row][0];
    bf16x8 bh0 = *(const bf16x8*)&s_hb[cur][row][kg*8];
    bf16x8 bh1 = *(const bf16x8*)&s_hb[cur][row][32 + kg*8];

    f32x4 aR = __builtin_amdgcn_mfma_f32_16x16x32_bf16(fRx, bx, z4, 0, 0, 0);
    aR = __builtin_amdgcn_mfma_f32_16x16x32_bf16(fRh0, bh0, aR, 0, 0, 0);
    aR = __builtin_amdgcn_mfma_f32_16x16x32_bf16(fRh1, bh1, aR, 0, 0, 0);
    f32x4 aZ = __builtin_amdgcn_mfma_f32_16x16x32_bf16(fZx, bx, z4, 0, 0, 0);
    aZ = __builtin_amdgcn_mfma_f32_16x16x32_bf16(fZh0, bh0, aZ, 0, 0, 0);
    aZ = __builtin_amdgcn_mfma_f32_16x16x32_bf16(fZh1, bh1, aZ, 0, 0, 0);
    f32x4 aNx = __builtin_amdgcn_mfma_f32_16x16x32_bf16(fNx, bx, z4, 0, 0, 0);
    f32x4 aNh = __builtin_amdgcn_mfma_f32_16x16x32_bf16(fNh0, bh0, z4, 0, 0, 0);
    aNh = __builtin_amdgcn_mfma_f32_16x16x32_bf16(fNh1, bh1, aNh, 0, 0, 0);

    #pragma unroll
    for (int j = 0; j < 4; ++j){
      float rr = sigm(aR[j]);
      float zz = sigm(aZ[j]);
      float nn = tanh_fast(aNx[j] + rr*(aNh[j] + bhn_[j]));
      hreg[j] = (1.f - zz)*nn + zz*hreg[j];
    }
    uint2 p;
    p.x = bfpack2(hreg[0], hreg[1]);
    p.y = bfpack2(hreg[2], hreg[3]);
    *(uint2*)&s_hb[cur^1][row][w*16 + kg*4] = p;
    __syncthreads();
    cur ^= 1;
  }

  #pragma unroll
  for (int j = 0; j < 4; ++j)
    hout[(size_t)(nb + row)*64 + w*16 + kg*4 + j] = hreg[j];
}

// ---------------- K2: supb (bf16) = h@gat_w; f1t/f2 pre-scaled by log2e ----------------
__global__ __launch_bounds__(256) void k2_sup(
    const float* __restrict__ h, const float* __restrict__ gat_w,
    const float* __restrict__ wu, const float* __restrict__ wv,
    unsigned short* __restrict__ supb,  // [64][N] bf16, row = hh*8+o
    float* __restrict__ f1t,            // [8][N]  (x log2e)
    float* __restrict__ f2)             // [N][8]  (x log2e)
{
  int tid = threadIdx.x;
  int wave = tid >> 6, lane = tid & 63;
  int n = blockIdx.x*4 + wave;
  float hreg = h[n*64 + lane];
  float acc = 0.f;
  #pragma unroll
  for (int k = 0; k < 64; ++k){
    float hk = __shfl(hreg, k, 64);
    acc += hk * gat_w[k*64 + lane];
  }
  supb[(size_t)lane*NN + n] = bf16rne(acc);   // bf16: k3 consumes as MFMA B-operand
  float p1 = acc * wu[lane];
  float p2 = acc * wv[lane];
  #pragma unroll
  for (int s = 1; s < 8; s <<= 1){
    p1 += __shfl_xor(p1, s, 64);
    p2 += __shfl_xor(p2, s, 64);
  }
  int hh = lane >> 3;
  if ((lane & 7) == 0){
    f1t[(size_t)hh*NN + n] = p1 * LOG2E;   // exp(x) == exp2(x*log2e): scale folded here
    f2[n*8 + hh] = p2 * LOG2E;
  }
}

// ---------------- K2c: pack adjacency rows into 64-bit masks ----------------
__global__ __launch_bounds__(256) void k2c_pack(const int* __restrict__ adj,
                                               unsigned long long* __restrict__ adjm)
{
  int lane = threadIdx.x & 63, wave = threadIdx.x >> 6;
  int row = blockIdx.x*4 + wave;
  const int* ap = adj + (size_t)row*NN;
  #pragma unroll 8
  for (int s = 0; s < 64; ++s){
    unsigned long long m = __ballot(ap[s*64 + lane] != 0);
    if (lane == 0) adjm[(size_t)row*64 + s] = m;
  }
}

// ---------------- K3: flash-style MFMA GAT, 4-way j-split, raw v_exp_f32 ----------------
// Round-15 finding: VALUBusy implied ~5x the hand-counted instructions; exp2f()
// is an ocml libcall with denormal fixup (~10 insts). EXP2 -> raw v_exp_f32
// (exact for our |x|<=10 range). Inner loop unroll 4 for load ILP.
__global__ __launch_bounds__(256) void k3_gat(
    const unsigned long long* __restrict__ adjm,   // [N][64]
    const unsigned short* __restrict__ supb,       // [64][N] bf16
    const float* __restrict__ f1t,                 // [8][N]  (x log2e)
    const float* __restrict__ f2,                  // [N][8]  (x log2e)
    float* __restrict__ posg)
{
  __shared__ f32x4 s_acc[4][64];        // 4KB merge buffer
  int tid = threadIdx.x;
  int lane = tid & 63, js = tid >> 6;
  int gid = blockIdx.x;                 // 0..2047
  int ib = gid >> 3, h = gid & 7;
  int i0 = ib*16;
  int col = lane & 15;                  // A-row during build; B/D column after
  int kg  = lane >> 4;

  float f2v = f2[(size_t)(i0+col)*8 + h];   // already x log2e

  const unsigned long long* mrow = adjm + (size_t)(i0+col)*64;
  const float* f1p = f1t + (size_t)h*NN;
  const unsigned short* bsrc = supb + (size_t)(h*8 + (col & 7))*NN;
  unsigned bge8 = (col >= 8) ? 0xffffffffu : 0u;   // lanes feeding the sum column

  f32x4 acc = {0.f, 0.f, 0.f, 0.f};

  #pragma unroll 4
  for (int cc = 0; cc < 32; ++cc){
    int c = js*32 + cc;
    int j8 = c*32 + kg*8;
    unsigned long long mw = mrow[c >> 1];
    unsigned mb = (unsigned)(mw >> (((c & 1) << 5) + (kg << 3)));
    float4 fa = *(const float4*)(f1p + j8);
    float4 fb = *(const float4*)(f1p + j8 + 4);

    float p[8];
    p[0]=fa.x; p[1]=fa.y; p[2]=fa.z; p[3]=fa.w;
    p[4]=fb.x; p[5]=fb.y; p[6]=fb.z; p[7]=fb.w;
    #pragma unroll
    for (int e = 0; e < 8; ++e){
      float ls = p[e] + f2v;                 // (f1+f2)*log2e
      float lrs = fmaxf(ls, 0.2f*ls);        // leaky-relu commutes with +scale
      float pe = EXP2(lrs);                  // raw v_exp_f32
      p[e] = (mb & (1u << e)) ? pe : 0.f;
    }
    union { bf16x8 v; unsigned u[4]; } A;
    A.u[0] = cvtpk_bf16(p[0], p[1]);
    A.u[1] = cvtpk_bf16(p[2], p[3]);
    A.u[2] = cvtpk_bf16(p[4], p[5]);
    A.u[3] = cvtpk_bf16(p[6], p[7]);

    union { bf16x8 v; unsigned u[4]; } B;
    uint4 ld = *(const uint4*)(bsrc + j8);
    B.u[0] = bge8 ? 0x3f803f80u : ld.x;   // col>=8: bf16 1.0 (col 8 = denominator)
    B.u[1] = bge8 ? 0x3f803f80u : ld.y;
    B.u[2] = bge8 ? 0x3f803f80u : ld.z;
    B.u[3] = bge8 ? 0x3f803f80u : ld.w;

    acc = __builtin_amdgcn_mfma_f32_16x16x32_bf16(A.v, B.v, acc, 0, 0, 0);
  }

  s_acc[js][lane] = acc;
  __syncthreads();
  if (js == 0){
    f32x4 a1 = s_acc[1][lane], a2 = s_acc[2][lane], a3 = s_acc[3][lane];
    #pragma unroll
    for (int j = 0; j < 4; ++j) acc[j] += a1[j] + a2[j] + a3[j];

    // denominator lives in column 8 of this kg-group: lane (lane&48)+8
    int slane = (lane & 48) + 8;
    #pragma unroll
    for (int r4 = 0; r4 < 4; ++r4){
      float sv = __shfl(acc[r4], slane, 64);
      float inv = 1.f / fmaxf(sv, 1e-10f);
      if (col < 8)
        posg[(size_t)(i0 + kg*4 + r4)*64 + h*8 + col] = acc[r4] * inv;
    }
  }
}

// ---------------- K4: residual proj + the two MLP channels + PairNorm partials ----------------
__global__ __launch_bounds__(256) void k4_mix(
    const float* __restrict__ h, const float* __restrict__ posg,
    const float* __restrict__ gat_bias, const float* __restrict__ proj_b,
    const float* __restrict__ wtproj, const float* __restrict__ wtself,
    const float* __restrict__ wtpos,
    const float* __restrict__ mlp_self_b, const float* __restrict__ mlp_pos_b,
    float* __restrict__ s0, float* __restrict__ s1, float* __restrict__ part)
{
  int tid = threadIdx.x;
  int wave = tid >> 6, lane = tid & 63;
  int n = blockIdx.x*4 + wave;
  float hreg = h[n*64 + lane];
  float pr = proj_b[lane];
  float se = mlp_self_b[lane];
  #pragma unroll
  for (int k = 0; k < 64; ++k){
    float hk = __shfl(hreg, k, 64);
    pr += hk * wtproj[k*64 + lane];
    se += hk * wtself[k*64 + lane];
  }
  float posf = posg[n*64 + lane] + gat_bias[lane] + pr;
  float s1v = mlp_pos_b[lane];
  #pragma unroll
  for (int k = 0; k < 64; ++k){
    float pk = __shfl(posf, k, 64);
    s1v += pk * wtpos[k*64 + lane];
  }
  s0[n*64+lane] = se;
  s1[n*64+lane] = s1v;

  __shared__ float sb0[4][64];
  __shared__ float sb1[4][64];
  __shared__ float sq[4];
  sb0[wave][lane] = se;
  sb1[wave][lane] = s1v;
  float q = se*se + s1v*s1v;
  #pragma unroll
  for (int s = 1; s < 64; s <<= 1) q += __shfl_xor(q, s, 64);
  if (lane == 0) sq[wave] = q;
  __syncthreads();
  if (tid < 64){
    part[blockIdx.x*130 + tid] = sb0[0][tid]+sb0[1][tid]+sb0[2][tid]+sb0[3][tid];
  } else if (tid < 128){
    int d = tid - 64;
    part[blockIdx.x*130 + 64 + d] = sb1[0][d]+sb1[1][d]+sb1[2][d]+sb1[3][d];
  } else if (tid == 128){
    part[blockIdx.x*130 + 128] = sq[0]+sq[1]+sq[2]+sq[3];
  }
}

// ---------------- K5: PairNorm stats (1024-thread two-stage reduce) ----------------
__global__ __launch_bounds__(1024) void k5_stats(const float* __restrict__ part, float* __restrict__ stats)
{
  int tid = threadIdx.x;
  __shared__ float s_mu[8][128];
  __shared__ float s_sq[8];
  int c = tid & 127, ch = tid >> 7;
  float a = 0.f;
  for (int b = ch*128; b < ch*128+128; ++b) a += part[b*130 + c];
  s_mu[ch][c] = a;
  if (tid < 8){
    float q = 0.f;
    for (int b = tid*128; b < tid*128+128; ++b) q += part[b*130 + 128];
    s_sq[tid] = q;
  }
  __syncthreads();
  if (tid < 128){
    float m = 0.f;
    #pragma unroll
    for (int j = 0; j < 8; ++j) m += s_mu[j][tid];
    s_mu[0][tid] = m;
    stats[tid] = m / 4096.f;
  }
  __syncthreads();
  if (tid == 0){
    float sq = 0.f;
    #pragma unroll
    for (int j = 0; j < 8; ++j) sq += s_sq[j];
    float mu2 = 0.f;
    for (int i = 0; i < 128; ++i){ float m = s_mu[0][i] / 4096.f; mu2 += m*m; }
    float msq = sq/(4096.f*64.f) - mu2/64.f;
    stats[128] = 1.f / sqrtf(1e-6f + msq);
  }
}

// ---------------- K6: semantic attention + predictor ----------------
__global__ __launch_bounds__(256) void k6_sem(
    const float* __restrict__ s0, const float* __restrict__ s1,
    const float* __restrict__ stats, const float* __restrict__ wtsem,
    const float* __restrict__ sem_b1, const float* __restrict__ sem_w2,
    const float* __restrict__ pred_w, const float* __restrict__ pred_b,
    float* __restrict__ out)
{
  int tid = threadIdx.x;
  int wave = tid >> 6, lane = tid & 63;
  int n = blockIdx.x*4 + wave;
  float rinv = stats[128];
  float a0 = (s0[n*64+lane] - stats[lane]) * rinv;
  float a1 = (s1[n*64+lane] - stats[64+lane]) * rinv;
  float t0 = sem_b1[lane], t1 = t0;
  #pragma unroll
  for (int k = 0; k < 64; ++k){
    float w = wtsem[k*64 + lane];
    t0 += __shfl(a0, k, 64) * w;
    t1 += __shfl(a1, k, 64) * w;
  }
  t0 = tanh_fast(t0); t1 = tanh_fast(t1);
  float w2 = sem_w2[lane];
  float w0 = t0*w2, w1 = t1*w2;
  #pragma unroll
  for (int s = 1; s < 64; s <<= 1){
    w0 += __shfl_xor(w0, s, 64);
    w1 += __shfl_xor(w1, s, 64);
  }
  float mx = fmaxf(w0, w1);
  float e0 = __expf(w0 - mx), e1 = __expf(w1 - mx);
  float denom = e0 + e1 + 1e-10f;
  float b0 = e0/denom, b1 = e1/denom;
  float emb = b0*a0 + b1*a1;
  float pl = emb * pred_w[lane];
  #pragma unroll
  for (int s = 1; s < 64; s <<= 1) pl += __shfl_xor(pl, s, 64);
  if (lane == 0) out[n] = sigm(pl + pred_b[0]);
}

extern "C" void kernel_launch(void* const* d_in, const int* in_sizes, int n_in,
                              void* d_out, int out_size, void* d_ws, size_t ws_size,
                              hipStream_t stream)
{
  (void)in_sizes; (void)n_in; (void)out_size; (void)ws_size;
  const float* x         = (const float*)d_in[0];
  const int*   adj       = (const int*)d_in[1];
  const float* W_ih      = (const float*)d_in[2];
  const float* W_hh      = (const float*)d_in[3];
  const float* b_ih      = (const float*)d_in[4];
  const float* b_hh      = (const float*)d_in[5];
  const float* gat_w     = (const float*)d_in[6];
  const float* gat_wu    = (const float*)d_in[7];
  const float* gat_wv    = (const float*)d_in[8];
  const float* gat_bias  = (const float*)d_in[9];
  const float* proj_w    = (const float*)d_in[10];
  const float* proj_b    = (const float*)d_in[11];
  const float* mlp_self_w= (const float*)d_in[12];
  const float* mlp_self_b= (const float*)d_in[13];
  const float* mlp_pos_w = (const float*)d_in[14];
  const float* mlp_pos_b = (const float*)d_in[15];
  const float* sem_w1    = (const float*)d_in[16];
  const float* sem_b1    = (const float*)d_in[17];
  const float* sem_w2    = (const float*)d_in[18];
  const float* pred_w    = (const float*)d_in[19];
  const float* pred_b    = (const float*)d_in[20];
  float* out = (float*)d_out;
  float* ws  = (float*)d_ws;

  float* h     = ws + 0;         // 262144
  // supb (bf16 [64][4096] = 512KB) overlays the old f32 supt region (1MB)
  unsigned short* supb = (unsigned short*)(ws + 262144);
  float* f1t   = ws + 524288;    // 32768   [8][4096]
  float* f2    = ws + 557056;    // 32768   [4096][8]
  float* posg  = ws + 589824;    // 262144
  float* s0    = ws + 851968;    // 262144
  float* s1    = ws + 1114112;   // 262144
  // adjm overlays s0+s1 (2MB): written by k2c, consumed by k3, dead before k4 writes s0/s1.
  // GRU fragment buffers (36KB) overlay the TAIL of the adjm region: k0 writes them,
  // k1 reads them, both complete before k2c overwrites (stream-ordered).
  unsigned long long* adjm = (unsigned long long*)(ws + 851968);
  uint4* whhF = (uint4*)(ws + 1114112 + 200000);  // 24*64 uint4
  uint4* wihF = whhF + 24*64;                      // 12*64
  float* part  = ws + 1376256;   // 1024*130
  float* stats = ws + 1517576;   // 129
  float* wtproj= ws + 1517712;   // 4096
  float* wtself= wtproj + 4096;
  float* wtpos = wtself + 4096;
  float* wtsem = wtpos  + 4096;

  k0_prep<<<25, 256, 0, stream>>>(proj_w, mlp_self_w, mlp_pos_w, sem_w1,
                                  W_ih, W_hh, b_ih, b_hh,
                                  wtproj, wtself, wtpos, wtsem, whhF, wihF);
  k1_gru<<<256, 256, 0, stream>>>(x, whhF, wihF, b_hh, h);
  k2_sup<<<1024, 256, 0, stream>>>(h, gat_w, gat_wu, gat_wv, supb, f1t, f2);
  k2c_pack<<<1024, 256, 0, stream>>>(adj, adjm);
  k3_gat<<<2048, 256, 0, stream>>>(adjm, supb, f1t, f2, posg);
  k4_mix<<<1024, 256, 0, stream>>>(h, posg, gat_bias, proj_b, wtproj, wtself, wtpos,
                                   mlp_self_b, mlp_pos_b, s0, s1, part);
  k5_stats<<<1, 1024, 0, stream>>>(part, stats);
  k6_sem<<<1024, 256, 0, stream>>>(s0, s1, stats, wtsem, sem_b1, sem_w2, pred_w, pred_b, out);
}

// Round 17
// 165.174 us; speedup vs baseline: 3.2516x; 1.1963x over previous
//
#include <hip/hip_runtime.h>
#include <math.h>

#define NN 4096
#define TT 32
#define FF 7
#define HH 64
#define NHEAD 8
#define DOUT 8
#define LOG2E 1.44269504f

#if __has_builtin(__builtin_amdgcn_exp2f)
#define EXP2(x) __builtin_amdgcn_exp2f(x)
#else
#define EXP2(x) exp2f(x)
#endif

typedef short bf16x8 __attribute__((ext_vector_type(8)));
typedef float f32x4 __attribute__((ext_vector_type(4)));

__device__ __forceinline__ float sigm(float x){
  x = fminf(fmaxf(x, -30.f), 30.f);
  return 1.f / (1.f + __expf(-x));
}
__device__ __forceinline__ float tanh_fast(float x){
  x = fminf(fmaxf(x, -15.f), 15.f);
  float e = __expf(2.f*x);
  return (e - 1.f) / (e + 1.f);
}
__device__ __forceinline__ unsigned short bf16rne(float f){
  unsigned u = __float_as_uint(f);
  u += 0x7fffu + ((u >> 16) & 1u);
  return (unsigned short)(u >> 16);
}
__device__ __forceinline__ unsigned bfpack2(float a, float b){
  return (unsigned)bf16rne(a) | ((unsigned)bf16rne(b) << 16);
}
__device__ __forceinline__ unsigned cvtpk_bf16(float a, float b){
  unsigned r;
  asm("v_cvt_pk_bf16_f32 %0, %1, %2" : "=v"(r) : "v"(a), "v"(b));
  return r;
}

// ---------------- K0: weight transposes (blocks 0-15) + GRU frag pack (16-24) ----------------
__global__ __launch_bounds__(256) void k0_prep(
    const float* __restrict__ pw, const float* __restrict__ msw,
    const float* __restrict__ mpw, const float* __restrict__ sw1,
    const float* __restrict__ Wih, const float* __restrict__ Whh,
    const float* __restrict__ bih, const float* __restrict__ bhh,
    float* __restrict__ wtproj, float* __restrict__ wtself,
    float* __restrict__ wtpos, float* __restrict__ wtsem,
    uint4* __restrict__ whhF, uint4* __restrict__ wihF)
{
  if (blockIdx.x < 16){
    int tid = threadIdx.x + blockIdx.x*256;
    int d = tid >> 6, k = tid & 63;
    wtproj[k*64+d] = pw[tid];
    wtself[k*64+d] = msw[tid];
    wtpos[k*64+d]  = mpw[tid];
    wtsem[k*64+d]  = sw1[tid];
    return;
  }
  int idx = (blockIdx.x-16)*256 + threadIdx.x;     // 0..2303
  if (idx < 24*64){
    int f = idx >> 6, lane = idx & 63;
    int T = f >> 1, c = f & 1;
    int g = T*16 + (lane & 15);
    const float* wp = Whh + g*64 + c*32 + (lane >> 4)*8;
    uint4 v;
    v.x = bfpack2(wp[0], wp[1]);
    v.y = bfpack2(wp[2], wp[3]);
    v.z = bfpack2(wp[4], wp[5]);
    v.w = bfpack2(wp[6], wp[7]);
    whhF[idx] = v;
  } else if (idx < 36*64){
    int i2 = idx - 24*64;
    int T = i2 >> 6, lane = i2 & 63;
    int g = T*16 + (lane & 15);
    int kg = lane >> 4;
    float bias = (T < 8) ? (bih[g] + bhh[g]) : bih[g];   // b_hhn NOT folded (inside r*())
    float f8[8];
    #pragma unroll
    for (int j = 0; j < 8; ++j){
      int k = kg*8 + j;
      f8[j] = (k < 7) ? Wih[g*7 + k] : ((k == 7) ? bias : 0.f);
    }
    uint4 v;
    v.x = bfpack2(f8[0], f8[1]); v.y = bfpack2(f8[2], f8[3]);
    v.z = bfpack2(f8[4], f8[5]); v.w = bfpack2(f8[6], f8[7]);
    wihF[i2] = v;
  }
}

// ---------------- K1: GRU encoder via MFMA, gates split across 4 waves ----------------
__global__ __launch_bounds__(256) void k1_gru(
    const float* __restrict__ x,      // [N][T][F]
    const uint4* __restrict__ whhF,   // [24][64]
    const uint4* __restrict__ wihF,   // [12][64]
    const float* __restrict__ bhh,
    float* __restrict__ hout)         // [N][64]
{
  __shared__ __align__(16) short s_xb[32][16][8];   // 8KB   bf16 x (k=7 -> 1.0)
  __shared__ __align__(16) short s_hb[2][16][72];   // 4.5KB bf16 h, double-buffered

  int tid = threadIdx.x;
  int lane = tid & 63, w = tid >> 6;    // wave = gate-tile group
  int nb = blockIdx.x * 16;
  int row = lane & 15;                  // B/D: node column
  int kg  = lane >> 4;                  // k-group

  union U { bf16x8 v; uint4 q; };
  U u;
  u.q = wihF[w*64 + lane];           bf16x8 fRx  = u.v;
  u.q = whhF[(w*2+0)*64 + lane];     bf16x8 fRh0 = u.v;
  u.q = whhF[(w*2+1)*64 + lane];     bf16x8 fRh1 = u.v;
  u.q = wihF[(4+w)*64 + lane];       bf16x8 fZx  = u.v;
  u.q = whhF[((4+w)*2+0)*64 + lane]; bf16x8 fZh0 = u.v;
  u.q = whhF[((4+w)*2+1)*64 + lane]; bf16x8 fZh1 = u.v;
  u.q = wihF[(8+w)*64 + lane];       bf16x8 fNx  = u.v;
  u.q = whhF[((8+w)*2+0)*64 + lane]; bf16x8 fNh0 = u.v;
  u.q = whhF[((8+w)*2+1)*64 + lane]; bf16x8 fNh1 = u.v;

  for (int s = tid; s < 4096; s += 256){
    int t = s >> 7, node = (s >> 3) & 15, k = s & 7;
    float v = (k < 7) ? x[(size_t)(nb + node)*224 + t*7 + k] : ((k == 7) ? 1.f : 0.f);
    s_xb[t][node][k] = (short)bf16rne(v);
  }
  for (int i = tid; i < 576; i += 256) ((unsigned*)&s_hb[0][0][0])[i] = 0u;

  float bhn_[4];
  #pragma unroll
  for (int j = 0; j < 4; ++j) bhn_[j] = bhh[128 + w*16 + kg*4 + j];
  float hreg[4] = {0.f, 0.f, 0.f, 0.f};
  f32x4 z4 = {0.f, 0.f, 0.f, 0.f};

  __syncthreads();
  int cur = 0;
  for (int t = 0; t < TT; ++t){
    bf16x8 bx = {0,0,0,0,0,0,0,0};
    if (lane < 16) bx = *(const bf16x8*)&s_xb[t][row][0];
    bf16x8 bh0 = *(const bf16x8*)&s_hb[cur][row][kg*8];
    bf16x8 bh1 = *(const bf16x8*)&s_hb[cur][row][32 + kg*8];

    f32x4 aR = __builtin_amdgcn_mfma_f32_16x16x32_bf16(fRx, bx, z4, 0, 0, 0);
    aR = __builtin_amdgcn_mfma_f32_16x16x32_bf16(fRh0, bh0, aR, 0, 0, 0);
    aR = __builtin_amdgcn_mfma_f32_16x16x32_bf16(fRh1, bh1, aR, 0, 0, 0);
    f32x4 aZ = __builtin_amdgcn_mfma_f32_16x16x32_bf16(fZx, bx, z4, 0, 0, 0);
    aZ = __builtin_amdgcn_mfma_f32_16x16x32_bf16(fZh0, bh0, aZ, 0, 0, 0);
    aZ = __builtin_amdgcn_mfma_f32_16x16x32_bf16(fZh1, bh1, aZ, 0, 0, 0);
    f32x4 aNx = __builtin_amdgcn_mfma_f32_16x16x32_bf16(fNx, bx, z4, 0, 0, 0);
    f32x4 aNh = __builtin_amdgcn_mfma_f32_16x16x32_bf16(fNh0, bh0, z4, 0, 0, 0);
    aNh = __builtin_amdgcn_mfma_f32_16x16x32_bf16(fNh1, bh1, aNh, 0, 0, 0);

    #pragma unroll
    for (int j = 0; j < 4; ++j){
      float rr = sigm(aR[j]);
      float zz = sigm(aZ[j]);
      float nn = tanh_fast(aNx[j] + rr*(aNh[j] + bhn_[j]));
      hreg[j] = (1.f - zz)*nn + zz*hreg[j];
    }
    uint2 p;
    p.x = bfpack2(hreg[0], hreg[1]);
    p.y = bfpack2(hreg[2], hreg[3]);
    *(uint2*)&s_hb[cur^1][row][w*16 + kg*4] = p;
    __syncthreads();
    cur ^= 1;
  }

  #pragma unroll
  for (int j = 0; j < 4; ++j)
    hout[(size_t)(nb + row)*64 + w*16 + kg*4 + j] = hreg[j];
}

// ---------------- K2: supbJ (bf16, j-blocked) = h@gat_w; f1t/f2 pre-scaled by log2e ----------------
// supbJ layout: [head][j>>3][o][j&7] so k3's B-fragment load is one contiguous
// 512B region per wave instruction (round-16: the [64][N] layout made it a
// 32-distinct-address gather -> TA-unit serialization was k3's real wall).
__global__ __launch_bounds__(256) void k2_sup(
    const float* __restrict__ h, const float* __restrict__ gat_w,
    const float* __restrict__ wu, const float* __restrict__ wv,
    unsigned short* __restrict__ supbJ, // [8][512][8][8] bf16
    float* __restrict__ f1t,            // [8][N]  (x log2e)
    float* __restrict__ f2)             // [N][8]  (x log2e)
{
  int tid = threadIdx.x;
  int wave = tid >> 6, lane = tid & 63;
  int n = blockIdx.x*4 + wave;
  float hreg = h[n*64 + lane];
  float acc = 0.f;
  #pragma unroll
  for (int k = 0; k < 64; ++k){
    float hk = __shfl(hreg, k, 64);
    acc += hk * gat_w[k*64 + lane];
  }
  int hh = lane >> 3, o = lane & 7;
  supbJ[(size_t)hh*32768 + (n>>3)*64 + o*8 + (n&7)] = bf16rne(acc);
  float p1 = acc * wu[lane];
  float p2 = acc * wv[lane];
  #pragma unroll
  for (int s = 1; s < 8; s <<= 1){
    p1 += __shfl_xor(p1, s, 64);
    p2 += __shfl_xor(p2, s, 64);
  }
  if (o == 0){
    f1t[(size_t)hh*NN + n] = p1 * LOG2E;   // exp(x) == exp2(x*log2e): scale folded here
    f2[n*8 + hh] = p2 * LOG2E;
  }
}

// ---------------- K2c: pack adjacency rows into transposed 64-bit masks ----------------
// adjmT layout: [tile=row>>4][word][row&15] so k3's mask load is 128B contiguous.
__global__ __launch_bounds__(256) void k2c_pack(const int* __restrict__ adj,
                                               unsigned long long* __restrict__ adjmT)
{
  int lane = threadIdx.x & 63, wave = threadIdx.x >> 6;
  int row = blockIdx.x*4 + wave;
  const int* ap = adj + (size_t)row*NN;
  size_t base = (size_t)(row >> 4)*1024 + (row & 15);
  #pragma unroll 8
  for (int s = 0; s < 64; ++s){
    unsigned long long m = __ballot(ap[s*64 + lane] != 0);
    if (lane == 0) adjmT[base + s*16] = m;
  }
}

// ---------------- K3: flash-style MFMA GAT, 4-way j-split, coalesced loads ----------------
__global__ __launch_bounds__(256) void k3_gat(
    const unsigned long long* __restrict__ adjmT,  // [256][64][16]
    const unsigned short* __restrict__ supbJ,      // [8][512][8][8] bf16
    const float* __restrict__ f1t,                 // [8][N]  (x log2e)
    const float* __restrict__ f2,                  // [N][8]  (x log2e)
    float* __restrict__ posg)
{
  __shared__ f32x4 s_acc[4][64];        // 4KB merge buffer
  int tid = threadIdx.x;
  int lane = tid & 63, js = tid >> 6;
  int gid = blockIdx.x;                 // 0..2047
  int ib = gid >> 3, h = gid & 7;
  int i0 = ib*16;
  int col = lane & 15;                  // A-row during build; B/D column after
  int kg  = lane >> 4;

  float f2v = f2[(size_t)(i0+col)*8 + h];   // already x log2e

  const unsigned long long* mrowT = adjmT + (size_t)ib*1024;   // [word][16 rows]
  const float* f1p = f1t + (size_t)h*NN;
  const unsigned short* bsrcJ = supbJ + (size_t)h*32768;
  unsigned bge8 = (col >= 8) ? 0xffffffffu : 0u;   // lanes feeding the sum column

  f32x4 acc = {0.f, 0.f, 0.f, 0.f};

  #pragma unroll 4
  for (int cc = 0; cc < 32; ++cc){
    int c = js*32 + cc;
    int j8 = c*32 + kg*8;
    unsigned long long mw = mrowT[(c >> 1)*16 + col];          // 128B contiguous
    unsigned mb = (unsigned)(mw >> (((c & 1) << 5) + (kg << 3)));
    float4 fa = *(const float4*)(f1p + j8);
    float4 fb = *(const float4*)(f1p + j8 + 4);

    float p[8];
    p[0]=fa.x; p[1]=fa.y; p[2]=fa.z; p[3]=fa.w;
    p[4]=fb.x; p[5]=fb.y; p[6]=fb.z; p[7]=fb.w;
    #pragma unroll
    for (int e = 0; e < 8; ++e){
      float ls = p[e] + f2v;                 // (f1+f2)*log2e
      float lrs = fmaxf(ls, 0.2f*ls);        // leaky-relu commutes with +scale
      float pe = EXP2(lrs);                  // raw v_exp_f32
      p[e] = (mb & (1u << e)) ? pe : 0.f;
    }
    union { bf16x8 v; unsigned u[4]; } A;
    A.u[0] = cvtpk_bf16(p[0], p[1]);
    A.u[1] = cvtpk_bf16(p[2], p[3]);
    A.u[2] = cvtpk_bf16(p[4], p[5]);
    A.u[3] = cvtpk_bf16(p[6], p[7]);

    union { bf16x8 v; unsigned u[4]; } B;
    uint4 ld = *(const uint4*)(bsrcJ + (size_t)(c*4 + kg)*64 + (col & 7)*8);  // contiguous 512B/wave
    B.u[0] = bge8 ? 0x3f803f80u : ld.x;   // col>=8: bf16 1.0 (col 8 = denominator)
    B.u[1] = bge8 ? 0x3f803f80u : ld.y;
    B.u[2] = bge8 ? 0x3f803f80u : ld.z;
    B.u[3] = bge8 ? 0x3f803f80u : ld.w;

    acc = __builtin_amdgcn_mfma_f32_16x16x32_bf16(A.v, B.v, acc, 0, 0, 0);
  }

  s_acc[js][lane] = acc;
  __syncthreads();
  if (js == 0){
    f32x4 a1 = s_acc[1][lane], a2 = s_acc[2][lane], a3 = s_acc[3][lane];
    #pragma unroll
    for (int j = 0; j < 4; ++j) acc[j] += a1[j] + a2[j] + a3[j];

    // denominator lives in column 8 of this kg-group: lane (lane&48)+8
    int slane = (lane & 48) + 8;
    #pragma unroll
    for (int r4 = 0; r4 < 4; ++r4){
      float sv = __shfl(acc[r4], slane, 64);
      float inv = 1.f / fmaxf(sv, 1e-10f);
      if (col < 8)
        posg[(size_t)(i0 + kg*4 + r4)*64 + h*8 + col] = acc[r4] * inv;
    }
  }
}

// ---------------- K4: residual proj + the two MLP channels + PairNorm partials ----------------
__global__ __launch_bounds__(256) void k4_mix(
    const float* __restrict__ h, const float* __restrict__ posg,
    const float* __restrict__ gat_bias, const float* __restrict__ proj_b,
    const float* __restrict__ wtproj, const float* __restrict__ wtself,
    const float* __restrict__ wtpos,
    const float* __restrict__ mlp_self_b, const float* __restrict__ mlp_pos_b,
    float* __restrict__ s0, float* __restrict__ s1, float* __restrict__ part)
{
  int tid = threadIdx.x;
  int wave = tid >> 6, lane = tid & 63;
  int n = blockIdx.x*4 + wave;
  float hreg = h[n*64 + lane];
  float pr = proj_b[lane];
  float se = mlp_self_b[lane];
  #pragma unroll
  for (int k = 0; k < 64; ++k){
    float hk = __shfl(hreg, k, 64);
    pr += hk * wtproj[k*64 + lane];
    se += hk * wtself[k*64 + lane];
  }
  float posf = posg[n*64 + lane] + gat_bias[lane] + pr;
  float s1v = mlp_pos_b[lane];
  #pragma unroll
  for (int k = 0; k < 64; ++k){
    float pk = __shfl(posf, k, 64);
    s1v += pk * wtpos[k*64 + lane];
  }
  s0[n*64+lane] = se;
  s1[n*64+lane] = s1v;

  __shared__ float sb0[4][64];
  __shared__ float sb1[4][64];
  __shared__ float sq[4];
  sb0[wave][lane] = se;
  sb1[wave][lane] = s1v;
  float q = se*se + s1v*s1v;
  #pragma unroll
  for (int s = 1; s < 64; s <<= 1) q += __shfl_xor(q, s, 64);
  if (lane == 0) sq[wave] = q;
  __syncthreads();
  if (tid < 64){
    part[blockIdx.x*130 + tid] = sb0[0][tid]+sb0[1][tid]+sb0[2][tid]+sb0[3][tid];
  } else if (tid < 128){
    int d = tid - 64;
    part[blockIdx.x*130 + 64 + d] = sb1[0][d]+sb1[1][d]+sb1[2][d]+sb1[3][d];
  } else if (tid == 128){
    part[blockIdx.x*130 + 128] = sq[0]+sq[1]+sq[2]+sq[3];
  }
}

// ---------------- K5: PairNorm stats (1024-thread two-stage reduce) ----------------
__global__ __launch_bounds__(1024) void k5_stats(const float* __restrict__ part, float* __restrict__ stats)
{
  int tid = threadIdx.x;
  __shared__ float s_mu[8][128];
  __shared__ float s_sq[8];
  int c = tid & 127, ch = tid >> 7;
  float a = 0.f;
  for (int b = ch*128; b < ch*128+128; ++b) a += part[b*130 + c];
  s_mu[ch][c] = a;
  if (tid < 8){
    float q = 0.f;
    for (int b = tid*128; b < tid*128+128; ++b) q += part[b*130 + 128];
    s_sq[tid] = q;
  }
  __syncthreads();
  if (tid < 128){
    float m = 0.f;
    #pragma unroll
    for (int j = 0; j < 8; ++j) m += s_mu[j][tid];
    s_mu[0][tid] = m;
    stats[tid] = m / 4096.f;
  }
  __syncthreads();
  if (tid == 0){
    float sq = 0.f;
    #pragma unroll
    for (int j = 0; j < 8; ++j) sq += s_sq[j];
    float mu2 = 0.f;
    for (int i = 0; i < 128; ++i){ float m = s_mu[0][i] / 4096.f; mu2 += m*m; }
    float msq = sq/(4096.f*64.f) - mu2/64.f;
    stats[128] = 1.f / sqrtf(1e-6f + msq);
  }
}

// ---------------- K6: semantic attention + predictor ----------------
__global__ __launch_bounds__(256) void k6_sem(
    const float* __restrict__ s0, const float* __restrict__ s1,
    const float* __restrict__ stats, const float* __restrict__ wtsem,
    const float* __restrict__ sem_b1, const float* __restrict__ sem_w2,
    const float* __restrict__ pred_w, const float* __restrict__ pred_b,
    float* __restrict__ out)
{
  int tid = threadIdx.x;
  int wave = tid >> 6, lane = tid & 63;
  int n = blockIdx.x*4 + wave;
  float rinv = stats[128];
  float a0 = (s0[n*64+lane] - stats[lane]) * rinv;
  float a1 = (s1[n*64+lane] - stats[64+lane]) * rinv;
  float t0 = sem_b1[lane], t1 = t0;
  #pragma unroll
  for (int k = 0; k < 64; ++k){
    float w = wtsem[k*64 + lane];
    t0 += __shfl(a0, k, 64) * w;
    t1 += __shfl(a1, k, 64) * w;
  }
  t0 = tanh_fast(t0); t1 = tanh_fast(t1);
  float w2 = sem_w2[lane];
  float w0 = t0*w2, w1 = t1*w2;
  #pragma unroll
  for (int s = 1; s < 64; s <<= 1){
    w0 += __shfl_xor(w0, s, 64);
    w1 += __shfl_xor(w1, s, 64);
  }
  float mx = fmaxf(w0, w1);
  float e0 = __expf(w0 - mx), e1 = __expf(w1 - mx);
  float denom = e0 + e1 + 1e-10f;
  float b0 = e0/denom, b1 = e1/denom;
  float emb = b0*a0 + b1*a1;
  float pl = emb * pred_w[lane];
  #pragma unroll
  for (int s = 1; s < 64; s <<= 1) pl += __shfl_xor(pl, s, 64);
  if (lane == 0) out[n] = sigm(pl + pred_b[0]);
}

extern "C" void kernel_launch(void* const* d_in, const int* in_sizes, int n_in,
                              void* d_out, int out_size, void* d_ws, size_t ws_size,
                              hipStream_t stream)
{
  (void)in_sizes; (void)n_in; (void)out_size; (void)ws_size;
  const float* x         = (const float*)d_in[0];
  const int*   adj       = (const int*)d_in[1];
  const float* W_ih      = (const float*)d_in[2];
  const float* W_hh      = (const float*)d_in[3];
  const float* b_ih      = (const float*)d_in[4];
  const float* b_hh      = (const float*)d_in[5];
  const float* gat_w     = (const float*)d_in[6];
  const float* gat_wu    = (const float*)d_in[7];
  const float* gat_wv    = (const float*)d_in[8];
  const float* gat_bias  = (const float*)d_in[9];
  const float* proj_w    = (const float*)d_in[10];
  const float* proj_b    = (const float*)d_in[11];
  const float* mlp_self_w= (const float*)d_in[12];
  const float* mlp_self_b= (const float*)d_in[13];
  const float* mlp_pos_w = (const float*)d_in[14];
  const float* mlp_pos_b = (const float*)d_in[15];
  const float* sem_w1    = (const float*)d_in[16];
  const float* sem_b1    = (const float*)d_in[17];
  const float* sem_w2    = (const float*)d_in[18];
  const float* pred_w    = (const float*)d_in[19];
  const float* pred_b    = (const float*)d_in[20];
  float* out = (float*)d_out;
  float* ws  = (float*)d_ws;

  float* h     = ws + 0;         // 262144
  // supbJ (bf16 [8][512][8][8] = 512KB) overlays the old supt region (1MB)
  unsigned short* supbJ = (unsigned short*)(ws + 262144);
  float* f1t   = ws + 524288;    // 32768   [8][4096]
  float* f2    = ws + 557056;    // 32768   [4096][8]
  float* posg  = ws + 589824;    // 262144
  float* s0    = ws + 851968;    // 262144
  float* s1    = ws + 1114112;   // 262144
  // adjmT overlays s0+s1 (2MB): written by k2c, consumed by k3, dead before k4 writes s0/s1.
  // GRU fragment buffers (36KB) overlay the TAIL of the region: k0 writes, k1 reads,
  // both complete before k2c overwrites (stream-ordered).
  unsigned long long* adjmT = (unsigned long long*)(ws + 851968);
  uint4* whhF = (uint4*)(ws + 1114112 + 200000);  // 24*64 uint4
  uint4* wihF = whhF + 24*64;                      // 12*64
  float* part  = ws + 1376256;   // 1024*130
  float* stats = ws + 1517576;   // 129
  float* wtproj= ws + 1517712;   // 4096
  float* wtself= wtproj + 4096;
  float* wtpos = wtself + 4096;
  float* wtsem = wtpos  + 4096;

  k0_prep<<<25, 256, 0, stream>>>(proj_w, mlp_self_w, mlp_pos_w, sem_w1,
                                  W_ih, W_hh, b_ih, b_hh,
                                  wtproj, wtself, wtpos, wtsem, whhF, wihF);
  k1_gru<<<256, 256, 0, stream>>>(x, whhF, wihF, b_hh, h);
  k2_sup<<<1024, 256, 0, stream>>>(h, gat_w, gat_wu, gat_wv, supbJ, f1t, f2);
  k2c_pack<<<1024, 256, 0, stream>>>(adj, adjmT);
  k3_gat<<<2048, 256, 0, stream>>>(adjmT, supbJ, f1t, f2, posg);
  k4_mix<<<1024, 256, 0, stream>>>(h, posg, gat_bias, proj_b, wtproj, wtself, wtpos,
                                   mlp_self_b, mlp_pos_b, s0, s1, part);
  k5_stats<<<1, 1024, 0, stream>>>(part, stats);
  k6_sem<<<1024, 256, 0, stream>>>(s0, s1, stats, wtsem, sem_b1, sem_w2, pred_w, pred_b, out);
}